// Round 7
// baseline (283.828 us; speedup 1.0000x reference)
//
#include <hip/hip_runtime.h>
#include <hip/hip_bf16.h>

typedef unsigned short u16;
typedef __bf16 bf16x8 __attribute__((ext_vector_type(8)));
typedef float f32x4 __attribute__((ext_vector_type(4)));

#define AS1 __attribute__((address_space(1)))
#define AS3 __attribute__((address_space(3)))

__device__ inline u16 f2bf(float f) {
  union { float f; unsigned int u; } c; c.f = f;
  unsigned int u = c.u;
  return (u16)((u + 0x7fffu + ((u >> 16) & 1u)) >> 16);
}

// ---------------- fp32 -> bf16 conversion ----------------
__global__ __launch_bounds__(256) void cvt_f32_bf16(const float* __restrict__ in,
                                                    u16* __restrict__ out, int n4) {
  int i = blockIdx.x * 256 + threadIdx.x;
  if (i >= n4) return;
  float4 v = reinterpret_cast<const float4*>(in)[i];
  ushort4 o;
  o.x = f2bf(v.x); o.y = f2bf(v.y); o.z = f2bf(v.z); o.w = f2bf(v.w);
  reinterpret_cast<ushort4*>(out)[i] = o;
}

// ============ 256x256 NT GEMM, BK=64, 8 waves, 4-phase, vmcnt(6)/phase ========
// C[m,n] = scale * sum_k A[m,k]*B[n,k].  M,N mult of 256; K mult of 64, K/64>=4.
// LDS: 2 x (A[256][64]+B[256][64]) bf16 = 128 KiB, XOR-swizzled (byte^=(row&7)<<4)
// with pre-swizzled global source. Stage slots: ph0->B0(t+1), ph1->A1(t+1),
// ph2->A0(t+2), ph3->B1(t+2). UNIFORM vmcnt(6) before every phase barrier (the
// R3-proven pacing: each phase retires exactly one half-tile, spreading the
// drain; each half-tile retires >=1 barrier before its first ds_read).
// z-offset = (z>>2)*sZ4 + (z&3)*sZ1 (split-K chunks). C column fold:
// chunk = n0>>cShift (tiles never span folds).

__device__ __forceinline__ void stage_half(const u16* __restrict__ g, long ld, int k0,
                                           u16* dst, int t) {
#pragma unroll
  for (int i = 0; i < 2; ++i) {
    const int c = i * 512 + t;
    const int r = c >> 3;
    const int s = c & 7;
    const int col = ((s ^ (r & 7)) << 3) + k0;   // pre-swizzled global source
    __builtin_amdgcn_global_load_lds((const AS1 void*)(g + (long)r * ld + col),
                                     (AS3 void*)(dst + c * 8), 16, 0, 0);
  }
}

__device__ __forceinline__ bf16x8 frag_ld(const u16* s, int row, int colb) {
  return *reinterpret_cast<const bf16x8*>(
      reinterpret_cast<const char*>(s) + row * 128 + (colb ^ ((row & 7) << 4)));
}

#define BAR_PRE()       do { asm volatile("s_waitcnt vmcnt(6)" ::: "memory"); \
                             __builtin_amdgcn_s_barrier(); \
                             asm volatile("" ::: "memory"); } while (0)
#define BAR_POST()      do { asm volatile("" ::: "memory"); \
                             __builtin_amdgcn_s_barrier(); \
                             asm volatile("" ::: "memory"); } while (0)

template<bool OUT_F32>
__global__ __launch_bounds__(512, 2) void gemm_nt256(
    const u16* __restrict__ A, long lda, long sAz4, long sAz1,
    const u16* __restrict__ B, long ldb, long sBz4, long sBz1,
    void* __restrict__ Cv, long ldc, long sCz4, long sCz1,
    long cBatch, int cShift,
    int K, float scale)
{
  __shared__ u16 sm[2 * 32768] __attribute__((aligned(16)));  // 128 KiB

  const int t = threadIdx.x;
  // T1: bijective XCD-chunked block swizzle (nwg % 8 == 0 for all our grids)
  int wg = blockIdx.x + gridDim.x * blockIdx.y;
  const int nwg = gridDim.x * gridDim.y;
  const int qq = nwg >> 3;
  wg = (wg & 7) * qq + (wg >> 3);
  const long m0 = (long)(wg % gridDim.x) * 256;
  const long n0 = (long)(wg / gridDim.x) * 256;
  const int z = blockIdx.z;
  const long azoff = (long)(z >> 2) * sAz4 + (long)(z & 3) * sAz1;
  const long bzoff = (long)(z >> 2) * sBz4 + (long)(z & 3) * sBz1;
  const u16* Ab = A + azoff + m0 * lda;
  const u16* Bb = B + bzoff + n0 * ldb;

  const int wid = t >> 6, lane = t & 63;
  const int lhi = lane >> 4, llo = lane & 15;
  const int wm = wid >> 2, wn = wid & 3;  // wave rows {wm*64, 128+wm*64}, cols {wn*32, 128+wn*32}

  f32x4 acc[2][4][2][2] = {};

  const int NT = K >> 6;

  // prologue, age order: A0(0), B1(0), B0(0), A1(0), A0(1), B1(1)
  stage_half(Ab, lda, 0, sm, t);
  stage_half(Bb + 128 * ldb, ldb, 0, sm + 16384 + 8192, t);
  stage_half(Bb, ldb, 0, sm + 16384, t);
  stage_half(Ab + 128 * lda, lda, 0, sm + 8192, t);
  stage_half(Ab, lda, 64, sm + 32768, t);
  stage_half(Bb + 128 * ldb, ldb, 64, sm + 32768 + 16384 + 8192, t);
  asm volatile("s_waitcnt vmcnt(4)" ::: "memory");  // tile0 done; A0(1),B1(1) in flight
  __builtin_amdgcn_s_barrier();
  asm volatile("" ::: "memory");

  for (int kt = 0; kt < NT; ++kt) {
    const int kb = kt & 1;
    u16* bc = sm + kb * 32768;          // current tile buffer
    u16* bn = sm + (kb ^ 1) * 32768;    // next tile buffer
    const u16* sAc = bc;
    const u16* sBc = bc + 16384;
    const int k1 = ((kt + 1 < NT) ? kt + 1 : 0) << 6;            // wrapped (dead) at tail
    const int k2 = ((kt + 2 < NT) ? kt + 2 : kt + 2 - NT) << 6;

    bf16x8 a[4][2], bl[2][2], bh[2][2];

    // ---- ph0: stage B0(t+1) -> bn; read A-lo(8) + B-lo(4); MFMA (Alo,Blo)
    stage_half(Bb, ldb, k1, bn + 16384, t);
#pragma unroll
    for (int fr = 0; fr < 4; ++fr)
#pragma unroll
      for (int kk = 0; kk < 2; ++kk)
        a[fr][kk] = frag_ld(sAc, wm * 64 + fr * 16 + llo, (kk << 6) + (lhi << 4));
#pragma unroll
    for (int fc = 0; fc < 2; ++fc)
#pragma unroll
      for (int kk = 0; kk < 2; ++kk)
        bl[fc][kk] = frag_ld(sBc, wn * 32 + fc * 16 + llo, (kk << 6) + (lhi << 4));
    BAR_PRE();
    __builtin_amdgcn_s_setprio(1);
#pragma unroll
    for (int fr = 0; fr < 4; ++fr)
#pragma unroll
      for (int fc = 0; fc < 2; ++fc)
#pragma unroll
        for (int kk = 0; kk < 2; ++kk)
          acc[0][fr][0][fc] = __builtin_amdgcn_mfma_f32_16x16x32_bf16(a[fr][kk], bl[fc][kk], acc[0][fr][0][fc], 0, 0, 0);
    __builtin_amdgcn_s_setprio(0);
    BAR_POST();

    // ---- ph1: stage A1(t+1) -> bn; read B-hi(4); MFMA (Alo,Bhi)
    stage_half(Ab + 128 * lda, lda, k1, bn + 8192, t);
#pragma unroll
    for (int fc = 0; fc < 2; ++fc)
#pragma unroll
      for (int kk = 0; kk < 2; ++kk)
        bh[fc][kk] = frag_ld(sBc, 128 + wn * 32 + fc * 16 + llo, (kk << 6) + (lhi << 4));
    BAR_PRE();
    __builtin_amdgcn_s_setprio(1);
#pragma unroll
    for (int fr = 0; fr < 4; ++fr)
#pragma unroll
      for (int fc = 0; fc < 2; ++fc)
#pragma unroll
        for (int kk = 0; kk < 2; ++kk)
          acc[0][fr][1][fc] = __builtin_amdgcn_mfma_f32_16x16x32_bf16(a[fr][kk], bh[fc][kk], acc[0][fr][1][fc], 0, 0, 0);
    __builtin_amdgcn_s_setprio(0);
    BAR_POST();

    // ---- ph2: stage A0(t+2) -> bc A-lo (dead); read A-hi(8); MFMA (Ahi,Bhi)
    stage_half(Ab, lda, k2, bc, t);
#pragma unroll
    for (int fr = 0; fr < 4; ++fr)
#pragma unroll
      for (int kk = 0; kk < 2; ++kk)
        a[fr][kk] = frag_ld(sAc, 128 + wm * 64 + fr * 16 + llo, (kk << 6) + (lhi << 4));
    BAR_PRE();
    __builtin_amdgcn_s_setprio(1);
#pragma unroll
    for (int fr = 0; fr < 4; ++fr)
#pragma unroll
      for (int fc = 0; fc < 2; ++fc)
#pragma unroll
        for (int kk = 0; kk < 2; ++kk)
          acc[1][fr][1][fc] = __builtin_amdgcn_mfma_f32_16x16x32_bf16(a[fr][kk], bh[fc][kk], acc[1][fr][1][fc], 0, 0, 0);
    __builtin_amdgcn_s_setprio(0);
    BAR_POST();

    // ---- ph3: stage B1(t+2) -> bc B-hi (dead); MFMA (Ahi,Blo)
    stage_half(Bb + 128 * ldb, ldb, k2, bc + 16384 + 8192, t);
    BAR_PRE();
    __builtin_amdgcn_s_setprio(1);
#pragma unroll
    for (int fr = 0; fr < 4; ++fr)
#pragma unroll
      for (int fc = 0; fc < 2; ++fc)
#pragma unroll
        for (int kk = 0; kk < 2; ++kk)
          acc[1][fr][0][fc] = __builtin_amdgcn_mfma_f32_16x16x32_bf16(a[fr][kk], bl[fc][kk], acc[1][fr][0][fc], 0, 0, 0);
    __builtin_amdgcn_s_setprio(0);
    BAR_POST();
  }

  // epilogue: C/D frag row=(lane>>4)*4+e, col=lane&15; column fold for chunked C
  const long cb = n0 >> cShift;
  const long ncol0 = n0 - (cb << cShift);
  const long czoff = (long)(z >> 2) * sCz4 + (long)(z & 3) * sCz1 + cb * cBatch;
#pragma unroll
  for (int ah = 0; ah < 2; ++ah)
#pragma unroll
    for (int fr = 0; fr < 4; ++fr)
#pragma unroll
      for (int e = 0; e < 4; ++e) {
        const long r = m0 + ah * 128 + wm * 64 + fr * 16 + lhi * 4 + e;
#pragma unroll
        for (int bh2 = 0; bh2 < 2; ++bh2)
#pragma unroll
          for (int fc = 0; fc < 2; ++fc) {
            const long col = ncol0 + bh2 * 128 + wn * 32 + fc * 16 + llo;
            const float val = acc[ah][fr][bh2][fc][e] * scale;
            if (OUT_F32)
              ((float*)Cv)[czoff + r * ldc + col] = val;
            else
              ((u16*)Cv)[czoff + r * ldc + col] = f2bf(val);
          }
      }
}

// ---- softmax over rows of att = sum of 4 split-K partials [16][1024][1024] f32 ----
__global__ __launch_bounds__(256) void softmax_reduce4(const float* __restrict__ att,
                                                       u16* __restrict__ P) {
  const long row = blockIdx.x;            // b*1024 + r
  const long b = row >> 10;
  const int t = threadIdx.x;
  float4 v; v.x = 0.f; v.y = 0.f; v.z = 0.f; v.w = 0.f;
#pragma unroll
  for (int p = 0; p < 4; ++p) {
    const float4 u = reinterpret_cast<const float4*>(att)[((b * 4 + p) << 18) + ((row & 1023) << 8) + t];
    v.x += u.x; v.y += u.y; v.z += u.z; v.w += u.w;
  }
  float m = fmaxf(fmaxf(v.x, v.y), fmaxf(v.z, v.w));
#pragma unroll
  for (int off = 32; off > 0; off >>= 1) m = fmaxf(m, __shfl_down(m, off, 64));
  __shared__ float smax[4], ssum[4];
  const int wid = t >> 6, lane = t & 63;
  if (lane == 0) smax[wid] = m;
  __syncthreads();
  m = fmaxf(fmaxf(smax[0], smax[1]), fmaxf(smax[2], smax[3]));
  float e0 = expf(v.x - m), e1 = expf(v.y - m), e2 = expf(v.z - m), e3 = expf(v.w - m);
  float s = e0 + e1 + e2 + e3;
#pragma unroll
  for (int off = 32; off > 0; off >>= 1) s += __shfl_down(s, off, 64);
  if (lane == 0) ssum[wid] = s;
  __syncthreads();
  s = ssum[0] + ssum[1] + ssum[2] + ssum[3];
  float inv = 1.0f / s;
  ushort4 o;
  o.x = f2bf(e0 * inv); o.y = f2bf(e1 * inv); o.z = f2bf(e2 * inv); o.w = f2bf(e3 * inv);
  reinterpret_cast<ushort4*>(P + row * 1024)[t] = o;
}

extern "C" void kernel_launch(void* const* d_in, const int* in_sizes, int n_in,
                              void* d_out, int out_size, void* d_ws, size_t ws_size,
                              hipStream_t stream) {
  const float* x  = (const float*)d_in[0];
  const float* Wq = (const float*)d_in[1];
  const float* Wk = (const float*)d_in[2];
  const float* Wv = (const float*)d_in[3];
  const float* Wo = (const float*)d_in[4];

  const long Bz = 4, L = 4096, E = 1024;
  const long BL = Bz * L;                 // 16384 tokens

  // workspace layout (u16 elements)
  u16* xbf  = (u16*)d_ws;                 // [16384][1024]
  u16* wqk  = xbf + BL * E;               // [2048][1024]  (Wq rows 0-1023, Wk 1024-2047)
  u16* wv   = wqk + 2048L * 1024;         // [1024][1024]
  u16* wo   = wv + 1024L * 1024;          // [1024][1024]
  u16* qhat = wo + 1024L * 1024;          // [4][4][1024][1024]: (b, token-chunk p, feature, token%1024)
  u16* khat = qhat + 16L * 1024 * 1024;   // same layout
  u16* vbuf = khat + 16L * 1024 * 1024;   // [16384][1024]
  // aliases (disjoint lifetimes):
  u16* P    = qhat;                       // [4][1024][1024] bf16 (qhat dead after stage 2)
  u16* outb = xbf;                        // [16384][1024] bf16 (xbf dead after stage 1b)
  float* attp = (float*)d_out;            // [16][1024][1024] f32 split-K partials (64 MB)

  dim3 b256(256), b512(512);
  const long NOF = 0;                     // no fold
  const int NSH = 30;

  // conversions
  cvt_f32_bf16<<<dim3((BL * E / 4 + 255) / 256), b256, 0, stream>>>(x, xbf, (int)(BL * E / 4));
  cvt_f32_bf16<<<dim3(1024), b256, 0, stream>>>(Wq, wqk, 1024 * 1024 / 4);
  cvt_f32_bf16<<<dim3(1024), b256, 0, stream>>>(Wk, wqk + 1024L * 1024, 1024 * 1024 / 4);
  cvt_f32_bf16<<<dim3(1024), b256, 0, stream>>>(Wv, wv, 1024 * 1024 / 4);
  cvt_f32_bf16<<<dim3(1024), b256, 0, stream>>>(Wo, wo, 1024 * 1024 / 4);

  // stage 1a (merged q+k): z=0 -> qhat = Wq @ xbf^T, z=1 -> khat = Wk @ xbf^T
  // (M=1024, N=16384 folded by 1024-token chunks: addr = (n>>10)*1M + feat*1024 + n%1024)
  gemm_nt256<false><<<dim3(4, 64, 2), b512, 0, stream>>>(
      wqk, 1024, 0, 1024L * 1024, xbf, 1024, 0, 0,
      (void*)qhat, 1024, 0, 16L * 1024 * 1024, 1L << 20, 10, 1024, 1.0f);
  // stage 1b: v = xbf @ Wv^T  (M=16384, N=1024, K=1024)
  gemm_nt256<false><<<dim3(64, 4, 1), b512, 0, stream>>>(
      xbf, 1024, 0, 0, wv, 1024, 0, 0,
      (void*)vbuf, 1024, 0, 0, NOF, NSH, 1024, 1.0f);
  // stage 2: att partials; z=b*4+p: A/B = dense [1024][1024] chunk at b*4M + p*1M
  gemm_nt256<true><<<dim3(4, 4, 16), b512, 0, stream>>>(
      qhat, 1024, 1L << 22, 1L << 20, khat, 1024, 1L << 22, 1L << 20,
      (void*)attp, 1024, 4L << 20, 1L << 20, NOF, NSH, 1024, 1.0f / 32.0f);
  // stage 3: reduce partials + softmax -> P bf16
  softmax_reduce4<<<dim3(4096), b256, 0, stream>>>(attp, P);
  // stage 4: out[b] = v[b] @ P[b]^T  (M=4096, N=1024, K=1024, z=b)
  gemm_nt256<false><<<dim3(16, 4, 4), b512, 0, stream>>>(
      vbuf, 1024, 0, 1L << 22, P, 1024, 0, 1L << 20,
      (void*)outb, 1024, 0, 1L << 22, NOF, NSH, 1024, 1.0f);
  // stage 5: final = out @ Wo^T  (M=16384, N=1024, K=1024) -> d_out fp32
  gemm_nt256<true><<<dim3(64, 4, 1), b512, 0, stream>>>(
      outb, 1024, 0, 0, wo, 1024, 0, 0,
      d_out, 1024, 0, 0, NOF, NSH, 1024, 1.0f);
}

// Round 8
// 275.647 us; speedup vs baseline: 1.0297x; 1.0297x over previous
//
#include <hip/hip_runtime.h>
#include <hip/hip_bf16.h>

typedef unsigned short u16;
typedef __bf16 bf16x8 __attribute__((ext_vector_type(8)));
typedef float f32x4 __attribute__((ext_vector_type(4)));

#define AS1 __attribute__((address_space(1)))
#define AS3 __attribute__((address_space(3)))

__device__ inline u16 f2bf(float f) {
  union { float f; unsigned int u; } c; c.f = f;
  unsigned int u = c.u;
  return (u16)((u + 0x7fffu + ((u >> 16) & 1u)) >> 16);
}

// ---------------- fp32 -> bf16 conversion (x) ----------------
__global__ __launch_bounds__(256) void cvt_f32_bf16(const float* __restrict__ in,
                                                    u16* __restrict__ out, int n4) {
  int i = blockIdx.x * 256 + threadIdx.x;
  if (i >= n4) return;
  float4 v = reinterpret_cast<const float4*>(in)[i];
  ushort4 o;
  o.x = f2bf(v.x); o.y = f2bf(v.y); o.z = f2bf(v.z); o.w = f2bf(v.w);
  reinterpret_cast<ushort4*>(out)[i] = o;
}

// ---------------- fused conversion of the 4 weight matrices ----------------
__global__ __launch_bounds__(256) void cvt_w4(const float* __restrict__ a, const float* __restrict__ b,
                                              const float* __restrict__ c, const float* __restrict__ d,
                                              u16* __restrict__ oa, u16* __restrict__ ob,
                                              u16* __restrict__ oc, u16* __restrict__ od) {
  int i = blockIdx.x * 256 + threadIdx.x;   // 4 * 262144 float4 chunks
  const int which = i >> 18;
  const int j = i & 262143;
  const float* src = which == 0 ? a : which == 1 ? b : which == 2 ? c : d;
  u16* dst = which == 0 ? oa : which == 1 ? ob : which == 2 ? oc : od;
  float4 v = reinterpret_cast<const float4*>(src)[j];
  ushort4 o;
  o.x = f2bf(v.x); o.y = f2bf(v.y); o.z = f2bf(v.z); o.w = f2bf(v.w);
  reinterpret_cast<ushort4*>(dst)[j] = o;
}

// ============ 256x256 NT GEMM, BK=64, 8 waves, 4-phase, vmcnt(6)/phase ========
// C[m,n] = scale * sum_k A[m,k]*B[n,k].  M,N mult of 256; K mult of 64, K/64>=4.
// LDS: 2 x (A[256][64]+B[256][64]) bf16 = 128 KiB, XOR-swizzled (byte^=(row&7)<<4)
// with pre-swizzled global source. Stage slots: ph0->B0(t+1), ph1->A1(t+1),
// ph2->A0(t+2), ph3->B1(t+2). UNIFORM vmcnt(6) before every phase barrier (the
// R3-proven pacing). Within each phase: ds_reads issued BEFORE the stage gloads
// (m201 order). z-offset = (z>>2)*sZ4 + (z&3)*sZ1. C column fold:
// chunk = n0>>cShift (tiles never span folds), chunk stride cBatch.

__device__ __forceinline__ void stage_half(const u16* __restrict__ g, long ld, int k0,
                                           u16* dst, int t) {
#pragma unroll
  for (int i = 0; i < 2; ++i) {
    const int c = i * 512 + t;
    const int r = c >> 3;
    const int s = c & 7;
    const int col = ((s ^ (r & 7)) << 3) + k0;   // pre-swizzled global source
    __builtin_amdgcn_global_load_lds((const AS1 void*)(g + (long)r * ld + col),
                                     (AS3 void*)(dst + c * 8), 16, 0, 0);
  }
}

__device__ __forceinline__ bf16x8 frag_ld(const u16* s, int row, int colb) {
  return *reinterpret_cast<const bf16x8*>(
      reinterpret_cast<const char*>(s) + row * 128 + (colb ^ ((row & 7) << 4)));
}

#define BAR_PRE()       do { asm volatile("s_waitcnt vmcnt(6)" ::: "memory"); \
                             __builtin_amdgcn_s_barrier(); \
                             asm volatile("" ::: "memory"); } while (0)
#define BAR_POST()      do { asm volatile("" ::: "memory"); \
                             __builtin_amdgcn_s_barrier(); \
                             asm volatile("" ::: "memory"); } while (0)

template<bool OUT_F32>
__global__ __launch_bounds__(512, 2) void gemm_nt256(
    const u16* __restrict__ A, long lda, long sAz4, long sAz1,
    const u16* __restrict__ B, long ldb, long sBz4, long sBz1,
    void* __restrict__ Cv, long ldc, long sCz4, long sCz1,
    long cBatch, int cShift,
    int K, float scale)
{
  __shared__ u16 sm[2 * 32768] __attribute__((aligned(16)));  // 128 KiB

  const int t = threadIdx.x;
  // T1: bijective XCD-chunked block swizzle (nwg % 8 == 0 for all our grids)
  int wg = blockIdx.x + gridDim.x * blockIdx.y;
  const int nwg = gridDim.x * gridDim.y;
  const int qq = nwg >> 3;
  wg = (wg & 7) * qq + (wg >> 3);
  const long m0 = (long)(wg % gridDim.x) * 256;
  const long n0 = (long)(wg / gridDim.x) * 256;
  const int z = blockIdx.z;
  const long azoff = (long)(z >> 2) * sAz4 + (long)(z & 3) * sAz1;
  const long bzoff = (long)(z >> 2) * sBz4 + (long)(z & 3) * sBz1;
  const u16* Ab = A + azoff + m0 * lda;
  const u16* Bb = B + bzoff + n0 * ldb;

  const int wid = t >> 6, lane = t & 63;
  const int lhi = lane >> 4, llo = lane & 15;
  const int wm = wid >> 2, wn = wid & 3;  // wave rows {wm*64, 128+wm*64}, cols {wn*32, 128+wn*32}

  f32x4 acc[2][4][2][2] = {};

  const int NT = K >> 6;

  // prologue, age order: A0(0), B1(0), B0(0), A1(0), A0(1), B1(1)
  stage_half(Ab, lda, 0, sm, t);
  stage_half(Bb + 128 * ldb, ldb, 0, sm + 16384 + 8192, t);
  stage_half(Bb, ldb, 0, sm + 16384, t);
  stage_half(Ab + 128 * lda, lda, 0, sm + 8192, t);
  stage_half(Ab, lda, 64, sm + 32768, t);
  stage_half(Bb + 128 * ldb, ldb, 64, sm + 32768 + 16384 + 8192, t);
  asm volatile("s_waitcnt vmcnt(4)" ::: "memory");  // tile0 done; A0(1),B1(1) in flight
  __builtin_amdgcn_s_barrier();
  asm volatile("" ::: "memory");

  for (int kt = 0; kt < NT; ++kt) {
    const int kb = kt & 1;
    u16* bc = sm + kb * 32768;          // current tile buffer
    u16* bn = sm + (kb ^ 1) * 32768;    // next tile buffer
    const u16* sAc = bc;
    const u16* sBc = bc + 16384;
    const int k1 = ((kt + 1 < NT) ? kt + 1 : 0) << 6;            // wrapped (dead) at tail
    const int k2 = ((kt + 2 < NT) ? kt + 2 : kt + 2 - NT) << 6;

    bf16x8 a[4][2], bl[2][2], bh[2][2];

    // ---- ph0: read A-lo(8) + B-lo(4); stage B0(t+1) -> bn; MFMA (Alo,Blo)
#pragma unroll
    for (int fr = 0; fr < 4; ++fr)
#pragma unroll
      for (int kk = 0; kk < 2; ++kk)
        a[fr][kk] = frag_ld(sAc, wm * 64 + fr * 16 + llo, (kk << 6) + (lhi << 4));
#pragma unroll
    for (int fc = 0; fc < 2; ++fc)
#pragma unroll
      for (int kk = 0; kk < 2; ++kk)
        bl[fc][kk] = frag_ld(sBc, wn * 32 + fc * 16 + llo, (kk << 6) + (lhi << 4));
    stage_half(Bb, ldb, k1, bn + 16384, t);
    BAR_PRE();
    __builtin_amdgcn_s_setprio(1);
#pragma unroll
    for (int fr = 0; fr < 4; ++fr)
#pragma unroll
      for (int fc = 0; fc < 2; ++fc)
#pragma unroll
        for (int kk = 0; kk < 2; ++kk)
          acc[0][fr][0][fc] = __builtin_amdgcn_mfma_f32_16x16x32_bf16(a[fr][kk], bl[fc][kk], acc[0][fr][0][fc], 0, 0, 0);
    __builtin_amdgcn_s_setprio(0);
    BAR_POST();

    // ---- ph1: read B-hi(4); stage A1(t+1) -> bn; MFMA (Alo,Bhi)
#pragma unroll
    for (int fc = 0; fc < 2; ++fc)
#pragma unroll
      for (int kk = 0; kk < 2; ++kk)
        bh[fc][kk] = frag_ld(sBc, 128 + wn * 32 + fc * 16 + llo, (kk << 6) + (lhi << 4));
    stage_half(Ab + 128 * lda, lda, k1, bn + 8192, t);
    BAR_PRE();
    __builtin_amdgcn_s_setprio(1);
#pragma unroll
    for (int fr = 0; fr < 4; ++fr)
#pragma unroll
      for (int fc = 0; fc < 2; ++fc)
#pragma unroll
        for (int kk = 0; kk < 2; ++kk)
          acc[0][fr][1][fc] = __builtin_amdgcn_mfma_f32_16x16x32_bf16(a[fr][kk], bh[fc][kk], acc[0][fr][1][fc], 0, 0, 0);
    __builtin_amdgcn_s_setprio(0);
    BAR_POST();

    // ---- ph2: read A-hi(8); stage A0(t+2) -> bc A-lo (dead); MFMA (Ahi,Bhi)
#pragma unroll
    for (int fr = 0; fr < 4; ++fr)
#pragma unroll
      for (int kk = 0; kk < 2; ++kk)
        a[fr][kk] = frag_ld(sAc, 128 + wm * 64 + fr * 16 + llo, (kk << 6) + (lhi << 4));
    stage_half(Ab, lda, k2, bc, t);
    BAR_PRE();
    __builtin_amdgcn_s_setprio(1);
#pragma unroll
    for (int fr = 0; fr < 4; ++fr)
#pragma unroll
      for (int fc = 0; fc < 2; ++fc)
#pragma unroll
        for (int kk = 0; kk < 2; ++kk)
          acc[1][fr][1][fc] = __builtin_amdgcn_mfma_f32_16x16x32_bf16(a[fr][kk], bh[fc][kk], acc[1][fr][1][fc], 0, 0, 0);
    __builtin_amdgcn_s_setprio(0);
    BAR_POST();

    // ---- ph3: stage B1(t+2) -> bc B-hi (dead); MFMA (Ahi,Blo)
    stage_half(Bb + 128 * ldb, ldb, k2, bc + 16384 + 8192, t);
    BAR_PRE();
    __builtin_amdgcn_s_setprio(1);
#pragma unroll
    for (int fr = 0; fr < 4; ++fr)
#pragma unroll
      for (int fc = 0; fc < 2; ++fc)
#pragma unroll
        for (int kk = 0; kk < 2; ++kk)
          acc[1][fr][0][fc] = __builtin_amdgcn_mfma_f32_16x16x32_bf16(a[fr][kk], bl[fc][kk], acc[1][fr][0][fc], 0, 0, 0);
    __builtin_amdgcn_s_setprio(0);
    BAR_POST();
  }

  // epilogue: C/D frag row=(lane>>4)*4+e, col=lane&15; column fold for chunked C
  const long cb = n0 >> cShift;
  const long ncol0 = n0 - (cb << cShift);
  const long czoff = (long)(z >> 2) * sCz4 + (long)(z & 3) * sCz1 + cb * cBatch;
#pragma unroll
  for (int ah = 0; ah < 2; ++ah)
#pragma unroll
    for (int fr = 0; fr < 4; ++fr)
#pragma unroll
      for (int e = 0; e < 4; ++e) {
        const long r = m0 + ah * 128 + wm * 64 + fr * 16 + lhi * 4 + e;
#pragma unroll
        for (int bh2 = 0; bh2 < 2; ++bh2)
#pragma unroll
          for (int fc = 0; fc < 2; ++fc) {
            const long col = ncol0 + bh2 * 128 + wn * 32 + fc * 16 + llo;
            const float val = acc[ah][fr][bh2][fc][e] * scale;
            if (OUT_F32)
              ((float*)Cv)[czoff + r * ldc + col] = val;
            else
              ((u16*)Cv)[czoff + r * ldc + col] = f2bf(val);
          }
      }
}

// ---- softmax over rows of att = sum of 4 split-K partials [16][1024][1024] f32 ----
__global__ __launch_bounds__(256) void softmax_reduce4(const float* __restrict__ att,
                                                       u16* __restrict__ P) {
  const long row = blockIdx.x;            // b*1024 + r
  const long b = row >> 10;
  const int t = threadIdx.x;
  float4 v; v.x = 0.f; v.y = 0.f; v.z = 0.f; v.w = 0.f;
#pragma unroll
  for (int p = 0; p < 4; ++p) {
    const float4 u = reinterpret_cast<const float4*>(att)[((b * 4 + p) << 18) + ((row & 1023) << 8) + t];
    v.x += u.x; v.y += u.y; v.z += u.z; v.w += u.w;
  }
  float m = fmaxf(fmaxf(v.x, v.y), fmaxf(v.z, v.w));
#pragma unroll
  for (int off = 32; off > 0; off >>= 1) m = fmaxf(m, __shfl_down(m, off, 64));
  __shared__ float smax[4], ssum[4];
  const int wid = t >> 6, lane = t & 63;
  if (lane == 0) smax[wid] = m;
  __syncthreads();
  m = fmaxf(fmaxf(smax[0], smax[1]), fmaxf(smax[2], smax[3]));
  float e0 = expf(v.x - m), e1 = expf(v.y - m), e2 = expf(v.z - m), e3 = expf(v.w - m);
  float s = e0 + e1 + e2 + e3;
#pragma unroll
  for (int off = 32; off > 0; off >>= 1) s += __shfl_down(s, off, 64);
  if (lane == 0) ssum[wid] = s;
  __syncthreads();
  s = ssum[0] + ssum[1] + ssum[2] + ssum[3];
  float inv = 1.0f / s;
  ushort4 o;
  o.x = f2bf(e0 * inv); o.y = f2bf(e1 * inv); o.z = f2bf(e2 * inv); o.w = f2bf(e3 * inv);
  reinterpret_cast<ushort4*>(P + row * 1024)[t] = o;
}

extern "C" void kernel_launch(void* const* d_in, const int* in_sizes, int n_in,
                              void* d_out, int out_size, void* d_ws, size_t ws_size,
                              hipStream_t stream) {
  const float* x  = (const float*)d_in[0];
  const float* Wq = (const float*)d_in[1];
  const float* Wk = (const float*)d_in[2];
  const float* Wv = (const float*)d_in[3];
  const float* Wo = (const float*)d_in[4];

  const long Bz = 4, L = 4096, E = 1024;
  const long BL = Bz * L;                 // 16384 tokens

  // workspace layout (u16 elements)
  u16* xbf   = (u16*)d_ws;                // [16384][1024]
  u16* wqk   = xbf + BL * E;              // [2048][1024]  (Wq rows 0-1023, Wk 1024-2047)
  u16* wv    = wqk + 2048L * 1024;        // [1024][1024]
  u16* wo    = wv + 1024L * 1024;         // [1024][1024]
  u16* qkhat = wo + 1024L * 1024;         // [16 chunks][2048][1024]: chunk=(b,p); rows 0-1023 = q-features, 1024-2047 = k-features; col = token%1024
  u16* vbuf  = qkhat + 32L * 1024 * 1024; // [16384][1024]
  // aliases (disjoint lifetimes):
  u16* P    = qkhat;                      // [4][1024][1024] bf16 (qkhat dead after stage 2)
  u16* outb = xbf;                        // [16384][1024] bf16 (xbf dead after stage 1b)
  float* attp = (float*)d_out;            // [16][1024][1024] f32 split-K partials (64 MB)

  dim3 b256(256), b512(512);
  const long NOF = 0;                     // no fold
  const int NSH = 30;

  // conversions
  cvt_f32_bf16<<<dim3((BL * E / 4 + 255) / 256), b256, 0, stream>>>(x, xbf, (int)(BL * E / 4));
  cvt_w4<<<dim3(4096), b256, 0, stream>>>(Wq, Wk, Wv, Wo,
                                          wqk, wqk + 1024L * 1024, wv, wo);

  // stage 1a (single dispatch): qkhat chunks = Wqk @ xbf^T
  // (M=2048, N=16384 folded by 1024-token chunks: addr = (n>>10)*2M + r*1024 + n%1024)
  gemm_nt256<false><<<dim3(8, 64, 1), b512, 0, stream>>>(
      wqk, 1024, 0, 0, xbf, 1024, 0, 0,
      (void*)qkhat, 1024, 0, 0, 2L << 20, 10, 1024, 1.0f);
  // stage 1b: v = xbf @ Wv^T  (M=16384, N=1024, K=1024)
  gemm_nt256<false><<<dim3(64, 4, 1), b512, 0, stream>>>(
      xbf, 1024, 0, 0, wv, 1024, 0, 0,
      (void*)vbuf, 1024, 0, 0, NOF, NSH, 1024, 1.0f);
  // stage 2: att partials; z=b*4+p: chunk at b*8M + p*2M; A=q rows, B=k rows (+1M)
  gemm_nt256<true><<<dim3(4, 4, 16), b512, 0, stream>>>(
      qkhat, 1024, 1L << 23, 1L << 21, qkhat + (1L << 20), 1024, 1L << 23, 1L << 21,
      (void*)attp, 1024, 4L << 20, 1L << 20, NOF, NSH, 1024, 1.0f / 32.0f);
  // stage 3: reduce partials + softmax -> P bf16
  softmax_reduce4<<<dim3(4096), b256, 0, stream>>>(attp, P);
  // stage 4: out[b] = v[b] @ P[b]^T  (M=4096, N=1024, K=1024, z=b)
  gemm_nt256<false><<<dim3(16, 4, 4), b512, 0, stream>>>(
      vbuf, 1024, 0, 1L << 22, P, 1024, 0, 1L << 20,
      (void*)outb, 1024, 0, 1L << 22, NOF, NSH, 1024, 1.0f);
  // stage 5: final = out @ Wo^T  (M=16384, N=1024, K=1024) -> d_out fp32
  gemm_nt256<true><<<dim3(64, 4, 1), b512, 0, stream>>>(
      outb, 1024, 0, 0, wo, 1024, 0, 0,
      d_out, 1024, 0, 0, NOF, NSH, 1024, 1.0f);
}

// Round 9
// 243.894 us; speedup vs baseline: 1.1637x; 1.1302x over previous
//
#include <hip/hip_runtime.h>
#include <hip/hip_bf16.h>

typedef unsigned short u16;
typedef __bf16 bf16x8 __attribute__((ext_vector_type(8)));
typedef float f32x4 __attribute__((ext_vector_type(4)));

#define AS1 __attribute__((address_space(1)))
#define AS3 __attribute__((address_space(3)))

__device__ inline u16 f2bf(float f) {
  union { float f; unsigned int u; } c; c.f = f;
  unsigned int u = c.u;
  return (u16)((u + 0x7fffu + ((u >> 16) & 1u)) >> 16);
}

// ---------------- fp32 -> bf16 conversion (x) ----------------
__global__ __launch_bounds__(256) void cvt_f32_bf16(const float* __restrict__ in,
                                                    u16* __restrict__ out, int n4) {
  int i = blockIdx.x * 256 + threadIdx.x;
  if (i >= n4) return;
  float4 v = reinterpret_cast<const float4*>(in)[i];
  ushort4 o;
  o.x = f2bf(v.x); o.y = f2bf(v.y); o.z = f2bf(v.z); o.w = f2bf(v.w);
  reinterpret_cast<ushort4*>(out)[i] = o;
}

// ---------------- fused conversion of the 4 weight matrices ----------------
__global__ __launch_bounds__(256) void cvt_w4(const float* __restrict__ a, const float* __restrict__ b,
                                              const float* __restrict__ c, const float* __restrict__ d,
                                              u16* __restrict__ oa, u16* __restrict__ ob,
                                              u16* __restrict__ oc, u16* __restrict__ od) {
  int i = blockIdx.x * 256 + threadIdx.x;   // 4 * 262144 float4 chunks
  const int which = i >> 18;
  const int j = i & 262143;
  const float* src = which == 0 ? a : which == 1 ? b : which == 2 ? c : d;
  u16* dst = which == 0 ? oa : which == 1 ? ob : which == 2 ? oc : od;
  float4 v = reinterpret_cast<const float4*>(src)[j];
  ushort4 o;
  o.x = f2bf(v.x); o.y = f2bf(v.y); o.z = f2bf(v.z); o.w = f2bf(v.w);
  reinterpret_cast<ushort4*>(dst)[j] = o;
}

// ---------------- bf16 tiled transpose: dst[c][r] = src[r][c] ----------------
// grid (srcCols/64, srcRows/64, Z)
__global__ __launch_bounds__(256) void transpose_bf16(
    const u16* __restrict__ src, long sLd, long sZ,
    u16* __restrict__ dst, long dLd, long dZ) {
  __shared__ u16 tile[64][68];            // row stride 136 B (8-aligned)
  const int t = threadIdx.x;
  const long r0 = (long)blockIdx.y * 64;
  const long c0 = (long)blockIdx.x * 64;
  const long z = blockIdx.z;
  const int tr = t >> 4, tc = t & 15;
#pragma unroll
  for (int i = 0; i < 4; ++i) {
    const int r = tr + i * 16;
    ushort4 v = *reinterpret_cast<const ushort4*>(src + z * sZ + (r0 + r) * sLd + c0 + tc * 4);
    *reinterpret_cast<ushort4*>(&tile[r][tc * 4]) = v;
  }
  __syncthreads();
#pragma unroll
  for (int i = 0; i < 4; ++i) {
    const int c = tr + i * 16;
    ushort4 o;
    o.x = tile[tc * 4 + 0][c]; o.y = tile[tc * 4 + 1][c];
    o.z = tile[tc * 4 + 2][c]; o.w = tile[tc * 4 + 3][c];
    *reinterpret_cast<ushort4*>(dst + z * dZ + (c0 + c) * dLd + r0 + tc * 4) = o;
  }
}

// ============ 256x256 NT GEMM, BK=64, 8 waves, 4-phase, vmcnt(6)/phase ========
// (R3/R8-proven engine, unchanged.)
__device__ __forceinline__ void stage_half(const u16* __restrict__ g, long ld, int k0,
                                           u16* dst, int t) {
#pragma unroll
  for (int i = 0; i < 2; ++i) {
    const int c = i * 512 + t;
    const int r = c >> 3;
    const int s = c & 7;
    const int col = ((s ^ (r & 7)) << 3) + k0;   // pre-swizzled global source
    __builtin_amdgcn_global_load_lds((const AS1 void*)(g + (long)r * ld + col),
                                     (AS3 void*)(dst + c * 8), 16, 0, 0);
  }
}

__device__ __forceinline__ bf16x8 frag_ld(const u16* s, int row, int colb) {
  return *reinterpret_cast<const bf16x8*>(
      reinterpret_cast<const char*>(s) + row * 128 + (colb ^ ((row & 7) << 4)));
}

#define BAR_PRE()       do { asm volatile("s_waitcnt vmcnt(6)" ::: "memory"); \
                             __builtin_amdgcn_s_barrier(); \
                             asm volatile("" ::: "memory"); } while (0)
#define BAR_POST()      do { asm volatile("" ::: "memory"); \
                             __builtin_amdgcn_s_barrier(); \
                             asm volatile("" ::: "memory"); } while (0)

template<bool OUT_F32>
__global__ __launch_bounds__(512, 2) void gemm_nt256(
    const u16* __restrict__ A, long lda, long sAz4, long sAz1,
    const u16* __restrict__ B, long ldb, long sBz4, long sBz1,
    void* __restrict__ Cv, long ldc, long sCz4, long sCz1,
    long cBatch, int cShift,
    int K, float scale)
{
  __shared__ u16 sm[2 * 32768] __attribute__((aligned(16)));  // 128 KiB

  const int t = threadIdx.x;
  int wg = blockIdx.x + gridDim.x * blockIdx.y;
  const int nwg = gridDim.x * gridDim.y;
  const int qq = nwg >> 3;
  wg = (wg & 7) * qq + (wg >> 3);
  const long m0 = (long)(wg % gridDim.x) * 256;
  const long n0 = (long)(wg / gridDim.x) * 256;
  const int z = blockIdx.z;
  const long azoff = (long)(z >> 2) * sAz4 + (long)(z & 3) * sAz1;
  const long bzoff = (long)(z >> 2) * sBz4 + (long)(z & 3) * sBz1;
  const u16* Ab = A + azoff + m0 * lda;
  const u16* Bb = B + bzoff + n0 * ldb;

  const int wid = t >> 6, lane = t & 63;
  const int lhi = lane >> 4, llo = lane & 15;
  const int wm = wid >> 2, wn = wid & 3;

  f32x4 acc[2][4][2][2] = {};
  const int NT = K >> 6;

  stage_half(Ab, lda, 0, sm, t);
  stage_half(Bb + 128 * ldb, ldb, 0, sm + 16384 + 8192, t);
  stage_half(Bb, ldb, 0, sm + 16384, t);
  stage_half(Ab + 128 * lda, lda, 0, sm + 8192, t);
  stage_half(Ab, lda, 64, sm + 32768, t);
  stage_half(Bb + 128 * ldb, ldb, 64, sm + 32768 + 16384 + 8192, t);
  asm volatile("s_waitcnt vmcnt(4)" ::: "memory");
  __builtin_amdgcn_s_barrier();
  asm volatile("" ::: "memory");

  for (int kt = 0; kt < NT; ++kt) {
    const int kb = kt & 1;
    u16* bc = sm + kb * 32768;
    u16* bn = sm + (kb ^ 1) * 32768;
    const u16* sAc = bc;
    const u16* sBc = bc + 16384;
    const int k1 = ((kt + 1 < NT) ? kt + 1 : 0) << 6;
    const int k2 = ((kt + 2 < NT) ? kt + 2 : kt + 2 - NT) << 6;

    bf16x8 a[4][2], bl[2][2], bh[2][2];

    // ph0
#pragma unroll
    for (int fr = 0; fr < 4; ++fr)
#pragma unroll
      for (int kk = 0; kk < 2; ++kk)
        a[fr][kk] = frag_ld(sAc, wm * 64 + fr * 16 + llo, (kk << 6) + (lhi << 4));
#pragma unroll
    for (int fc = 0; fc < 2; ++fc)
#pragma unroll
      for (int kk = 0; kk < 2; ++kk)
        bl[fc][kk] = frag_ld(sBc, wn * 32 + fc * 16 + llo, (kk << 6) + (lhi << 4));
    stage_half(Bb, ldb, k1, bn + 16384, t);
    BAR_PRE();
    __builtin_amdgcn_s_setprio(1);
#pragma unroll
    for (int fr = 0; fr < 4; ++fr)
#pragma unroll
      for (int fc = 0; fc < 2; ++fc)
#pragma unroll
        for (int kk = 0; kk < 2; ++kk)
          acc[0][fr][0][fc] = __builtin_amdgcn_mfma_f32_16x16x32_bf16(a[fr][kk], bl[fc][kk], acc[0][fr][0][fc], 0, 0, 0);
    __builtin_amdgcn_s_setprio(0);
    BAR_POST();

    // ph1
#pragma unroll
    for (int fc = 0; fc < 2; ++fc)
#pragma unroll
      for (int kk = 0; kk < 2; ++kk)
        bh[fc][kk] = frag_ld(sBc, 128 + wn * 32 + fc * 16 + llo, (kk << 6) + (lhi << 4));
    stage_half(Ab + 128 * lda, lda, k1, bn + 8192, t);
    BAR_PRE();
    __builtin_amdgcn_s_setprio(1);
#pragma unroll
    for (int fr = 0; fr < 4; ++fr)
#pragma unroll
      for (int fc = 0; fc < 2; ++fc)
#pragma unroll
        for (int kk = 0; kk < 2; ++kk)
          acc[0][fr][1][fc] = __builtin_amdgcn_mfma_f32_16x16x32_bf16(a[fr][kk], bh[fc][kk], acc[0][fr][1][fc], 0, 0, 0);
    __builtin_amdgcn_s_setprio(0);
    BAR_POST();

    // ph2
#pragma unroll
    for (int fr = 0; fr < 4; ++fr)
#pragma unroll
      for (int kk = 0; kk < 2; ++kk)
        a[fr][kk] = frag_ld(sAc, 128 + wm * 64 + fr * 16 + llo, (kk << 6) + (lhi << 4));
    stage_half(Ab, lda, k2, bc, t);
    BAR_PRE();
    __builtin_amdgcn_s_setprio(1);
#pragma unroll
    for (int fr = 0; fr < 4; ++fr)
#pragma unroll
      for (int fc = 0; fc < 2; ++fc)
#pragma unroll
        for (int kk = 0; kk < 2; ++kk)
          acc[1][fr][1][fc] = __builtin_amdgcn_mfma_f32_16x16x32_bf16(a[fr][kk], bh[fc][kk], acc[1][fr][1][fc], 0, 0, 0);
    __builtin_amdgcn_s_setprio(0);
    BAR_POST();

    // ph3
    stage_half(Bb + 128 * ldb, ldb, k2, bc + 16384 + 8192, t);
    BAR_PRE();
    __builtin_amdgcn_s_setprio(1);
#pragma unroll
    for (int fr = 0; fr < 4; ++fr)
#pragma unroll
      for (int fc = 0; fc < 2; ++fc)
#pragma unroll
        for (int kk = 0; kk < 2; ++kk)
          acc[1][fr][0][fc] = __builtin_amdgcn_mfma_f32_16x16x32_bf16(a[fr][kk], bl[fc][kk], acc[1][fr][0][fc], 0, 0, 0);
    __builtin_amdgcn_s_setprio(0);
    BAR_POST();
  }

  const long cb = n0 >> cShift;
  const long ncol0 = n0 - (cb << cShift);
  const long czoff = (long)(z >> 2) * sCz4 + (long)(z & 3) * sCz1 + cb * cBatch;
#pragma unroll
  for (int ah = 0; ah < 2; ++ah)
#pragma unroll
    for (int fr = 0; fr < 4; ++fr)
#pragma unroll
      for (int e = 0; e < 4; ++e) {
        const long r = m0 + ah * 128 + wm * 64 + fr * 16 + lhi * 4 + e;
#pragma unroll
        for (int bh2 = 0; bh2 < 2; ++bh2)
#pragma unroll
          for (int fc = 0; fc < 2; ++fc) {
            const long col = ncol0 + bh2 * 128 + wn * 32 + fc * 16 + llo;
            const float val = acc[ah][fr][bh2][fc][e] * scale;
            if (OUT_F32)
              ((float*)Cv)[czoff + r * ldc + col] = val;
            else
              ((u16*)Cv)[czoff + r * ldc + col] = f2bf(val);
          }
      }
}

// ============ 128x128 NT GEMM, BK=32, 4 waves (R1-proven + T2 swizzle) ========
// For small 1024^3 batched GEMMs (grid 8x8xZ = full machine at 1 block/CU x3).
__device__ __forceinline__ bf16x8 frag_ld128(const u16* s, int row, int lhi) {
  return *reinterpret_cast<const bf16x8*>(
      reinterpret_cast<const char*>(s) + row * 64 + ((lhi ^ (row & 3)) << 4));
}

template<bool OUT_F32>
__global__ __launch_bounds__(256) void gemm_nt128(
    const u16* __restrict__ A, long lda, long sAz,
    const u16* __restrict__ B, long ldb, long sBz,
    void* __restrict__ Cv, long ldc, long sCz,
    int K, float scale)
{
  __shared__ u16 sm[2 * 128 * 32] __attribute__((aligned(16)));
  u16* sA = sm;
  u16* sB = sm + 128 * 32;

  const int t = threadIdx.x;
  int wg = blockIdx.x + gridDim.x * blockIdx.y;
  const int nwg = gridDim.x * gridDim.y;
  const int qq = nwg >> 3;
  wg = (wg & 7) * qq + (wg >> 3);
  const long m0 = (long)(wg % gridDim.x) * 128;
  const long n0 = (long)(wg / gridDim.x) * 128;
  const int z = blockIdx.z;
  A += (long)z * sAz + m0 * lda;
  B += (long)z * sBz + n0 * ldb;

  const int wid = t >> 6, lane = t & 63;
  const int lhi = lane >> 4, llo = lane & 15;
  const int wr = (wid >> 1) * 64, wc = (wid & 1) * 64;
  const int srow = t >> 2;          // 0..63 within 64-row half
  const int scol = t & 3;           // 16B chunk within 32-wide K slab

  f32x4 acc[4][4] = {};

  for (int k0 = 0; k0 < K; k0 += 32) {
#pragma unroll
    for (int c = 0; c < 2; ++c) {
      const int row = c * 64 + srow;
      const int col = ((scol ^ (row & 3)) << 3) + k0;   // pre-swizzled source
      __builtin_amdgcn_global_load_lds((const AS1 void*)(A + (long)row * lda + col),
                                       (AS3 void*)(sA + (c * 256 + t) * 8), 16, 0, 0);
      __builtin_amdgcn_global_load_lds((const AS1 void*)(B + (long)row * ldb + col),
                                       (AS3 void*)(sB + (c * 256 + t) * 8), 16, 0, 0);
    }
    __syncthreads();

    bf16x8 af[4], bfr[4];
#pragma unroll
    for (int i = 0; i < 4; ++i)
      af[i] = frag_ld128(sA, wr + i * 16 + llo, lhi);
#pragma unroll
    for (int j = 0; j < 4; ++j)
      bfr[j] = frag_ld128(sB, wc + j * 16 + llo, lhi);

#pragma unroll
    for (int i = 0; i < 4; ++i)
#pragma unroll
      for (int j = 0; j < 4; ++j)
        acc[i][j] = __builtin_amdgcn_mfma_f32_16x16x32_bf16(af[i], bfr[j], acc[i][j], 0, 0, 0);
    __syncthreads();
  }

#pragma unroll
  for (int i = 0; i < 4; ++i) {
#pragma unroll
    for (int e = 0; e < 4; ++e) {
      const long r = m0 + wr + i * 16 + lhi * 4 + e;
      if (OUT_F32) {
        float* C = (float*)Cv + (long)z * sCz + r * ldc + n0 + wc + llo;
#pragma unroll
        for (int j = 0; j < 4; ++j) C[j * 16] = acc[i][j][e] * scale;
      } else {
        u16* C = (u16*)Cv + (long)z * sCz + r * ldc + n0 + wc + llo;
#pragma unroll
        for (int j = 0; j < 4; ++j) C[j * 16] = f2bf(acc[i][j][e] * scale);
      }
    }
  }
}

// ---- reduce 4 split-K f32 partials of G -> bf16 [4][1024][1024] ----
__global__ __launch_bounds__(256) void greduce4(const float* __restrict__ gp,
                                                u16* __restrict__ gb) {
  const long i = (long)blockIdx.x * 256 + threadIdx.x;   // 1,048,576 float4
  const long b = i >> 18;
  const long r = i & 262143;
  float4 s; s.x = 0.f; s.y = 0.f; s.z = 0.f; s.w = 0.f;
#pragma unroll
  for (int p = 0; p < 4; ++p) {
    const float4 u = reinterpret_cast<const float4*>(gp)[((b * 4 + p) << 18) + r];
    s.x += u.x; s.y += u.y; s.z += u.z; s.w += u.w;
  }
  ushort4 o;
  o.x = f2bf(s.x); o.y = f2bf(s.y); o.z = f2bf(s.z); o.w = f2bf(s.w);
  reinterpret_cast<ushort4*>(gb)[(b << 18) + r] = o;
}

// ---- single-pass row softmax: att f32 [4096][1024] -> P bf16 ----
__global__ __launch_bounds__(256) void softmax1(const float* __restrict__ att,
                                                u16* __restrict__ P) {
  const long row = blockIdx.x;
  const int t = threadIdx.x;
  float4 v = reinterpret_cast<const float4*>(att + row * 1024)[t];
  float m = fmaxf(fmaxf(v.x, v.y), fmaxf(v.z, v.w));
#pragma unroll
  for (int off = 32; off > 0; off >>= 1) m = fmaxf(m, __shfl_down(m, off, 64));
  __shared__ float smax[4], ssum[4];
  const int wid = t >> 6, lane = t & 63;
  if (lane == 0) smax[wid] = m;
  __syncthreads();
  m = fmaxf(fmaxf(smax[0], smax[1]), fmaxf(smax[2], smax[3]));
  float e0 = expf(v.x - m), e1 = expf(v.y - m), e2 = expf(v.z - m), e3 = expf(v.w - m);
  float s = e0 + e1 + e2 + e3;
#pragma unroll
  for (int off = 32; off > 0; off >>= 1) s += __shfl_down(s, off, 64);
  if (lane == 0) ssum[wid] = s;
  __syncthreads();
  s = ssum[0] + ssum[1] + ssum[2] + ssum[3];
  float inv = 1.0f / s;
  ushort4 o;
  o.x = f2bf(e0 * inv); o.y = f2bf(e1 * inv); o.z = f2bf(e2 * inv); o.w = f2bf(e3 * inv);
  reinterpret_cast<ushort4*>(P + row * 1024)[t] = o;
}

extern "C" void kernel_launch(void* const* d_in, const int* in_sizes, int n_in,
                              void* d_out, int out_size, void* d_ws, size_t ws_size,
                              hipStream_t stream) {
  const float* x  = (const float*)d_in[0];
  const float* Wq = (const float*)d_in[1];
  const float* Wk = (const float*)d_in[2];
  const float* Wv = (const float*)d_in[3];
  const float* Wo = (const float*)d_in[4];

  const long M1 = 1L << 20;               // 1M elements

  // workspace layout (u16 elements), 114 MB total
  u16* xbf  = (u16*)d_ws;                 // [16384][1024]                      16M
  u16* wq   = xbf + 16 * M1;              // [1024][1024]                        1M
  u16* wk   = wq + M1;                    //                                     1M
  u16* wv   = wk + M1;                    //                                     1M
  u16* wo   = wv + M1;                    //                                     1M
  u16* wvT  = wo + M1;                    // Wv^T                                1M
  u16* xT   = wvT + M1;                   // [4][1024 feat][4096 tok]           16M
  u16* gbf  = xT + 16 * M1;               // G bf16 [4][1024][1024]              4M
  u16* tbuf = gbf + 4 * M1;               // T~ = Wq G                           4M
  u16* pbuf = tbuf + 4 * M1;              // P (softmax)                         4M
  u16* rtb  = pbuf + 4 * M1;              // R^T = WvT x P                       4M
  u16* sbuf = rtb + 4 * M1;               // S = Wo R                            4M
  float* gpart = (float*)d_out;           // G split-K partials [16][1024][1024] f32 (64 MB)
  float* attf  = (float*)d_out;           // att f32 [4][1024][1024] (16 MB, after gpart dead)

  dim3 b256(256), b512(512);
  const long NOF = 0;
  const int NSH = 30;

  // conversions + transposes
  cvt_f32_bf16<<<dim3(16384), b256, 0, stream>>>(x, xbf, 16384 * 256);
  cvt_w4<<<dim3(4096), b256, 0, stream>>>(Wq, Wk, Wv, Wo, wq, wk, wv, wo);
  transpose_bf16<<<dim3(16, 16, 1), b256, 0, stream>>>(wv, 1024, 0, wvT, 1024, 0);
  transpose_bf16<<<dim3(16, 64, 4), b256, 0, stream>>>(xbf, 1024, 4096L * 1024, xT, 4096, 1024L * 4096);

  // G[b] = x[b]^T x[b]  (M=N=1024, K=4096 split into 4; z=b*4+p) -> f32 partials in d_out
  gemm_nt256<true><<<dim3(4, 4, 16), b512, 0, stream>>>(
      xT, 4096, 1024L * 4096, 1024, xT, 4096, 1024L * 4096, 1024,
      (void*)gpart, 1024, 4L << 20, 1L << 20, NOF, NSH, 1024, 1.0f);
  greduce4<<<dim3(4096), b256, 0, stream>>>(gpart, gbf);

  // T~[b] = Wq G[b]   (G symmetric -> NT form)
  gemm_nt128<false><<<dim3(8, 8, 4), b256, 0, stream>>>(
      wq, 1024, 0, gbf, 1024, M1, (void*)tbuf, 1024, M1, 1024, 1.0f);
  // att[b] = T~[b] Wk^T / 32 -> f32 [4][1024][1024] in d_out
  gemm_nt128<true><<<dim3(8, 8, 4), b256, 0, stream>>>(
      tbuf, 1024, M1, wk, 1024, 0, (void*)attf, 1024, M1, 1024, 1.0f / 32.0f);
  // softmax rows -> P bf16
  softmax1<<<dim3(4096), b256, 0, stream>>>(attf, pbuf);

  // R^T[b] = WvT . P[b]^T-contraction: C[e,k] = sum_j Wv[j,e] P[k,j]
  gemm_nt128<false><<<dim3(8, 8, 4), b256, 0, stream>>>(
      wvT, 1024, 0, pbuf, 1024, M1, (void*)rtb, 1024, M1, 1024, 1.0f);
  // S[b] = Wo . R[b]: C[e',e] = sum_k Wo[e',k] RT[e,k]
  gemm_nt128<false><<<dim3(8, 8, 4), b256, 0, stream>>>(
      wo, 1024, 0, rtb, 1024, M1, (void*)sbuf, 1024, M1, 1024, 1.0f);

  // final[b] = x[b] S[b]^T  (M=4096/batch, N=1024, K=1024) -> d_out f32
  gemm_nt256<true><<<dim3(16, 4, 4), b512, 0, stream>>>(
      xbf, 1024, 0, 4096L * 1024, sbuf, 1024, 0, M1,
      d_out, 1024, 0, 4096L * 1024, NOF, NSH, 1024, 1.0f);
}

// Round 10
// 220.273 us; speedup vs baseline: 1.2885x; 1.1072x over previous
//
#include <hip/hip_runtime.h>
#include <hip/hip_bf16.h>

typedef unsigned short u16;
typedef __bf16 bf16x8 __attribute__((ext_vector_type(8)));
typedef float f32x4 __attribute__((ext_vector_type(4)));

#define AS1 __attribute__((address_space(1)))
#define AS3 __attribute__((address_space(3)))

__device__ inline u16 f2bf(float f) {
  union { float f; unsigned int u; } c; c.f = f;
  unsigned int u = c.u;
  return (u16)((u + 0x7fffu + ((u >> 16) & 1u)) >> 16);
}

// ---------------- fused x conversion + transpose ----------------
// reads x f32 [4][4096][1024]; writes xbf [16384][1024] and xT [4][1024][4096]
__global__ __launch_bounds__(256) void cvt_x_dual(const float* __restrict__ x,
                                                  u16* __restrict__ xbf,
                                                  u16* __restrict__ xT) {
  __shared__ u16 tile[64][68];
  const int t = threadIdx.x;
  const long e0 = (long)blockIdx.x * 64;     // feature tile
  const long l0 = (long)blockIdx.y * 64;     // token tile within batch
  const long b  = blockIdx.z;
  const int tr = t >> 4, tc = t & 15;
#pragma unroll
  for (int i = 0; i < 4; ++i) {
    const int r = tr + i * 16;
    const long gl = b * 4096 + l0 + r;
    float4 v = *reinterpret_cast<const float4*>(x + gl * 1024 + e0 + tc * 4);
    ushort4 o;
    o.x = f2bf(v.x); o.y = f2bf(v.y); o.z = f2bf(v.z); o.w = f2bf(v.w);
    *reinterpret_cast<ushort4*>(xbf + gl * 1024 + e0 + tc * 4) = o;
    *reinterpret_cast<ushort4*>(&tile[r][tc * 4]) = o;
  }
  __syncthreads();
#pragma unroll
  for (int i = 0; i < 4; ++i) {
    const int c = tr + i * 16;
    ushort4 o;
    o.x = tile[tc * 4 + 0][c]; o.y = tile[tc * 4 + 1][c];
    o.z = tile[tc * 4 + 2][c]; o.w = tile[tc * 4 + 3][c];
    *reinterpret_cast<ushort4*>(xT + b * (1024L * 4096) + (e0 + c) * 4096 + l0 + tc * 4) = o;
  }
}

// ---------------- fused conversion of the 4 weight matrices ----------------
__global__ __launch_bounds__(256) void cvt_w4(const float* __restrict__ a, const float* __restrict__ b,
                                              const float* __restrict__ c, const float* __restrict__ d,
                                              u16* __restrict__ oa, u16* __restrict__ ob,
                                              u16* __restrict__ oc, u16* __restrict__ od) {
  int i = blockIdx.x * 256 + threadIdx.x;   // 4 * 262144 float4 chunks
  const int which = i >> 18;
  const int j = i & 262143;
  const float* src = which == 0 ? a : which == 1 ? b : which == 2 ? c : d;
  u16* dst = which == 0 ? oa : which == 1 ? ob : which == 2 ? oc : od;
  float4 v = reinterpret_cast<const float4*>(src)[j];
  ushort4 o;
  o.x = f2bf(v.x); o.y = f2bf(v.y); o.z = f2bf(v.z); o.w = f2bf(v.w);
  reinterpret_cast<ushort4*>(dst)[j] = o;
}

// ---------------- bf16 tiled transpose: dst[c][r] = src[r][c] ----------------
__global__ __launch_bounds__(256) void transpose_bf16(
    const u16* __restrict__ src, long sLd, long sZ,
    u16* __restrict__ dst, long dLd, long dZ) {
  __shared__ u16 tile[64][68];
  const int t = threadIdx.x;
  const long r0 = (long)blockIdx.y * 64;
  const long c0 = (long)blockIdx.x * 64;
  const long z = blockIdx.z;
  const int tr = t >> 4, tc = t & 15;
#pragma unroll
  for (int i = 0; i < 4; ++i) {
    const int r = tr + i * 16;
    ushort4 v = *reinterpret_cast<const ushort4*>(src + z * sZ + (r0 + r) * sLd + c0 + tc * 4);
    *reinterpret_cast<ushort4*>(&tile[r][tc * 4]) = v;
  }
  __syncthreads();
#pragma unroll
  for (int i = 0; i < 4; ++i) {
    const int c = tr + i * 16;
    ushort4 o;
    o.x = tile[tc * 4 + 0][c]; o.y = tile[tc * 4 + 1][c];
    o.z = tile[tc * 4 + 2][c]; o.w = tile[tc * 4 + 3][c];
    *reinterpret_cast<ushort4*>(dst + z * dZ + (c0 + c) * dLd + r0 + tc * 4) = o;
  }
}

// ============ 256x256 NT GEMM, BK=64, 8 waves, 4-phase, vmcnt(6)/phase ========
// (R3/R8-proven engine, unchanged.)
__device__ __forceinline__ void stage_half(const u16* __restrict__ g, long ld, int k0,
                                           u16* dst, int t) {
#pragma unroll
  for (int i = 0; i < 2; ++i) {
    const int c = i * 512 + t;
    const int r = c >> 3;
    const int s = c & 7;
    const int col = ((s ^ (r & 7)) << 3) + k0;   // pre-swizzled global source
    __builtin_amdgcn_global_load_lds((const AS1 void*)(g + (long)r * ld + col),
                                     (AS3 void*)(dst + c * 8), 16, 0, 0);
  }
}

__device__ __forceinline__ bf16x8 frag_ld(const u16* s, int row, int colb) {
  return *reinterpret_cast<const bf16x8*>(
      reinterpret_cast<const char*>(s) + row * 128 + (colb ^ ((row & 7) << 4)));
}

#define BAR_PRE()       do { asm volatile("s_waitcnt vmcnt(6)" ::: "memory"); \
                             __builtin_amdgcn_s_barrier(); \
                             asm volatile("" ::: "memory"); } while (0)
#define BAR_POST()      do { asm volatile("" ::: "memory"); \
                             __builtin_amdgcn_s_barrier(); \
                             asm volatile("" ::: "memory"); } while (0)

template<bool OUT_F32>
__global__ __launch_bounds__(512, 2) void gemm_nt256(
    const u16* __restrict__ A, long lda, long sAz4, long sAz1,
    const u16* __restrict__ B, long ldb, long sBz4, long sBz1,
    void* __restrict__ Cv, long ldc, long sCz4, long sCz1,
    long cBatch, int cShift,
    int K, float scale)
{
  __shared__ u16 sm[2 * 32768] __attribute__((aligned(16)));  // 128 KiB

  const int t = threadIdx.x;
  int wg = blockIdx.x + gridDim.x * blockIdx.y;
  const int nwg = gridDim.x * gridDim.y;
  const int qq = nwg >> 3;
  wg = (wg & 7) * qq + (wg >> 3);
  const long m0 = (long)(wg % gridDim.x) * 256;
  const long n0 = (long)(wg / gridDim.x) * 256;
  const int z = blockIdx.z;
  const long azoff = (long)(z >> 2) * sAz4 + (long)(z & 3) * sAz1;
  const long bzoff = (long)(z >> 2) * sBz4 + (long)(z & 3) * sBz1;
  const u16* Ab = A + azoff + m0 * lda;
  const u16* Bb = B + bzoff + n0 * ldb;

  const int wid = t >> 6, lane = t & 63;
  const int lhi = lane >> 4, llo = lane & 15;
  const int wm = wid >> 2, wn = wid & 3;

  f32x4 acc[2][4][2][2] = {};
  const int NT = K >> 6;

  stage_half(Ab, lda, 0, sm, t);
  stage_half(Bb + 128 * ldb, ldb, 0, sm + 16384 + 8192, t);
  stage_half(Bb, ldb, 0, sm + 16384, t);
  stage_half(Ab + 128 * lda, lda, 0, sm + 8192, t);
  stage_half(Ab, lda, 64, sm + 32768, t);
  stage_half(Bb + 128 * ldb, ldb, 64, sm + 32768 + 16384 + 8192, t);
  asm volatile("s_waitcnt vmcnt(4)" ::: "memory");
  __builtin_amdgcn_s_barrier();
  asm volatile("" ::: "memory");

  for (int kt = 0; kt < NT; ++kt) {
    const int kb = kt & 1;
    u16* bc = sm + kb * 32768;
    u16* bn = sm + (kb ^ 1) * 32768;
    const u16* sAc = bc;
    const u16* sBc = bc + 16384;
    const int k1 = ((kt + 1 < NT) ? kt + 1 : 0) << 6;
    const int k2 = ((kt + 2 < NT) ? kt + 2 : kt + 2 - NT) << 6;

    bf16x8 a[4][2], bl[2][2], bh[2][2];

    // ph0
#pragma unroll
    for (int fr = 0; fr < 4; ++fr)
#pragma unroll
      for (int kk = 0; kk < 2; ++kk)
        a[fr][kk] = frag_ld(sAc, wm * 64 + fr * 16 + llo, (kk << 6) + (lhi << 4));
#pragma unroll
    for (int fc = 0; fc < 2; ++fc)
#pragma unroll
      for (int kk = 0; kk < 2; ++kk)
        bl[fc][kk] = frag_ld(sBc, wn * 32 + fc * 16 + llo, (kk << 6) + (lhi << 4));
    stage_half(Bb, ldb, k1, bn + 16384, t);
    BAR_PRE();
    __builtin_amdgcn_s_setprio(1);
#pragma unroll
    for (int fr = 0; fr < 4; ++fr)
#pragma unroll
      for (int fc = 0; fc < 2; ++fc)
#pragma unroll
        for (int kk = 0; kk < 2; ++kk)
          acc[0][fr][0][fc] = __builtin_amdgcn_mfma_f32_16x16x32_bf16(a[fr][kk], bl[fc][kk], acc[0][fr][0][fc], 0, 0, 0);
    __builtin_amdgcn_s_setprio(0);
    BAR_POST();

    // ph1
#pragma unroll
    for (int fc = 0; fc < 2; ++fc)
#pragma unroll
      for (int kk = 0; kk < 2; ++kk)
        bh[fc][kk] = frag_ld(sBc, 128 + wn * 32 + fc * 16 + llo, (kk << 6) + (lhi << 4));
    stage_half(Ab + 128 * lda, lda, k1, bn + 8192, t);
    BAR_PRE();
    __builtin_amdgcn_s_setprio(1);
#pragma unroll
    for (int fr = 0; fr < 4; ++fr)
#pragma unroll
      for (int fc = 0; fc < 2; ++fc)
#pragma unroll
        for (int kk = 0; kk < 2; ++kk)
          acc[0][fr][1][fc] = __builtin_amdgcn_mfma_f32_16x16x32_bf16(a[fr][kk], bh[fc][kk], acc[0][fr][1][fc], 0, 0, 0);
    __builtin_amdgcn_s_setprio(0);
    BAR_POST();

    // ph2
#pragma unroll
    for (int fr = 0; fr < 4; ++fr)
#pragma unroll
      for (int kk = 0; kk < 2; ++kk)
        a[fr][kk] = frag_ld(sAc, 128 + wm * 64 + fr * 16 + llo, (kk << 6) + (lhi << 4));
    stage_half(Ab, lda, k2, bc, t);
    BAR_PRE();
    __builtin_amdgcn_s_setprio(1);
#pragma unroll
    for (int fr = 0; fr < 4; ++fr)
#pragma unroll
      for (int fc = 0; fc < 2; ++fc)
#pragma unroll
        for (int kk = 0; kk < 2; ++kk)
          acc[1][fr][1][fc] = __builtin_amdgcn_mfma_f32_16x16x32_bf16(a[fr][kk], bh[fc][kk], acc[1][fr][1][fc], 0, 0, 0);
    __builtin_amdgcn_s_setprio(0);
    BAR_POST();

    // ph3
    stage_half(Bb + 128 * ldb, ldb, k2, bc + 16384 + 8192, t);
    BAR_PRE();
    __builtin_amdgcn_s_setprio(1);
#pragma unroll
    for (int fr = 0; fr < 4; ++fr)
#pragma unroll
      for (int fc = 0; fc < 2; ++fc)
#pragma unroll
        for (int kk = 0; kk < 2; ++kk)
          acc[1][fr][0][fc] = __builtin_amdgcn_mfma_f32_16x16x32_bf16(a[fr][kk], bl[fc][kk], acc[1][fr][0][fc], 0, 0, 0);
    __builtin_amdgcn_s_setprio(0);
    BAR_POST();
  }

  const long cb = n0 >> cShift;
  const long ncol0 = n0 - (cb << cShift);
  const long czoff = (long)(z >> 2) * sCz4 + (long)(z & 3) * sCz1 + cb * cBatch;
#pragma unroll
  for (int ah = 0; ah < 2; ++ah)
#pragma unroll
    for (int fr = 0; fr < 4; ++fr)
#pragma unroll
      for (int e = 0; e < 4; ++e) {
        const long r = m0 + ah * 128 + wm * 64 + fr * 16 + lhi * 4 + e;
#pragma unroll
        for (int bh2 = 0; bh2 < 2; ++bh2)
#pragma unroll
          for (int fc = 0; fc < 2; ++fc) {
            const long col = ncol0 + bh2 * 128 + wn * 32 + fc * 16 + llo;
            const float val = acc[ah][fr][bh2][fc][e] * scale;
            if (OUT_F32)
              ((float*)Cv)[czoff + r * ldc + col] = val;
            else
              ((u16*)Cv)[czoff + r * ldc + col] = f2bf(val);
          }
      }
}

// ===== 128x128 NT GEMM, BK=32, 4 waves, TRIPLE-buffered counted-vmcnt =====
// For small 1024^3 batched GEMMs. Depth-2 prefetch: prologue stages tiles
// 0,1,2; per iter: vmcnt(8) retires tile kt (kt+1,kt+2 stay in flight across
// both barriers) -> barrier -> ds_read+MFMA buf[kt%3] -> barrier -> stage
// kt+3 into buf[kt%3] (wrapped-dead at tail; counts stay uniform). NT >= 3.
__device__ __forceinline__ bf16x8 frag_ld128(const u16* s, int row, int lhi) {
  return *reinterpret_cast<const bf16x8*>(
      reinterpret_cast<const char*>(s) + row * 64 + ((lhi ^ (row & 3)) << 4));
}

template<bool OUT_F32>
__global__ __launch_bounds__(256) void gemm_nt128p(
    const u16* __restrict__ A, long lda, long sAz,
    const u16* __restrict__ B, long ldb, long sBz,
    void* __restrict__ Cv, long ldc, long sCz,
    int K, float scale)
{
  __shared__ u16 sm[3 * 8192] __attribute__((aligned(16)));  // 48 KiB

  const int t = threadIdx.x;
  int wg = blockIdx.x + gridDim.x * blockIdx.y;
  const int nwg = gridDim.x * gridDim.y;
  const int qq = nwg >> 3;
  wg = (wg & 7) * qq + (wg >> 3);
  const long m0 = (long)(wg % gridDim.x) * 128;
  const long n0 = (long)(wg / gridDim.x) * 128;
  const int z = blockIdx.z;
  A += (long)z * sAz + m0 * lda;
  B += (long)z * sBz + n0 * ldb;

  const int wid = t >> 6, lane = t & 63;
  const int lhi = lane >> 4, llo = lane & 15;
  const int wr = (wid >> 1) * 64, wc = (wid & 1) * 64;
  const int srow = t >> 2;
  const int scol = t & 3;

  f32x4 acc[4][4] = {};
  const int NT = K >> 5;   // >= 3

#define STAGE128(kk, buf)                                                              \
  do {                                                                                 \
    _Pragma("unroll")                                                                  \
    for (int c = 0; c < 2; ++c) {                                                      \
      const int row = c * 64 + srow;                                                   \
      const int col = ((scol ^ (row & 3)) << 3) + (kk);                                \
      __builtin_amdgcn_global_load_lds((const AS1 void*)(A + (long)row * lda + col),   \
                                       (AS3 void*)((buf) + (c * 256 + t) * 8), 16, 0, 0); \
      __builtin_amdgcn_global_load_lds((const AS1 void*)(B + (long)row * ldb + col),   \
                                       (AS3 void*)((buf) + 4096 + (c * 256 + t) * 8), 16, 0, 0); \
    }                                                                                  \
  } while (0)

  STAGE128(0, sm);
  STAGE128(32, sm + 8192);
  STAGE128(64, sm + 16384);

  for (int kt = 0; kt < NT; ++kt) {
    asm volatile("s_waitcnt vmcnt(8)" ::: "memory");   // tile kt resident
    __builtin_amdgcn_s_barrier();
    asm volatile("" ::: "memory");
    u16* buf = sm + (kt % 3) * 8192;
    const u16* sA = buf;
    const u16* sB = buf + 4096;
    bf16x8 af[4], bfr[4];
#pragma unroll
    for (int i = 0; i < 4; ++i) af[i] = frag_ld128(sA, wr + i * 16 + llo, lhi);
#pragma unroll
    for (int j = 0; j < 4; ++j) bfr[j] = frag_ld128(sB, wc + j * 16 + llo, lhi);
    __builtin_amdgcn_s_setprio(1);
#pragma unroll
    for (int i = 0; i < 4; ++i)
#pragma unroll
      for (int j = 0; j < 4; ++j)
        acc[i][j] = __builtin_amdgcn_mfma_f32_16x16x32_bf16(af[i], bfr[j], acc[i][j], 0, 0, 0);
    __builtin_amdgcn_s_setprio(0);
    asm volatile("" ::: "memory");
    __builtin_amdgcn_s_barrier();
    asm volatile("" ::: "memory");
    const int k3 = ((kt + 3 < NT) ? kt + 3 : kt + 3 - NT) << 5;   // wrapped-dead at tail
    STAGE128(k3, buf);
  }

#pragma unroll
  for (int i = 0; i < 4; ++i) {
#pragma unroll
    for (int e = 0; e < 4; ++e) {
      const long r = m0 + wr + i * 16 + lhi * 4 + e;
      if (OUT_F32) {
        float* C = (float*)Cv + (long)z * sCz + r * ldc + n0 + wc + llo;
#pragma unroll
        for (int j = 0; j < 4; ++j) C[j * 16] = acc[i][j][e] * scale;
      } else {
        u16* C = (u16*)Cv + (long)z * sCz + r * ldc + n0 + wc + llo;
#pragma unroll
        for (int j = 0; j < 4; ++j) C[j * 16] = f2bf(acc[i][j][e] * scale);
      }
    }
  }
}

// ---- reduce 4 split-K f32 partials of G -> bf16 [4][1024][1024] ----
__global__ __launch_bounds__(256) void greduce4(const float* __restrict__ gp,
                                                u16* __restrict__ gb) {
  const long i = (long)blockIdx.x * 256 + threadIdx.x;
  const long b = i >> 18;
  const long r = i & 262143;
  float4 s; s.x = 0.f; s.y = 0.f; s.z = 0.f; s.w = 0.f;
#pragma unroll
  for (int p = 0; p < 4; ++p) {
    const float4 u = reinterpret_cast<const float4*>(gp)[((b * 4 + p) << 18) + r];
    s.x += u.x; s.y += u.y; s.z += u.z; s.w += u.w;
  }
  ushort4 o;
  o.x = f2bf(s.x); o.y = f2bf(s.y); o.z = f2bf(s.z); o.w = f2bf(s.w);
  reinterpret_cast<ushort4*>(gb)[(b << 18) + r] = o;
}

// ---- single-pass row softmax: att f32 [4096][1024] -> P bf16 ----
__global__ __launch_bounds__(256) void softmax1(const float* __restrict__ att,
                                                u16* __restrict__ P) {
  const long row = blockIdx.x;
  const int t = threadIdx.x;
  float4 v = reinterpret_cast<const float4*>(att + row * 1024)[t];
  float m = fmaxf(fmaxf(v.x, v.y), fmaxf(v.z, v.w));
#pragma unroll
  for (int off = 32; off > 0; off >>= 1) m = fmaxf(m, __shfl_down(m, off, 64));
  __shared__ float smax[4], ssum[4];
  const int wid = t >> 6, lane = t & 63;
  if (lane == 0) smax[wid] = m;
  __syncthreads();
  m = fmaxf(fmaxf(smax[0], smax[1]), fmaxf(smax[2], smax[3]));
  float e0 = expf(v.x - m), e1 = expf(v.y - m), e2 = expf(v.z - m), e3 = expf(v.w - m);
  float s = e0 + e1 + e2 + e3;
#pragma unroll
  for (int off = 32; off > 0; off >>= 1) s += __shfl_down(s, off, 64);
  if (lane == 0) ssum[wid] = s;
  __syncthreads();
  s = ssum[0] + ssum[1] + ssum[2] + ssum[3];
  float inv = 1.0f / s;
  ushort4 o;
  o.x = f2bf(e0 * inv); o.y = f2bf(e1 * inv); o.z = f2bf(e2 * inv); o.w = f2bf(e3 * inv);
  reinterpret_cast<ushort4*>(P + row * 1024)[t] = o;
}

extern "C" void kernel_launch(void* const* d_in, const int* in_sizes, int n_in,
                              void* d_out, int out_size, void* d_ws, size_t ws_size,
                              hipStream_t stream) {
  const float* x  = (const float*)d_in[0];
  const float* Wq = (const float*)d_in[1];
  const float* Wk = (const float*)d_in[2];
  const float* Wv = (const float*)d_in[3];
  const float* Wo = (const float*)d_in[4];

  const long M1 = 1L << 20;               // 1M elements

  // workspace layout (u16 elements)
  u16* xbf  = (u16*)d_ws;                 // [16384][1024]                      16M
  u16* wq   = xbf + 16 * M1;              // [1024][1024]                        1M
  u16* wk   = wq + M1;                    //                                     1M
  u16* wv   = wk + M1;                    //                                     1M
  u16* wo   = wv + M1;                    //                                     1M
  u16* wvT  = wo + M1;                    // Wv^T                                1M
  u16* xT   = wvT + M1;                   // [4][1024 feat][4096 tok]           16M
  u16* gbf  = xT + 16 * M1;               // G bf16 [4][1024][1024]              4M
  u16* tbuf = gbf + 4 * M1;               // T~ = Wq G                           4M
  u16* pbuf = tbuf + 4 * M1;              // P (softmax)                         4M
  u16* rtb  = pbuf + 4 * M1;              // R^T                                 4M
  u16* sbuf = rtb + 4 * M1;               // S = Wo R                            4M
  float* gpart = (float*)d_out;           // G split-K partials [16][1024][1024] f32
  float* attf  = (float*)d_out;           // att f32 [4][1024][1024] (after gpart dead)

  dim3 b256(256), b512(512);
  const long NOF = 0;
  const int NSH = 30;

  // conversions + transposes
  cvt_x_dual<<<dim3(16, 64, 4), b256, 0, stream>>>(x, xbf, xT);
  cvt_w4<<<dim3(4096), b256, 0, stream>>>(Wq, Wk, Wv, Wo, wq, wk, wv, wo);
  transpose_bf16<<<dim3(16, 16, 1), b256, 0, stream>>>(wv, 1024, 0, wvT, 1024, 0);

  // G[b] = x[b]^T x[b]  (M=N=1024, K=4096 split into 4; z=b*4+p) -> f32 partials
  gemm_nt256<true><<<dim3(4, 4, 16), b512, 0, stream>>>(
      xT, 4096, 1024L * 4096, 1024, xT, 4096, 1024L * 4096, 1024,
      (void*)gpart, 1024, 4L << 20, 1L << 20, NOF, NSH, 1024, 1.0f);
  greduce4<<<dim3(4096), b256, 0, stream>>>(gpart, gbf);

  // T~[b] = Wq G[b]   (G symmetric -> NT form)
  gemm_nt128p<false><<<dim3(8, 8, 4), b256, 0, stream>>>(
      wq, 1024, 0, gbf, 1024, M1, (void*)tbuf, 1024, M1, 1024, 1.0f);
  // att[b] = T~[b] Wk^T / 32 -> f32 in d_out
  gemm_nt128p<true><<<dim3(8, 8, 4), b256, 0, stream>>>(
      tbuf, 1024, M1, wk, 1024, 0, (void*)attf, 1024, M1, 1024, 1.0f / 32.0f);
  // softmax rows -> P bf16
  softmax1<<<dim3(4096), b256, 0, stream>>>(attf, pbuf);

  // R^T[b]: C[e,k] = sum_j Wv[j,e] P[k,j]
  gemm_nt128p<false><<<dim3(8, 8, 4), b256, 0, stream>>>(
      wvT, 1024, 0, pbuf, 1024, M1, (void*)rtb, 1024, M1, 1024, 1.0f);
  // S[b]: C[e',e] = sum_k Wo[e',k] RT[e,k]
  gemm_nt128p<false><<<dim3(8, 8, 4), b256, 0, stream>>>(
      wo, 1024, 0, rtb, 1024, M1, (void*)sbuf, 1024, M1, 1024, 1.0f);

  // final[b] = x[b] S[b]^T  (M=4096/batch, N=1024, K=1024) -> d_out f32
  gemm_nt256<true><<<dim3(16, 4, 4), b512, 0, stream>>>(
      xbf, 1024, 0, 4096L * 1024, sbuf, 1024, 0, M1,
      d_out, 1024, 0, 4096L * 1024, NOF, NSH, 1024, 1.0f);
}

// Round 11
// 197.318 us; speedup vs baseline: 1.4384x; 1.1163x over previous
//
#include <hip/hip_runtime.h>
#include <hip/hip_bf16.h>

typedef unsigned short u16;
typedef __bf16 bf16x8 __attribute__((ext_vector_type(8)));
typedef float f32x4 __attribute__((ext_vector_type(4)));
typedef unsigned short ushort8 __attribute__((ext_vector_type(8)));

#define AS1 __attribute__((address_space(1)))
#define AS3 __attribute__((address_space(3)))

__device__ inline u16 f2bf(float f) {
  union { float f; unsigned int u; } c; c.f = f;
  unsigned int u = c.u;
  return (u16)((u + 0x7fffu + ((u >> 16) & 1u)) >> 16);
}
__device__ inline float bf2f(u16 v) {
  union { unsigned int u; float f; } c; c.u = ((unsigned int)v) << 16;
  return c.f;
}

// ---------------- fused x conversion + transpose ----------------
__global__ __launch_bounds__(256) void cvt_x_dual(const float* __restrict__ x,
                                                  u16* __restrict__ xbf,
                                                  u16* __restrict__ xT) {
  __shared__ u16 tile[64][68];
  const int t = threadIdx.x;
  const long e0 = (long)blockIdx.x * 64;     // feature tile
  const long l0 = (long)blockIdx.y * 64;     // token tile within batch
  const long b  = blockIdx.z;
  const int tr = t >> 4, tc = t & 15;
#pragma unroll
  for (int i = 0; i < 4; ++i) {
    const int r = tr + i * 16;
    const long gl = b * 4096 + l0 + r;
    float4 v = *reinterpret_cast<const float4*>(x + gl * 1024 + e0 + tc * 4);
    ushort4 o;
    o.x = f2bf(v.x); o.y = f2bf(v.y); o.z = f2bf(v.z); o.w = f2bf(v.w);
    *reinterpret_cast<ushort4*>(xbf + gl * 1024 + e0 + tc * 4) = o;
    *reinterpret_cast<ushort4*>(&tile[r][tc * 4]) = o;
  }
  __syncthreads();
#pragma unroll
  for (int i = 0; i < 4; ++i) {
    const int c = tr + i * 16;
    ushort4 o;
    o.x = tile[tc * 4 + 0][c]; o.y = tile[tc * 4 + 1][c];
    o.z = tile[tc * 4 + 2][c]; o.w = tile[tc * 4 + 3][c];
    *reinterpret_cast<ushort4*>(xT + b * (1024L * 4096) + (e0 + c) * 4096 + l0 + tc * 4) = o;
  }
}

// ---------------- fused conversion of the 4 weight matrices ----------------
__global__ __launch_bounds__(256) void cvt_w4(const float* __restrict__ a, const float* __restrict__ b,
                                              const float* __restrict__ c, const float* __restrict__ d,
                                              u16* __restrict__ oa, u16* __restrict__ ob,
                                              u16* __restrict__ oc, u16* __restrict__ od) {
  int i = blockIdx.x * 256 + threadIdx.x;
  const int which = i >> 18;
  const int j = i & 262143;
  const float* src = which == 0 ? a : which == 1 ? b : which == 2 ? c : d;
  u16* dst = which == 0 ? oa : which == 1 ? ob : which == 2 ? oc : od;
  float4 v = reinterpret_cast<const float4*>(src)[j];
  ushort4 o;
  o.x = f2bf(v.x); o.y = f2bf(v.y); o.z = f2bf(v.z); o.w = f2bf(v.w);
  reinterpret_cast<ushort4*>(dst)[j] = o;
}

// ---------------- bf16 tiled transpose ----------------
__global__ __launch_bounds__(256) void transpose_bf16(
    const u16* __restrict__ src, long sLd, long sZ,
    u16* __restrict__ dst, long dLd, long dZ) {
  __shared__ u16 tile[64][68];
  const int t = threadIdx.x;
  const long r0 = (long)blockIdx.y * 64;
  const long c0 = (long)blockIdx.x * 64;
  const long z = blockIdx.z;
  const int tr = t >> 4, tc = t & 15;
#pragma unroll
  for (int i = 0; i < 4; ++i) {
    const int r = tr + i * 16;
    ushort4 v = *reinterpret_cast<const ushort4*>(src + z * sZ + (r0 + r) * sLd + c0 + tc * 4);
    *reinterpret_cast<ushort4*>(&tile[r][tc * 4]) = v;
  }
  __syncthreads();
#pragma unroll
  for (int i = 0; i < 4; ++i) {
    const int c = tr + i * 16;
    ushort4 o;
    o.x = tile[tc * 4 + 0][c]; o.y = tile[tc * 4 + 1][c];
    o.z = tile[tc * 4 + 2][c]; o.w = tile[tc * 4 + 3][c];
    *reinterpret_cast<ushort4*>(dst + z * dZ + (c0 + c) * dLd + r0 + tc * 4) = o;
  }
}

// ============ 256x256 NT GEMM, BK=64, 8 waves, 4-phase, vmcnt(6)/phase ========
__device__ __forceinline__ void stage_half(const u16* __restrict__ g, long ld, int k0,
                                           u16* dst, int t) {
#pragma unroll
  for (int i = 0; i < 2; ++i) {
    const int c = i * 512 + t;
    const int r = c >> 3;
    const int s = c & 7;
    const int col = ((s ^ (r & 7)) << 3) + k0;
    __builtin_amdgcn_global_load_lds((const AS1 void*)(g + (long)r * ld + col),
                                     (AS3 void*)(dst + c * 8), 16, 0, 0);
  }
}

__device__ __forceinline__ bf16x8 frag_ld(const u16* s, int row, int colb) {
  return *reinterpret_cast<const bf16x8*>(
      reinterpret_cast<const char*>(s) + row * 128 + (colb ^ ((row & 7) << 4)));
}

#define BAR_PRE()       do { asm volatile("s_waitcnt vmcnt(6)" ::: "memory"); \
                             __builtin_amdgcn_s_barrier(); \
                             asm volatile("" ::: "memory"); } while (0)
#define BAR_POST()      do { asm volatile("" ::: "memory"); \
                             __builtin_amdgcn_s_barrier(); \
                             asm volatile("" ::: "memory"); } while (0)

template<bool OUT_F32>
__global__ __launch_bounds__(512, 2) void gemm_nt256(
    const u16* __restrict__ A, long lda, long sAz4, long sAz1,
    const u16* __restrict__ B, long ldb, long sBz4, long sBz1,
    void* __restrict__ Cv, long ldc, long sCz4, long sCz1,
    long cBatch, int cShift,
    int K, float scale)
{
  __shared__ u16 sm[2 * 32768] __attribute__((aligned(16)));  // 128 KiB

  const int t = threadIdx.x;
  int wg = blockIdx.x + gridDim.x * blockIdx.y;
  const int nwg = gridDim.x * gridDim.y;
  const int qq = nwg >> 3;
  wg = (wg & 7) * qq + (wg >> 3);
  const long m0 = (long)(wg % gridDim.x) * 256;
  const long n0 = (long)(wg / gridDim.x) * 256;
  const int z = blockIdx.z;
  const long azoff = (long)(z >> 2) * sAz4 + (long)(z & 3) * sAz1;
  const long bzoff = (long)(z >> 2) * sBz4 + (long)(z & 3) * sBz1;
  const u16* Ab = A + azoff + m0 * lda;
  const u16* Bb = B + bzoff + n0 * ldb;

  const int wid = t >> 6, lane = t & 63;
  const int lhi = lane >> 4, llo = lane & 15;
  const int wm = wid >> 2, wn = wid & 3;

  f32x4 acc[2][4][2][2] = {};
  const int NT = K >> 6;

  stage_half(Ab, lda, 0, sm, t);
  stage_half(Bb + 128 * ldb, ldb, 0, sm + 16384 + 8192, t);
  stage_half(Bb, ldb, 0, sm + 16384, t);
  stage_half(Ab + 128 * lda, lda, 0, sm + 8192, t);
  stage_half(Ab, lda, 64, sm + 32768, t);
  stage_half(Bb + 128 * ldb, ldb, 64, sm + 32768 + 16384 + 8192, t);
  asm volatile("s_waitcnt vmcnt(4)" ::: "memory");
  __builtin_amdgcn_s_barrier();
  asm volatile("" ::: "memory");

  for (int kt = 0; kt < NT; ++kt) {
    const int kb = kt & 1;
    u16* bc = sm + kb * 32768;
    u16* bn = sm + (kb ^ 1) * 32768;
    const u16* sAc = bc;
    const u16* sBc = bc + 16384;
    const int k1 = ((kt + 1 < NT) ? kt + 1 : 0) << 6;
    const int k2 = ((kt + 2 < NT) ? kt + 2 : kt + 2 - NT) << 6;

    bf16x8 a[4][2], bl[2][2], bh[2][2];

    // ph0
#pragma unroll
    for (int fr = 0; fr < 4; ++fr)
#pragma unroll
      for (int kk = 0; kk < 2; ++kk)
        a[fr][kk] = frag_ld(sAc, wm * 64 + fr * 16 + llo, (kk << 6) + (lhi << 4));
#pragma unroll
    for (int fc = 0; fc < 2; ++fc)
#pragma unroll
      for (int kk = 0; kk < 2; ++kk)
        bl[fc][kk] = frag_ld(sBc, wn * 32 + fc * 16 + llo, (kk << 6) + (lhi << 4));
    stage_half(Bb, ldb, k1, bn + 16384, t);
    BAR_PRE();
    __builtin_amdgcn_s_setprio(1);
#pragma unroll
    for (int fr = 0; fr < 4; ++fr)
#pragma unroll
      for (int fc = 0; fc < 2; ++fc)
#pragma unroll
        for (int kk = 0; kk < 2; ++kk)
          acc[0][fr][0][fc] = __builtin_amdgcn_mfma_f32_16x16x32_bf16(a[fr][kk], bl[fc][kk], acc[0][fr][0][fc], 0, 0, 0);
    __builtin_amdgcn_s_setprio(0);
    BAR_POST();

    // ph1
#pragma unroll
    for (int fc = 0; fc < 2; ++fc)
#pragma unroll
      for (int kk = 0; kk < 2; ++kk)
        bh[fc][kk] = frag_ld(sBc, 128 + wn * 32 + fc * 16 + llo, (kk << 6) + (lhi << 4));
    stage_half(Ab + 128 * lda, lda, k1, bn + 8192, t);
    BAR_PRE();
    __builtin_amdgcn_s_setprio(1);
#pragma unroll
    for (int fr = 0; fr < 4; ++fr)
#pragma unroll
      for (int fc = 0; fc < 2; ++fc)
#pragma unroll
        for (int kk = 0; kk < 2; ++kk)
          acc[0][fr][1][fc] = __builtin_amdgcn_mfma_f32_16x16x32_bf16(a[fr][kk], bh[fc][kk], acc[0][fr][1][fc], 0, 0, 0);
    __builtin_amdgcn_s_setprio(0);
    BAR_POST();

    // ph2
#pragma unroll
    for (int fr = 0; fr < 4; ++fr)
#pragma unroll
      for (int kk = 0; kk < 2; ++kk)
        a[fr][kk] = frag_ld(sAc, 128 + wm * 64 + fr * 16 + llo, (kk << 6) + (lhi << 4));
    stage_half(Ab, lda, k2, bc, t);
    BAR_PRE();
    __builtin_amdgcn_s_setprio(1);
#pragma unroll
    for (int fr = 0; fr < 4; ++fr)
#pragma unroll
      for (int fc = 0; fc < 2; ++fc)
#pragma unroll
        for (int kk = 0; kk < 2; ++kk)
          acc[1][fr][1][fc] = __builtin_amdgcn_mfma_f32_16x16x32_bf16(a[fr][kk], bh[fc][kk], acc[1][fr][1][fc], 0, 0, 0);
    __builtin_amdgcn_s_setprio(0);
    BAR_POST();

    // ph3
    stage_half(Bb + 128 * ldb, ldb, k2, bc + 16384 + 8192, t);
    BAR_PRE();
    __builtin_amdgcn_s_setprio(1);
#pragma unroll
    for (int fr = 0; fr < 4; ++fr)
#pragma unroll
      for (int fc = 0; fc < 2; ++fc)
#pragma unroll
        for (int kk = 0; kk < 2; ++kk)
          acc[1][fr][0][fc] = __builtin_amdgcn_mfma_f32_16x16x32_bf16(a[fr][kk], bl[fc][kk], acc[1][fr][0][fc], 0, 0, 0);
    __builtin_amdgcn_s_setprio(0);
    BAR_POST();
  }

  const long cb = n0 >> cShift;
  const long ncol0 = n0 - (cb << cShift);
  const long czoff = (long)(z >> 2) * sCz4 + (long)(z & 3) * sCz1 + cb * cBatch;
#pragma unroll
  for (int ah = 0; ah < 2; ++ah)
#pragma unroll
    for (int fr = 0; fr < 4; ++fr)
#pragma unroll
      for (int e = 0; e < 4; ++e) {
        const long r = m0 + ah * 128 + wm * 64 + fr * 16 + lhi * 4 + e;
#pragma unroll
        for (int bh2 = 0; bh2 < 2; ++bh2)
#pragma unroll
          for (int fc = 0; fc < 2; ++fc) {
            const long col = ncol0 + bh2 * 128 + wn * 32 + fc * 16 + llo;
            const float val = acc[ah][fr][bh2][fc][e] * scale;
            if (OUT_F32)
              ((float*)Cv)[czoff + r * ldc + col] = val;
            else
              ((u16*)Cv)[czoff + r * ldc + col] = f2bf(val);
          }
      }
}

// ===== 128x128 NT GEMM, BK=32, 8 WAVES (2x4), triple-buffered counted-vmcnt ====
// Wave tile 64x32 (acc 4x2). 2 waves/SIMD -> MFMA of one wave overlaps LDS reads
// of the other (m114 co-scheduling). Staging: 1 A-chunk + 1 B-chunk per thread
// per tile (2 loads); prologue 3 tiles = 6 outstanding; loop vmcnt(4) retires
// exactly tile kt. NT >= 3.
__device__ __forceinline__ bf16x8 frag_ld128(const u16* s, int row, int lhi) {
  return *reinterpret_cast<const bf16x8*>(
      reinterpret_cast<const char*>(s) + row * 64 + ((lhi ^ (row & 3)) << 4));
}

template<bool OUT_F32>
__global__ __launch_bounds__(512, 2) void gemm_nt128w(
    const u16* __restrict__ A, long lda, long sAz,
    const u16* __restrict__ B, long ldb, long sBz,
    void* __restrict__ Cv, long ldc, long sCz,
    int K, float scale)
{
  __shared__ u16 sm[3 * 8192] __attribute__((aligned(16)));  // 48 KiB

  const int t = threadIdx.x;
  int wg = blockIdx.x + gridDim.x * blockIdx.y;
  const int nwg = gridDim.x * gridDim.y;
  const int qq = nwg >> 3;
  wg = (wg & 7) * qq + (wg >> 3);
  const long m0 = (long)(wg % gridDim.x) * 128;
  const long n0 = (long)(wg / gridDim.x) * 128;
  const int z = blockIdx.z;
  A += (long)z * sAz + m0 * lda;
  B += (long)z * sBz + n0 * ldb;

  const int wid = t >> 6, lane = t & 63;
  const int lhi = lane >> 4, llo = lane & 15;
  const int wr = (wid >> 2) * 64, wc = (wid & 3) * 32;
  const int srow = t >> 2;     // 0..127
  const int scol = t & 3;

  f32x4 acc[4][2] = {};
  const int NT = K >> 5;   // >= 3

#define STAGEW(kk, buf)                                                                 \
  do {                                                                                  \
    const int col = ((scol ^ (srow & 3)) << 3) + (kk);                                  \
    __builtin_amdgcn_global_load_lds((const AS1 void*)(A + (long)srow * lda + col),     \
                                     (AS3 void*)((buf) + t * 8), 16, 0, 0);             \
    __builtin_amdgcn_global_load_lds((const AS1 void*)(B + (long)srow * ldb + col),     \
                                     (AS3 void*)((buf) + 4096 + t * 8), 16, 0, 0);      \
  } while (0)

  STAGEW(0, sm);
  STAGEW(32, sm + 8192);
  STAGEW(64, sm + 16384);

  for (int kt = 0; kt < NT; ++kt) {
    asm volatile("s_waitcnt vmcnt(4)" ::: "memory");   // tile kt resident
    __builtin_amdgcn_s_barrier();
    asm volatile("" ::: "memory");
    u16* buf = sm + (kt % 3) * 8192;
    bf16x8 af[4], bfr[2];
#pragma unroll
    for (int i = 0; i < 4; ++i) af[i] = frag_ld128(buf, wr + i * 16 + llo, lhi);
#pragma unroll
    for (int j = 0; j < 2; ++j) bfr[j] = frag_ld128(buf + 4096, wc + j * 16 + llo, lhi);
    __builtin_amdgcn_s_setprio(1);
#pragma unroll
    for (int i = 0; i < 4; ++i)
#pragma unroll
      for (int j = 0; j < 2; ++j)
        acc[i][j] = __builtin_amdgcn_mfma_f32_16x16x32_bf16(af[i], bfr[j], acc[i][j], 0, 0, 0);
    __builtin_amdgcn_s_setprio(0);
    asm volatile("" ::: "memory");
    __builtin_amdgcn_s_barrier();
    asm volatile("" ::: "memory");
    const int k3 = ((kt + 3 < NT) ? kt + 3 : kt + 3 - NT) << 5;   // wrapped-dead at tail
    STAGEW(k3, buf);
  }

#pragma unroll
  for (int i = 0; i < 4; ++i) {
#pragma unroll
    for (int e = 0; e < 4; ++e) {
      const long r = m0 + wr + i * 16 + lhi * 4 + e;
      if (OUT_F32) {
        float* C = (float*)Cv + (long)z * sCz + r * ldc + n0 + wc + llo;
#pragma unroll
        for (int j = 0; j < 2; ++j) C[j * 16] = acc[i][j][e] * scale;
      } else {
        u16* C = (u16*)Cv + (long)z * sCz + r * ldc + n0 + wc + llo;
#pragma unroll
        for (int j = 0; j < 2; ++j) C[j * 16] = f2bf(acc[i][j][e] * scale);
      }
    }
  }
}

// ---- reduce 4 split-K bf16 partials of G -> bf16 [4][1024][1024] ----
__global__ __launch_bounds__(256) void greduce4b(const u16* __restrict__ gp,
                                                 u16* __restrict__ gb) {
  const long o = (long)blockIdx.x * 256 + threadIdx.x;   // ushort8 index; 512K total
  const long b = o >> 17;                                // (1<<20)/8 = 131072
  const long r = o & 131071;
  float s[8] = {};
#pragma unroll
  for (int p = 0; p < 4; ++p) {
    ushort8 u = reinterpret_cast<const ushort8*>(gp)[((b * 4 + p) << 17) + r];
#pragma unroll
    for (int j = 0; j < 8; ++j) s[j] += bf2f(u[j]);
  }
  ushort8 out;
#pragma unroll
  for (int j = 0; j < 8; ++j) out[j] = f2bf(s[j]);
  reinterpret_cast<ushort8*>(gb)[o] = out;
}

// ---- single-pass row softmax: att f32 [4096][1024] -> P bf16 ----
__global__ __launch_bounds__(256) void softmax1(const float* __restrict__ att,
                                                u16* __restrict__ P) {
  const long row = blockIdx.x;
  const int t = threadIdx.x;
  float4 v = reinterpret_cast<const float4*>(att + row * 1024)[t];
  float m = fmaxf(fmaxf(v.x, v.y), fmaxf(v.z, v.w));
#pragma unroll
  for (int off = 32; off > 0; off >>= 1) m = fmaxf(m, __shfl_down(m, off, 64));
  __shared__ float smax[4], ssum[4];
  const int wid = t >> 6, lane = t & 63;
  if (lane == 0) smax[wid] = m;
  __syncthreads();
  m = fmaxf(fmaxf(smax[0], smax[1]), fmaxf(smax[2], smax[3]));
  float e0 = expf(v.x - m), e1 = expf(v.y - m), e2 = expf(v.z - m), e3 = expf(v.w - m);
  float s = e0 + e1 + e2 + e3;
#pragma unroll
  for (int off = 32; off > 0; off >>= 1) s += __shfl_down(s, off, 64);
  if (lane == 0) ssum[wid] = s;
  __syncthreads();
  s = ssum[0] + ssum[1] + ssum[2] + ssum[3];
  float inv = 1.0f / s;
  ushort4 o;
  o.x = f2bf(e0 * inv); o.y = f2bf(e1 * inv); o.z = f2bf(e2 * inv); o.w = f2bf(e3 * inv);
  reinterpret_cast<ushort4*>(P + row * 1024)[t] = o;
}

extern "C" void kernel_launch(void* const* d_in, const int* in_sizes, int n_in,
                              void* d_out, int out_size, void* d_ws, size_t ws_size,
                              hipStream_t stream) {
  const float* x  = (const float*)d_in[0];
  const float* Wq = (const float*)d_in[1];
  const float* Wk = (const float*)d_in[2];
  const float* Wv = (const float*)d_in[3];
  const float* Wo = (const float*)d_in[4];

  const long M1 = 1L << 20;               // 1M elements

  // workspace layout (u16 elements)
  u16* xbf    = (u16*)d_ws;               // [16384][1024]                      16M
  u16* wq     = xbf + 16 * M1;            //                                     1M
  u16* wk     = wq + M1;                  //                                     1M
  u16* wv     = wk + M1;                  //                                     1M
  u16* wo     = wv + M1;                  //                                     1M
  u16* wvT    = wo + M1;                  // Wv^T                                1M
  u16* xT     = wvT + M1;                 // [4][1024 feat][4096 tok]           16M
  u16* gbf    = xT + 16 * M1;             // G bf16 [4][1024][1024]              4M
  u16* tbuf   = gbf + 4 * M1;             // T~ = Wq G                           4M
  u16* pbuf   = tbuf + 4 * M1;            // P (softmax)                         4M
  u16* rtb    = pbuf + 4 * M1;            // R^T                                 4M
  u16* sbuf   = rtb + 4 * M1;             // S = Wo R                            4M
  u16* gpartb = sbuf + 4 * M1;            // G bf16 partials [16][1024][1024]   16M
  float* attf = (float*)d_out;            // att f32 [4][1024][1024] (16 MB)

  dim3 b256(256), b512(512);
  const long NOF = 0;
  const int NSH = 30;

  // conversions + transposes
  cvt_x_dual<<<dim3(16, 64, 4), b256, 0, stream>>>(x, xbf, xT);
  cvt_w4<<<dim3(4096), b256, 0, stream>>>(Wq, Wk, Wv, Wo, wq, wk, wv, wo);
  transpose_bf16<<<dim3(16, 16, 1), b256, 0, stream>>>(wv, 1024, 0, wvT, 1024, 0);

  // G[b] = x[b]^T x[b]  (M=N=1024, K=4096 split 4; z=b*4+p) -> bf16 partials
  gemm_nt256<false><<<dim3(4, 4, 16), b512, 0, stream>>>(
      xT, 4096, 1024L * 4096, 1024, xT, 4096, 1024L * 4096, 1024,
      (void*)gpartb, 1024, 4L << 20, 1L << 20, NOF, NSH, 1024, 1.0f);
  greduce4b<<<dim3(2048), b256, 0, stream>>>(gpartb, gbf);

  // T~[b] = Wq G[b]   (G symmetric -> NT form)
  gemm_nt128w<false><<<dim3(8, 8, 4), b512, 0, stream>>>(
      wq, 1024, 0, gbf, 1024, M1, (void*)tbuf, 1024, M1, 1024, 1.0f);
  // att[b] = T~[b] Wk^T / 32 -> f32 in d_out
  gemm_nt128w<true><<<dim3(8, 8, 4), b512, 0, stream>>>(
      tbuf, 1024, M1, wk, 1024, 0, (void*)attf, 1024, M1, 1024, 1.0f / 32.0f);
  // softmax rows -> P bf16
  softmax1<<<dim3(4096), b256, 0, stream>>>(attf, pbuf);

  // R^T[b]: C[e,k] = sum_j Wv[j,e] P[k,j]
  gemm_nt128w<false><<<dim3(8, 8, 4), b512, 0, stream>>>(
      wvT, 1024, 0, pbuf, 1024, M1, (void*)rtb, 1024, M1, 1024, 1.0f);
  // S[b]: C[e',e] = sum_k Wo[e',k] RT[e,k]
  gemm_nt128w<false><<<dim3(8, 8, 4), b512, 0, stream>>>(
      wo, 1024, 0, rtb, 1024, M1, (void*)sbuf, 1024, M1, 1024, 1.0f);

  // final[b] = x[b] S[b]^T  (M=4096/batch, N=1024, K=1024) -> d_out f32
  gemm_nt256<true><<<dim3(16, 4, 4), b512, 0, stream>>>(
      xbf, 1024, 0, 4096L * 1024, sbuf, 1024, 0, M1,
      d_out, 1024, 0, 4096L * 1024, NOF, NSH, 1024, 1.0f);
}

// Round 12
// 190.226 us; speedup vs baseline: 1.4921x; 1.0373x over previous
//
#include <hip/hip_runtime.h>
#include <hip/hip_bf16.h>

typedef unsigned short u16;
typedef __bf16 bf16x8 __attribute__((ext_vector_type(8)));
typedef float f32x4 __attribute__((ext_vector_type(4)));
typedef unsigned short ushort8 __attribute__((ext_vector_type(8)));

#define AS1 __attribute__((address_space(1)))
#define AS3 __attribute__((address_space(3)))

__device__ inline u16 f2bf(float f) {
  union { float f; unsigned int u; } c; c.f = f;
  unsigned int u = c.u;
  return (u16)((u + 0x7fffu + ((u >> 16) & 1u)) >> 16);
}
__device__ inline float bf2f(u16 v) {
  union { unsigned int u; float f; } c; c.u = ((unsigned int)v) << 16;
  return c.f;
}

// ---------------- fused x conversion + transpose ----------------
__global__ __launch_bounds__(256) void cvt_x_dual(const float* __restrict__ x,
                                                  u16* __restrict__ xbf,
                                                  u16* __restrict__ xT) {
  __shared__ u16 tile[64][68];
  const int t = threadIdx.x;
  const long e0 = (long)blockIdx.x * 64;     // feature tile
  const long l0 = (long)blockIdx.y * 64;     // token tile within batch
  const long b  = blockIdx.z;
  const int tr = t >> 4, tc = t & 15;
#pragma unroll
  for (int i = 0; i < 4; ++i) {
    const int r = tr + i * 16;
    const long gl = b * 4096 + l0 + r;
    float4 v = *reinterpret_cast<const float4*>(x + gl * 1024 + e0 + tc * 4);
    ushort4 o;
    o.x = f2bf(v.x); o.y = f2bf(v.y); o.z = f2bf(v.z); o.w = f2bf(v.w);
    *reinterpret_cast<ushort4*>(xbf + gl * 1024 + e0 + tc * 4) = o;
    *reinterpret_cast<ushort4*>(&tile[r][tc * 4]) = o;
  }
  __syncthreads();
#pragma unroll
  for (int i = 0; i < 4; ++i) {
    const int c = tr + i * 16;
    ushort4 o;
    o.x = tile[tc * 4 + 0][c]; o.y = tile[tc * 4 + 1][c];
    o.z = tile[tc * 4 + 2][c]; o.w = tile[tc * 4 + 3][c];
    *reinterpret_cast<ushort4*>(xT + b * (1024L * 4096) + (e0 + c) * 4096 + l0 + tc * 4) = o;
  }
}

// ---------------- fused conversion of the 4 weight matrices ----------------
__global__ __launch_bounds__(256) void cvt_w4(const float* __restrict__ a, const float* __restrict__ b,
                                              const float* __restrict__ c, const float* __restrict__ d,
                                              u16* __restrict__ oa, u16* __restrict__ ob,
                                              u16* __restrict__ oc, u16* __restrict__ od) {
  int i = blockIdx.x * 256 + threadIdx.x;
  const int which = i >> 18;
  const int j = i & 262143;
  const float* src = which == 0 ? a : which == 1 ? b : which == 2 ? c : d;
  u16* dst = which == 0 ? oa : which == 1 ? ob : which == 2 ? oc : od;
  float4 v = reinterpret_cast<const float4*>(src)[j];
  ushort4 o;
  o.x = f2bf(v.x); o.y = f2bf(v.y); o.z = f2bf(v.z); o.w = f2bf(v.w);
  reinterpret_cast<ushort4*>(dst)[j] = o;
}

// ---------------- bf16 tiled transpose ----------------
__global__ __launch_bounds__(256) void transpose_bf16(
    const u16* __restrict__ src, long sLd, long sZ,
    u16* __restrict__ dst, long dLd, long dZ) {
  __shared__ u16 tile[64][68];
  const int t = threadIdx.x;
  const long r0 = (long)blockIdx.y * 64;
  const long c0 = (long)blockIdx.x * 64;
  const long z = blockIdx.z;
  const int tr = t >> 4, tc = t & 15;
#pragma unroll
  for (int i = 0; i < 4; ++i) {
    const int r = tr + i * 16;
    ushort4 v = *reinterpret_cast<const ushort4*>(src + z * sZ + (r0 + r) * sLd + c0 + tc * 4);
    *reinterpret_cast<ushort4*>(&tile[r][tc * 4]) = v;
  }
  __syncthreads();
#pragma unroll
  for (int i = 0; i < 4; ++i) {
    const int c = tr + i * 16;
    ushort4 o;
    o.x = tile[tc * 4 + 0][c]; o.y = tile[tc * 4 + 1][c];
    o.z = tile[tc * 4 + 2][c]; o.w = tile[tc * 4 + 3][c];
    *reinterpret_cast<ushort4*>(dst + z * dZ + (c0 + c) * dLd + r0 + tc * 4) = o;
  }
}

// ---- shared staging helper: one [128 rows][64 cols] bf16 tile via gload_lds ----
__device__ __forceinline__ void stage_half(const u16* __restrict__ g, long ld, int k0,
                                           u16* dst, int t) {
#pragma unroll
  for (int i = 0; i < 2; ++i) {
    const int c = i * 512 + t;
    const int r = c >> 3;
    const int s = c & 7;
    const int col = ((s ^ (r & 7)) << 3) + k0;   // pre-swizzled global source
    __builtin_amdgcn_global_load_lds((const AS1 void*)(g + (long)r * ld + col),
                                     (AS3 void*)(dst + c * 8), 16, 0, 0);
  }
}

__device__ __forceinline__ bf16x8 frag_ld(const u16* s, int row, int colb) {
  return *reinterpret_cast<const bf16x8*>(
      reinterpret_cast<const char*>(s) + row * 128 + (colb ^ ((row & 7) << 4)));
}

// ---- flattened bijective XCD swizzle: fold (x,y,z) before chunking ----
// total blocks must be % 8 == 0 (true at every call site: 256).
#define XCD_DECODE(TILE)                                                     \
  const int nxy = gridDim.x * gridDim.y;                                     \
  int flat = blockIdx.x + gridDim.x * blockIdx.y + nxy * blockIdx.z;         \
  const int total = nxy * gridDim.z;                                         \
  const int qq = total >> 3;                                                 \
  flat = (flat & 7) * qq + (flat >> 3);                                      \
  const int z = flat / nxy;                                                  \
  const int wg = flat % nxy;                                                 \
  const long m0 = (long)(wg % gridDim.x) * (TILE);                           \
  const long n0 = (long)(wg / gridDim.x) * (TILE);

// ============ 256x256 NT GEMM, BK=64, 8 waves, 4-phase, vmcnt(6)/phase ========
#define BAR_PRE()       do { asm volatile("s_waitcnt vmcnt(6)" ::: "memory"); \
                             __builtin_amdgcn_s_barrier(); \
                             asm volatile("" ::: "memory"); } while (0)
#define BAR_POST()      do { asm volatile("" ::: "memory"); \
                             __builtin_amdgcn_s_barrier(); \
                             asm volatile("" ::: "memory"); } while (0)

template<bool OUT_F32>
__global__ __launch_bounds__(512, 2) void gemm_nt256(
    const u16* __restrict__ A, long lda, long sAz4, long sAz1,
    const u16* __restrict__ B, long ldb, long sBz4, long sBz1,
    void* __restrict__ Cv, long ldc, long sCz4, long sCz1,
    long cBatch, int cShift,
    int K, float scale)
{
  __shared__ u16 sm[2 * 32768] __attribute__((aligned(16)));  // 128 KiB

  const int t = threadIdx.x;
  XCD_DECODE(256);
  const long azoff = (long)(z >> 2) * sAz4 + (long)(z & 3) * sAz1;
  const long bzoff = (long)(z >> 2) * sBz4 + (long)(z & 3) * sBz1;
  const u16* Ab = A + azoff + m0 * lda;
  const u16* Bb = B + bzoff + n0 * ldb;

  const int wid = t >> 6, lane = t & 63;
  const int lhi = lane >> 4, llo = lane & 15;
  const int wm = wid >> 2, wn = wid & 3;

  f32x4 acc[2][4][2][2] = {};
  const int NT = K >> 6;

  stage_half(Ab, lda, 0, sm, t);
  stage_half(Bb + 128 * ldb, ldb, 0, sm + 16384 + 8192, t);
  stage_half(Bb, ldb, 0, sm + 16384, t);
  stage_half(Ab + 128 * lda, lda, 0, sm + 8192, t);
  stage_half(Ab, lda, 64, sm + 32768, t);
  stage_half(Bb + 128 * ldb, ldb, 64, sm + 32768 + 16384 + 8192, t);
  asm volatile("s_waitcnt vmcnt(4)" ::: "memory");
  __builtin_amdgcn_s_barrier();
  asm volatile("" ::: "memory");

  for (int kt = 0; kt < NT; ++kt) {
    const int kb = kt & 1;
    u16* bc = sm + kb * 32768;
    u16* bn = sm + (kb ^ 1) * 32768;
    const u16* sAc = bc;
    const u16* sBc = bc + 16384;
    const int k1 = ((kt + 1 < NT) ? kt + 1 : 0) << 6;
    const int k2 = ((kt + 2 < NT) ? kt + 2 : kt + 2 - NT) << 6;

    bf16x8 a[4][2], bl[2][2], bh[2][2];

    // ph0
#pragma unroll
    for (int fr = 0; fr < 4; ++fr)
#pragma unroll
      for (int kk = 0; kk < 2; ++kk)
        a[fr][kk] = frag_ld(sAc, wm * 64 + fr * 16 + llo, (kk << 6) + (lhi << 4));
#pragma unroll
    for (int fc = 0; fc < 2; ++fc)
#pragma unroll
      for (int kk = 0; kk < 2; ++kk)
        bl[fc][kk] = frag_ld(sBc, wn * 32 + fc * 16 + llo, (kk << 6) + (lhi << 4));
    stage_half(Bb, ldb, k1, bn + 16384, t);
    BAR_PRE();
    __builtin_amdgcn_s_setprio(1);
#pragma unroll
    for (int fr = 0; fr < 4; ++fr)
#pragma unroll
      for (int fc = 0; fc < 2; ++fc)
#pragma unroll
        for (int kk = 0; kk < 2; ++kk)
          acc[0][fr][0][fc] = __builtin_amdgcn_mfma_f32_16x16x32_bf16(a[fr][kk], bl[fc][kk], acc[0][fr][0][fc], 0, 0, 0);
    __builtin_amdgcn_s_setprio(0);
    BAR_POST();

    // ph1
#pragma unroll
    for (int fc = 0; fc < 2; ++fc)
#pragma unroll
      for (int kk = 0; kk < 2; ++kk)
        bh[fc][kk] = frag_ld(sBc, 128 + wn * 32 + fc * 16 + llo, (kk << 6) + (lhi << 4));
    stage_half(Ab + 128 * lda, lda, k1, bn + 8192, t);
    BAR_PRE();
    __builtin_amdgcn_s_setprio(1);
#pragma unroll
    for (int fr = 0; fr < 4; ++fr)
#pragma unroll
      for (int fc = 0; fc < 2; ++fc)
#pragma unroll
        for (int kk = 0; kk < 2; ++kk)
          acc[0][fr][1][fc] = __builtin_amdgcn_mfma_f32_16x16x32_bf16(a[fr][kk], bh[fc][kk], acc[0][fr][1][fc], 0, 0, 0);
    __builtin_amdgcn_s_setprio(0);
    BAR_POST();

    // ph2
#pragma unroll
    for (int fr = 0; fr < 4; ++fr)
#pragma unroll
      for (int kk = 0; kk < 2; ++kk)
        a[fr][kk] = frag_ld(sAc, 128 + wm * 64 + fr * 16 + llo, (kk << 6) + (lhi << 4));
    stage_half(Ab, lda, k2, bc, t);
    BAR_PRE();
    __builtin_amdgcn_s_setprio(1);
#pragma unroll
    for (int fr = 0; fr < 4; ++fr)
#pragma unroll
      for (int fc = 0; fc < 2; ++fc)
#pragma unroll
        for (int kk = 0; kk < 2; ++kk)
          acc[1][fr][1][fc] = __builtin_amdgcn_mfma_f32_16x16x32_bf16(a[fr][kk], bh[fc][kk], acc[1][fr][1][fc], 0, 0, 0);
    __builtin_amdgcn_s_setprio(0);
    BAR_POST();

    // ph3
    stage_half(Bb + 128 * ldb, ldb, k2, bc + 16384 + 8192, t);
    BAR_PRE();
    __builtin_amdgcn_s_setprio(1);
#pragma unroll
    for (int fr = 0; fr < 4; ++fr)
#pragma unroll
      for (int fc = 0; fc < 2; ++fc)
#pragma unroll
        for (int kk = 0; kk < 2; ++kk)
          acc[1][fr][0][fc] = __builtin_amdgcn_mfma_f32_16x16x32_bf16(a[fr][kk], bl[fc][kk], acc[1][fr][0][fc], 0, 0, 0);
    __builtin_amdgcn_s_setprio(0);
    BAR_POST();
  }

  const long cb = n0 >> cShift;
  const long ncol0 = n0 - (cb << cShift);
  const long czoff = (long)(z >> 2) * sCz4 + (long)(z & 3) * sCz1 + cb * cBatch;
#pragma unroll
  for (int ah = 0; ah < 2; ++ah)
#pragma unroll
    for (int fr = 0; fr < 4; ++fr)
#pragma unroll
      for (int e = 0; e < 4; ++e) {
        const long r = m0 + ah * 128 + wm * 64 + fr * 16 + lhi * 4 + e;
#pragma unroll
        for (int bh2 = 0; bh2 < 2; ++bh2)
#pragma unroll
          for (int fc = 0; fc < 2; ++fc) {
            const long col = ncol0 + bh2 * 128 + wn * 32 + fc * 16 + llo;
            const float val = acc[ah][fr][bh2][fc][e] * scale;
            if (OUT_F32)
              ((float*)Cv)[czoff + r * ldc + col] = val;
            else
              ((u16*)Cv)[czoff + r * ldc + col] = f2bf(val);
          }
      }
}

// ===== 128x128 NT GEMM, BK=64, 8 WAVES (2x4), triple-buffered counted-vmcnt ====
// Wave tile 64x32 (acc 4x2). Tile = A[128][64]+B[128][64] = 32 KiB; 3 buffers
// (96 KiB LDS). Staging: 4 gload_lds per thread per tile (2 A + 2 B via
// stage_half). Prologue 3 tiles = 12 outstanding; loop vmcnt(8) retires
// exactly tile kt's 4. 16 iters at K=1024 (half the barriers of BK=32). NT>=3.
template<bool OUT_F32>
__global__ __launch_bounds__(512, 2) void gemm_nt128w(
    const u16* __restrict__ A, long lda, long sAz,
    const u16* __restrict__ B, long ldb, long sBz,
    void* __restrict__ Cv, long ldc, long sCz,
    int K, float scale)
{
  __shared__ u16 sm[3 * 16384] __attribute__((aligned(16)));  // 96 KiB

  const int t = threadIdx.x;
  XCD_DECODE(128);
  A += (long)z * sAz + m0 * lda;
  B += (long)z * sBz + n0 * ldb;

  const int wid = t >> 6, lane = t & 63;
  const int lhi = lane >> 4, llo = lane & 15;
  const int wr = (wid >> 2) * 64, wc = (wid & 3) * 32;

  f32x4 acc[4][2] = {};
  const int NT = K >> 6;   // >= 3

  stage_half(A, lda, 0, sm, t);
  stage_half(B, ldb, 0, sm + 8192, t);
  stage_half(A, lda, 64, sm + 16384, t);
  stage_half(B, ldb, 64, sm + 16384 + 8192, t);
  stage_half(A, lda, 128, sm + 32768, t);
  stage_half(B, ldb, 128, sm + 32768 + 8192, t);

  for (int kt = 0; kt < NT; ++kt) {
    asm volatile("s_waitcnt vmcnt(8)" ::: "memory");   // tile kt resident
    __builtin_amdgcn_s_barrier();
    asm volatile("" ::: "memory");
    u16* buf = sm + (kt % 3) * 16384;
    bf16x8 af[4][2], bfr[2][2];
#pragma unroll
    for (int i = 0; i < 4; ++i)
#pragma unroll
      for (int kk = 0; kk < 2; ++kk)
        af[i][kk] = frag_ld(buf, wr + i * 16 + llo, (kk << 6) + (lhi << 4));
#pragma unroll
    for (int j = 0; j < 2; ++j)
#pragma unroll
      for (int kk = 0; kk < 2; ++kk)
        bfr[j][kk] = frag_ld(buf + 8192, wc + j * 16 + llo, (kk << 6) + (lhi << 4));
    __builtin_amdgcn_s_setprio(1);
#pragma unroll
    for (int i = 0; i < 4; ++i)
#pragma unroll
      for (int j = 0; j < 2; ++j)
#pragma unroll
        for (int kk = 0; kk < 2; ++kk)
          acc[i][j] = __builtin_amdgcn_mfma_f32_16x16x32_bf16(af[i][kk], bfr[j][kk], acc[i][j], 0, 0, 0);
    __builtin_amdgcn_s_setprio(0);
    asm volatile("" ::: "memory");
    __builtin_amdgcn_s_barrier();
    asm volatile("" ::: "memory");
    const int k3 = ((kt + 3 < NT) ? kt + 3 : kt + 3 - NT) << 6;   // wrapped-dead at tail
    stage_half(A, lda, k3, buf, t);
    stage_half(B, ldb, k3, buf + 8192, t);
  }

#pragma unroll
  for (int i = 0; i < 4; ++i) {
#pragma unroll
    for (int e = 0; e < 4; ++e) {
      const long r = m0 + wr + i * 16 + lhi * 4 + e;
      if (OUT_F32) {
        float* C = (float*)Cv + (long)z * sCz + r * ldc + n0 + wc + llo;
#pragma unroll
        for (int j = 0; j < 2; ++j) C[j * 16] = acc[i][j][e] * scale;
      } else {
        u16* C = (u16*)Cv + (long)z * sCz + r * ldc + n0 + wc + llo;
#pragma unroll
        for (int j = 0; j < 2; ++j) C[j * 16] = f2bf(acc[i][j][e] * scale);
      }
    }
  }
}

// ---- reduce 4 split-K bf16 partials of G -> bf16 [4][1024][1024] ----
__global__ __launch_bounds__(256) void greduce4b(const u16* __restrict__ gp,
                                                 u16* __restrict__ gb) {
  const long o = (long)blockIdx.x * 256 + threadIdx.x;   // ushort8 index; 512K total
  const long b = o >> 17;
  const long r = o & 131071;
  float s[8] = {};
#pragma unroll
  for (int p = 0; p < 4; ++p) {
    ushort8 u = reinterpret_cast<const ushort8*>(gp)[((b * 4 + p) << 17) + r];
#pragma unroll
    for (int j = 0; j < 8; ++j) s[j] += bf2f(u[j]);
  }
  ushort8 out;
#pragma unroll
  for (int j = 0; j < 8; ++j) out[j] = f2bf(s[j]);
  reinterpret_cast<ushort8*>(gb)[o] = out;
}

// ---- single-pass row softmax: att f32 [4096][1024] -> P bf16 ----
__global__ __launch_bounds__(256) void softmax1(const float* __restrict__ att,
                                                u16* __restrict__ P) {
  const long row = blockIdx.x;
  const int t = threadIdx.x;
  float4 v = reinterpret_cast<const float4*>(att + row * 1024)[t];
  float m = fmaxf(fmaxf(v.x, v.y), fmaxf(v.z, v.w));
#pragma unroll
  for (int off = 32; off > 0; off >>= 1) m = fmaxf(m, __shfl_down(m, off, 64));
  __shared__ float smax[4], ssum[4];
  const int wid = t >> 6, lane = t & 63;
  if (lane == 0) smax[wid] = m;
  __syncthreads();
  m = fmaxf(fmaxf(smax[0], smax[1]), fmaxf(smax[2], smax[3]));
  float e0 = expf(v.x - m), e1 = expf(v.y - m), e2 = expf(v.z - m), e3 = expf(v.w - m);
  float s = e0 + e1 + e2 + e3;
#pragma unroll
  for (int off = 32; off > 0; off >>= 1) s += __shfl_down(s, off, 64);
  if (lane == 0) ssum[wid] = s;
  __syncthreads();
  s = ssum[0] + ssum[1] + ssum[2] + ssum[3];
  float inv = 1.0f / s;
  ushort4 o;
  o.x = f2bf(e0 * inv); o.y = f2bf(e1 * inv); o.z = f2bf(e2 * inv); o.w = f2bf(e3 * inv);
  reinterpret_cast<ushort4*>(P + row * 1024)[t] = o;
}

extern "C" void kernel_launch(void* const* d_in, const int* in_sizes, int n_in,
                              void* d_out, int out_size, void* d_ws, size_t ws_size,
                              hipStream_t stream) {
  const float* x  = (const float*)d_in[0];
  const float* Wq = (const float*)d_in[1];
  const float* Wk = (const float*)d_in[2];
  const float* Wv = (const float*)d_in[3];
  const float* Wo = (const float*)d_in[4];

  const long M1 = 1L << 20;               // 1M elements

  // workspace layout (u16 elements)
  u16* xbf    = (u16*)d_ws;               // [16384][1024]                      16M
  u16* wq     = xbf + 16 * M1;            //                                     1M
  u16* wk     = wq + M1;                  //                                     1M
  u16* wv     = wk + M1;                  //                                     1M
  u16* wo     = wv + M1;                  //                                     1M
  u16* wvT    = wo + M1;                  // Wv^T                                1M
  u16* xT     = wvT + M1;                 // [4][1024 feat][4096 tok]           16M
  u16* gbf    = xT + 16 * M1;             // G bf16 [4][1024][1024]              4M
  u16* tbuf   = gbf + 4 * M1;             // T~ = Wq G                           4M
  u16* pbuf   = tbuf + 4 * M1;            // P (softmax)                         4M
  u16* rtb    = pbuf + 4 * M1;            // R^T                                 4M
  u16* sbuf   = rtb + 4 * M1;             // S = Wo R                            4M
  u16* gpartb = sbuf + 4 * M1;            // G bf16 partials [16][1024][1024]   16M
  float* attf = (float*)d_out;            // att f32 [4][1024][1024] (16 MB)

  dim3 b256(256), b512(512);
  const long NOF = 0;
  const int NSH = 30;

  // conversions + transposes
  cvt_x_dual<<<dim3(16, 64, 4), b256, 0, stream>>>(x, xbf, xT);
  cvt_w4<<<dim3(4096), b256, 0, stream>>>(Wq, Wk, Wv, Wo, wq, wk, wv, wo);
  transpose_bf16<<<dim3(16, 16, 1), b256, 0, stream>>>(wv, 1024, 0, wvT, 1024, 0);

  // G[b] = x[b]^T x[b]  (M=N=1024, K=4096 split 4; z=b*4+p) -> bf16 partials
  gemm_nt256<false><<<dim3(4, 4, 16), b512, 0, stream>>>(
      xT, 4096, 1024L * 4096, 1024, xT, 4096, 1024L * 4096, 1024,
      (void*)gpartb, 1024, 4L << 20, 1L << 20, NOF, NSH, 1024, 1.0f);
  greduce4b<<<dim3(2048), b256, 0, stream>>>(gpartb, gbf);

  // T~[b] = Wq G[b]   (G symmetric -> NT form)
  gemm_nt128w<false><<<dim3(8, 8, 4), b512, 0, stream>>>(
      wq, 1024, 0, gbf, 1024, M1, (void*)tbuf, 1024, M1, 1024, 1.0f);
  // att[b] = T~[b] Wk^T / 32 -> f32 in d_out
  gemm_nt128w<true><<<dim3(8, 8, 4), b512, 0, stream>>>(
      tbuf, 1024, M1, wk, 1024, 0, (void*)attf, 1024, M1, 1024, 1.0f / 32.0f);
  // softmax rows -> P bf16
  softmax1<<<dim3(4096), b256, 0, stream>>>(attf, pbuf);

  // R^T[b]: C[e,k] = sum_j Wv[j,e] P[k,j]
  gemm_nt128w<false><<<dim3(8, 8, 4), b512, 0, stream>>>(
      wvT, 1024, 0, pbuf, 1024, M1, (void*)rtb, 1024, M1, 1024, 1.0f);
  // S[b]: C[e',e] = sum_k Wo[e',k] RT[e,k]
  gemm_nt128w<false><<<dim3(8, 8, 4), b512, 0, stream>>>(
      wo, 1024, 0, rtb, 1024, M1, (void*)sbuf, 1024, M1, 1024, 1.0f);

  // final[b] = x[b] S[b]^T  (M=4096/batch, N=1024, K=1024) -> d_out f32
  gemm_nt256<true><<<dim3(16, 4, 4), b512, 0, stream>>>(
      xbf, 1024, 0, 4096L * 1024, sbuf, 1024, 0, M1,
      d_out, 1024, 0, 4096L * 1024, NOF, NSH, 1024, 1.0f);
}

// Round 13
// 188.118 us; speedup vs baseline: 1.5088x; 1.0112x over previous
//
#include <hip/hip_runtime.h>
#include <hip/hip_bf16.h>

typedef unsigned short u16;
typedef __bf16 bf16x8 __attribute__((ext_vector_type(8)));
typedef float f32x4 __attribute__((ext_vector_type(4)));
typedef unsigned short ushort8 __attribute__((ext_vector_type(8)));

#define AS1 __attribute__((address_space(1)))
#define AS3 __attribute__((address_space(3)))

__device__ inline u16 f2bf(float f) {
  union { float f; unsigned int u; } c; c.f = f;
  unsigned int u = c.u;
  return (u16)((u + 0x7fffu + ((u >> 16) & 1u)) >> 16);
}
__device__ inline float bf2f(u16 v) {
  union { unsigned int u; float f; } c; c.u = ((unsigned int)v) << 16;
  return c.f;
}

// ---------------- fused x conversion + transpose ----------------
__global__ __launch_bounds__(256) void cvt_x_dual(const float* __restrict__ x,
                                                  u16* __restrict__ xbf,
                                                  u16* __restrict__ xT) {
  __shared__ u16 tile[64][68];
  const int t = threadIdx.x;
  const long e0 = (long)blockIdx.x * 64;     // feature tile
  const long l0 = (long)blockIdx.y * 64;     // token tile within batch
  const long b  = blockIdx.z;
  const int tr = t >> 4, tc = t & 15;
#pragma unroll
  for (int i = 0; i < 4; ++i) {
    const int r = tr + i * 16;
    const long gl = b * 4096 + l0 + r;
    float4 v = *reinterpret_cast<const float4*>(x + gl * 1024 + e0 + tc * 4);
    ushort4 o;
    o.x = f2bf(v.x); o.y = f2bf(v.y); o.z = f2bf(v.z); o.w = f2bf(v.w);
    *reinterpret_cast<ushort4*>(xbf + gl * 1024 + e0 + tc * 4) = o;
    *reinterpret_cast<ushort4*>(&tile[r][tc * 4]) = o;
  }
  __syncthreads();
#pragma unroll
  for (int i = 0; i < 4; ++i) {
    const int c = tr + i * 16;
    ushort4 o;
    o.x = tile[tc * 4 + 0][c]; o.y = tile[tc * 4 + 1][c];
    o.z = tile[tc * 4 + 2][c]; o.w = tile[tc * 4 + 3][c];
    *reinterpret_cast<ushort4*>(xT + b * (1024L * 4096) + (e0 + c) * 4096 + l0 + tc * 4) = o;
  }
}

// ---------------- fused conversion of the 4 weight matrices ----------------
__global__ __launch_bounds__(256) void cvt_w4(const float* __restrict__ a, const float* __restrict__ b,
                                              const float* __restrict__ c, const float* __restrict__ d,
                                              u16* __restrict__ oa, u16* __restrict__ ob,
                                              u16* __restrict__ oc, u16* __restrict__ od) {
  int i = blockIdx.x * 256 + threadIdx.x;
  const int which = i >> 18;
  const int j = i & 262143;
  const float* src = which == 0 ? a : which == 1 ? b : which == 2 ? c : d;
  u16* dst = which == 0 ? oa : which == 1 ? ob : which == 2 ? oc : od;
  float4 v = reinterpret_cast<const float4*>(src)[j];
  ushort4 o;
  o.x = f2bf(v.x); o.y = f2bf(v.y); o.z = f2bf(v.z); o.w = f2bf(v.w);
  reinterpret_cast<ushort4*>(dst)[j] = o;
}

// ---------------- bf16 tiled transpose ----------------
__global__ __launch_bounds__(256) void transpose_bf16(
    const u16* __restrict__ src, long sLd, long sZ,
    u16* __restrict__ dst, long dLd, long dZ) {
  __shared__ u16 tile[64][68];
  const int t = threadIdx.x;
  const long r0 = (long)blockIdx.y * 64;
  const long c0 = (long)blockIdx.x * 64;
  const long z = blockIdx.z;
  const int tr = t >> 4, tc = t & 15;
#pragma unroll
  for (int i = 0; i < 4; ++i) {
    const int r = tr + i * 16;
    ushort4 v = *reinterpret_cast<const ushort4*>(src + z * sZ + (r0 + r) * sLd + c0 + tc * 4);
    *reinterpret_cast<ushort4*>(&tile[r][tc * 4]) = v;
  }
  __syncthreads();
#pragma unroll
  for (int i = 0; i < 4; ++i) {
    const int c = tr + i * 16;
    ushort4 o;
    o.x = tile[tc * 4 + 0][c]; o.y = tile[tc * 4 + 1][c];
    o.z = tile[tc * 4 + 2][c]; o.w = tile[tc * 4 + 3][c];
    *reinterpret_cast<ushort4*>(dst + z * dZ + (c0 + c) * dLd + r0 + tc * 4) = o;
  }
}

// ---- shared staging helper: one [128 rows][64 cols] bf16 tile via gload_lds ----
__device__ __forceinline__ void stage_half(const u16* __restrict__ g, long ld, int k0,
                                           u16* dst, int t) {
#pragma unroll
  for (int i = 0; i < 2; ++i) {
    const int c = i * 512 + t;
    const int r = c >> 3;
    const int s = c & 7;
    const int col = ((s ^ (r & 7)) << 3) + k0;   // pre-swizzled global source
    __builtin_amdgcn_global_load_lds((const AS1 void*)(g + (long)r * ld + col),
                                     (AS3 void*)(dst + c * 8), 16, 0, 0);
  }
}

__device__ __forceinline__ bf16x8 frag_ld(const u16* s, int row, int colb) {
  return *reinterpret_cast<const bf16x8*>(
      reinterpret_cast<const char*>(s) + row * 128 + (colb ^ ((row & 7) << 4)));
}

// ---- flattened bijective XCD swizzle: fold (x,y,z) before chunking ----
// total blocks must be % 8 == 0 (true at every call site: 256).
#define XCD_DECODE(TILE)                                                     \
  const int nxy = gridDim.x * gridDim.y;                                     \
  int flat = blockIdx.x + gridDim.x * blockIdx.y + nxy * blockIdx.z;         \
  const int total = nxy * gridDim.z;                                         \
  const int qq = total >> 3;                                                 \
  flat = (flat & 7) * qq + (flat >> 3);                                      \
  const int z = flat / nxy;                                                  \
  const int wg = flat % nxy;                                                 \
  const long m0 = (long)(wg % gridDim.x) * (TILE);                           \
  const long n0 = (long)(wg / gridDim.x) * (TILE);

// ============ 256x256 NT GEMM, BK=64, 8 waves, 4-phase, vmcnt(6)/phase ========
#define BAR_PRE()       do { asm volatile("s_waitcnt vmcnt(6)" ::: "memory"); \
                             __builtin_amdgcn_s_barrier(); \
                             asm volatile("" ::: "memory"); } while (0)
#define BAR_POST()      do { asm volatile("" ::: "memory"); \
                             __builtin_amdgcn_s_barrier(); \
                             asm volatile("" ::: "memory"); } while (0)

template<bool OUT_F32>
__global__ __launch_bounds__(512, 2) void gemm_nt256(
    const u16* __restrict__ A, long lda, long sAz4, long sAz1,
    const u16* __restrict__ B, long ldb, long sBz4, long sBz1,
    void* __restrict__ Cv, long ldc, long sCz4, long sCz1,
    long cBatch, int cShift,
    int K, float scale)
{
  __shared__ u16 sm[2 * 32768] __attribute__((aligned(16)));  // 128 KiB

  const int t = threadIdx.x;
  XCD_DECODE(256);
  const long azoff = (long)(z >> 2) * sAz4 + (long)(z & 3) * sAz1;
  const long bzoff = (long)(z >> 2) * sBz4 + (long)(z & 3) * sBz1;
  const u16* Ab = A + azoff + m0 * lda;
  const u16* Bb = B + bzoff + n0 * ldb;

  const int wid = t >> 6, lane = t & 63;
  const int lhi = lane >> 4, llo = lane & 15;
  const int wm = wid >> 2, wn = wid & 3;

  f32x4 acc[2][4][2][2] = {};
  const int NT = K >> 6;

  stage_half(Ab, lda, 0, sm, t);
  stage_half(Bb + 128 * ldb, ldb, 0, sm + 16384 + 8192, t);
  stage_half(Bb, ldb, 0, sm + 16384, t);
  stage_half(Ab + 128 * lda, lda, 0, sm + 8192, t);
  stage_half(Ab, lda, 64, sm + 32768, t);
  stage_half(Bb + 128 * ldb, ldb, 64, sm + 32768 + 16384 + 8192, t);
  asm volatile("s_waitcnt vmcnt(4)" ::: "memory");
  __builtin_amdgcn_s_barrier();
  asm volatile("" ::: "memory");

  for (int kt = 0; kt < NT; ++kt) {
    const int kb = kt & 1;
    u16* bc = sm + kb * 32768;
    u16* bn = sm + (kb ^ 1) * 32768;
    const u16* sAc = bc;
    const u16* sBc = bc + 16384;
    const int k1 = ((kt + 1 < NT) ? kt + 1 : 0) << 6;
    const int k2 = ((kt + 2 < NT) ? kt + 2 : kt + 2 - NT) << 6;

    bf16x8 a[4][2], bl[2][2], bh[2][2];

    // ph0
#pragma unroll
    for (int fr = 0; fr < 4; ++fr)
#pragma unroll
      for (int kk = 0; kk < 2; ++kk)
        a[fr][kk] = frag_ld(sAc, wm * 64 + fr * 16 + llo, (kk << 6) + (lhi << 4));
#pragma unroll
    for (int fc = 0; fc < 2; ++fc)
#pragma unroll
      for (int kk = 0; kk < 2; ++kk)
        bl[fc][kk] = frag_ld(sBc, wn * 32 + fc * 16 + llo, (kk << 6) + (lhi << 4));
    stage_half(Bb, ldb, k1, bn + 16384, t);
    BAR_PRE();
    __builtin_amdgcn_s_setprio(1);
#pragma unroll
    for (int fr = 0; fr < 4; ++fr)
#pragma unroll
      for (int fc = 0; fc < 2; ++fc)
#pragma unroll
        for (int kk = 0; kk < 2; ++kk)
          acc[0][fr][0][fc] = __builtin_amdgcn_mfma_f32_16x16x32_bf16(a[fr][kk], bl[fc][kk], acc[0][fr][0][fc], 0, 0, 0);
    __builtin_amdgcn_s_setprio(0);
    BAR_POST();

    // ph1
#pragma unroll
    for (int fc = 0; fc < 2; ++fc)
#pragma unroll
      for (int kk = 0; kk < 2; ++kk)
        bh[fc][kk] = frag_ld(sBc, 128 + wn * 32 + fc * 16 + llo, (kk << 6) + (lhi << 4));
    stage_half(Ab + 128 * lda, lda, k1, bn + 8192, t);
    BAR_PRE();
    __builtin_amdgcn_s_setprio(1);
#pragma unroll
    for (int fr = 0; fr < 4; ++fr)
#pragma unroll
      for (int fc = 0; fc < 2; ++fc)
#pragma unroll
        for (int kk = 0; kk < 2; ++kk)
          acc[0][fr][1][fc] = __builtin_amdgcn_mfma_f32_16x16x32_bf16(a[fr][kk], bh[fc][kk], acc[0][fr][1][fc], 0, 0, 0);
    __builtin_amdgcn_s_setprio(0);
    BAR_POST();

    // ph2
#pragma unroll
    for (int fr = 0; fr < 4; ++fr)
#pragma unroll
      for (int kk = 0; kk < 2; ++kk)
        a[fr][kk] = frag_ld(sAc, 128 + wm * 64 + fr * 16 + llo, (kk << 6) + (lhi << 4));
    stage_half(Ab, lda, k2, bc, t);
    BAR_PRE();
    __builtin_amdgcn_s_setprio(1);
#pragma unroll
    for (int fr = 0; fr < 4; ++fr)
#pragma unroll
      for (int fc = 0; fc < 2; ++fc)
#pragma unroll
        for (int kk = 0; kk < 2; ++kk)
          acc[1][fr][1][fc] = __builtin_amdgcn_mfma_f32_16x16x32_bf16(a[fr][kk], bh[fc][kk], acc[1][fr][1][fc], 0, 0, 0);
    __builtin_amdgcn_s_setprio(0);
    BAR_POST();

    // ph3
    stage_half(Bb + 128 * ldb, ldb, k2, bc + 16384 + 8192, t);
    BAR_PRE();
    __builtin_amdgcn_s_setprio(1);
#pragma unroll
    for (int fr = 0; fr < 4; ++fr)
#pragma unroll
      for (int fc = 0; fc < 2; ++fc)
#pragma unroll
        for (int kk = 0; kk < 2; ++kk)
          acc[1][fr][0][fc] = __builtin_amdgcn_mfma_f32_16x16x32_bf16(a[fr][kk], bl[fc][kk], acc[1][fr][0][fc], 0, 0, 0);
    __builtin_amdgcn_s_setprio(0);
    BAR_POST();
  }

  const long cb = n0 >> cShift;
  const long ncol0 = n0 - (cb << cShift);
  const long czoff = (long)(z >> 2) * sCz4 + (long)(z & 3) * sCz1 + cb * cBatch;
#pragma unroll
  for (int ah = 0; ah < 2; ++ah)
#pragma unroll
    for (int fr = 0; fr < 4; ++fr)
#pragma unroll
      for (int e = 0; e < 4; ++e) {
        const long r = m0 + ah * 128 + wm * 64 + fr * 16 + lhi * 4 + e;
#pragma unroll
        for (int bh2 = 0; bh2 < 2; ++bh2)
#pragma unroll
          for (int fc = 0; fc < 2; ++fc) {
            const long col = ncol0 + bh2 * 128 + wn * 32 + fc * 16 + llo;
            const float val = acc[ah][fr][bh2][fc][e] * scale;
            if (OUT_F32)
              ((float*)Cv)[czoff + r * ldc + col] = val;
            else
              ((u16*)Cv)[czoff + r * ldc + col] = f2bf(val);
          }
      }
}

// ===== 128x128 NT GEMM, BK=64, 8 waves, DOUBLE-buffered, 2 blocks/CU =========
// 64 KiB LDS -> 2 co-resident blocks per CU (independent barrier domains):
// block A's MFMA covers block B's stage/barrier/vmcnt (m114 co-scheduling).
// Pacing: prologue stages t0,t1 (8 loads/wave); per iter vmcnt(4) retires
// exactly tile kt's own-wave loads, then barrier -> all portions resident.
// Post-read barrier precedes restage of same buffer (WAR-safe). NT >= 2.
template<bool OUT_F32>
__global__ __launch_bounds__(512, 4) void gemm_nt128d(
    const u16* __restrict__ A, long lda, long sAz,
    const u16* __restrict__ B, long ldb, long sBz,
    void* __restrict__ Cv, long ldc, long sCz,
    int K, float scale)
{
  __shared__ u16 sm[2 * 16384] __attribute__((aligned(16)));  // 64 KiB

  const int t = threadIdx.x;
  XCD_DECODE(128);
  A += (long)z * sAz + m0 * lda;
  B += (long)z * sBz + n0 * ldb;

  const int wid = t >> 6, lane = t & 63;
  const int lhi = lane >> 4, llo = lane & 15;
  const int wr = (wid >> 2) * 64, wc = (wid & 3) * 32;

  f32x4 acc[4][2] = {};
  const int NT = K >> 6;   // >= 2

  stage_half(A, lda, 0, sm, t);
  stage_half(B, ldb, 0, sm + 8192, t);
  stage_half(A, lda, 64, sm + 16384, t);
  stage_half(B, ldb, 64, sm + 16384 + 8192, t);

  for (int kt = 0; kt < NT; ++kt) {
    asm volatile("s_waitcnt vmcnt(4)" ::: "memory");   // tile kt resident (own-wave)
    __builtin_amdgcn_s_barrier();                      // -> all waves' portions resident
    asm volatile("" ::: "memory");
    u16* buf = sm + (kt & 1) * 16384;
    bf16x8 af[4][2], bfr[2][2];
#pragma unroll
    for (int i = 0; i < 4; ++i)
#pragma unroll
      for (int kk = 0; kk < 2; ++kk)
        af[i][kk] = frag_ld(buf, wr + i * 16 + llo, (kk << 6) + (lhi << 4));
#pragma unroll
    for (int j = 0; j < 2; ++j)
#pragma unroll
      for (int kk = 0; kk < 2; ++kk)
        bfr[j][kk] = frag_ld(buf + 8192, wc + j * 16 + llo, (kk << 6) + (lhi << 4));
    __builtin_amdgcn_s_setprio(1);
#pragma unroll
    for (int i = 0; i < 4; ++i)
#pragma unroll
      for (int j = 0; j < 2; ++j)
#pragma unroll
        for (int kk = 0; kk < 2; ++kk)
          acc[i][j] = __builtin_amdgcn_mfma_f32_16x16x32_bf16(af[i][kk], bfr[j][kk], acc[i][j], 0, 0, 0);
    __builtin_amdgcn_s_setprio(0);
    asm volatile("" ::: "memory");
    __builtin_amdgcn_s_barrier();
    asm volatile("" ::: "memory");
    const int k2 = ((kt + 2 < NT) ? kt + 2 : kt + 2 - NT) << 6;   // wrapped-dead at tail
    stage_half(A, lda, k2, buf, t);
    stage_half(B, ldb, k2, buf + 8192, t);
  }

#pragma unroll
  for (int i = 0; i < 4; ++i) {
#pragma unroll
    for (int e = 0; e < 4; ++e) {
      const long r = m0 + wr + i * 16 + lhi * 4 + e;
      if (OUT_F32) {
        float* C = (float*)Cv + (long)z * sCz + r * ldc + n0 + wc + llo;
#pragma unroll
        for (int j = 0; j < 2; ++j) C[j * 16] = acc[i][j][e] * scale;
      } else {
        u16* C = (u16*)Cv + (long)z * sCz + r * ldc + n0 + wc + llo;
#pragma unroll
        for (int j = 0; j < 2; ++j) C[j * 16] = f2bf(acc[i][j][e] * scale);
      }
    }
  }
}

// ---- reduce 4 split-K bf16 partials of G -> bf16 [4][1024][1024] ----
__global__ __launch_bounds__(256) void greduce4b(const u16* __restrict__ gp,
                                                 u16* __restrict__ gb) {
  const long o = (long)blockIdx.x * 256 + threadIdx.x;   // ushort8 index; 512K total
  const long b = o >> 17;
  const long r = o & 131071;
  float s[8] = {};
#pragma unroll
  for (int p = 0; p < 4; ++p) {
    ushort8 u = reinterpret_cast<const ushort8*>(gp)[((b * 4 + p) << 17) + r];
#pragma unroll
    for (int j = 0; j < 8; ++j) s[j] += bf2f(u[j]);
  }
  ushort8 out;
#pragma unroll
  for (int j = 0; j < 8; ++j) out[j] = f2bf(s[j]);
  reinterpret_cast<ushort8*>(gb)[o] = out;
}

// ---- single-pass row softmax: att f32 [4096][1024] -> P bf16 ----
__global__ __launch_bounds__(256) void softmax1(const float* __restrict__ att,
                                                u16* __restrict__ P) {
  const long row = blockIdx.x;
  const int t = threadIdx.x;
  float4 v = reinterpret_cast<const float4*>(att + row * 1024)[t];
  float m = fmaxf(fmaxf(v.x, v.y), fmaxf(v.z, v.w));
#pragma unroll
  for (int off = 32; off > 0; off >>= 1) m = fmaxf(m, __shfl_down(m, off, 64));
  __shared__ float smax[4], ssum[4];
  const int wid = t >> 6, lane = t & 63;
  if (lane == 0) smax[wid] = m;
  __syncthreads();
  m = fmaxf(fmaxf(smax[0], smax[1]), fmaxf(smax[2], smax[3]));
  float e0 = expf(v.x - m), e1 = expf(v.y - m), e2 = expf(v.z - m), e3 = expf(v.w - m);
  float s = e0 + e1 + e2 + e3;
#pragma unroll
  for (int off = 32; off > 0; off >>= 1) s += __shfl_down(s, off, 64);
  if (lane == 0) ssum[wid] = s;
  __syncthreads();
  s = ssum[0] + ssum[1] + ssum[2] + ssum[3];
  float inv = 1.0f / s;
  ushort4 o;
  o.x = f2bf(e0 * inv); o.y = f2bf(e1 * inv); o.z = f2bf(e2 * inv); o.w = f2bf(e3 * inv);
  reinterpret_cast<ushort4*>(P + row * 1024)[t] = o;
}

extern "C" void kernel_launch(void* const* d_in, const int* in_sizes, int n_in,
                              void* d_out, int out_size, void* d_ws, size_t ws_size,
                              hipStream_t stream) {
  const float* x  = (const float*)d_in[0];
  const float* Wq = (const float*)d_in[1];
  const float* Wk = (const float*)d_in[2];
  const float* Wv = (const float*)d_in[3];
  const float* Wo = (const float*)d_in[4];

  const long M1 = 1L << 20;               // 1M elements

  // workspace layout (u16 elements)
  u16* xbf    = (u16*)d_ws;               // [16384][1024]                      16M
  u16* wq     = xbf + 16 * M1;            //                                     1M
  u16* wk     = wq + M1;                  //                                     1M
  u16* wv     = wk + M1;                  //                                     1M
  u16* wo     = wv + M1;                  //                                     1M
  u16* wvT    = wo + M1;                  // Wv^T                                1M
  u16* xT     = wvT + M1;                 // [4][1024 feat][4096 tok]           16M
  u16* gbf    = xT + 16 * M1;             // G bf16 [4][1024][1024]              4M
  u16* tbuf   = gbf + 4 * M1;             // T~ = Wq G                           4M
  u16* pbuf   = tbuf + 4 * M1;            // P (softmax)                         4M
  u16* rtb    = pbuf + 4 * M1;            // R^T                                 4M
  u16* sbuf   = rtb + 4 * M1;             // S = Wo R                            4M
  u16* gpartb = sbuf + 4 * M1;            // G bf16 partials [16][1024][1024]   16M
  float* attf = (float*)d_out;            // att f32 [4][1024][1024] (16 MB)

  dim3 b256(256), b512(512);
  const long NOF = 0;
  const int NSH = 30;

  // conversions + transposes
  cvt_x_dual<<<dim3(16, 64, 4), b256, 0, stream>>>(x, xbf, xT);
  cvt_w4<<<dim3(4096), b256, 0, stream>>>(Wq, Wk, Wv, Wo, wq, wk, wv, wo);
  transpose_bf16<<<dim3(16, 16, 1), b256, 0, stream>>>(wv, 1024, 0, wvT, 1024, 0);

  // G[b] = x[b]^T x[b]  (M=N=1024, K=4096 split 4; z=b*4+p) -> bf16 partials
  gemm_nt256<false><<<dim3(4, 4, 16), b512, 0, stream>>>(
      xT, 4096, 1024L * 4096, 1024, xT, 4096, 1024L * 4096, 1024,
      (void*)gpartb, 1024, 4L << 20, 1L << 20, NOF, NSH, 1024, 1.0f);
  greduce4b<<<dim3(2048), b256, 0, stream>>>(gpartb, gbf);

  // T~[b] = Wq G[b]   (G symmetric -> NT form)
  gemm_nt128d<false><<<dim3(8, 8, 4), b512, 0, stream>>>(
      wq, 1024, 0, gbf, 1024, M1, (void*)tbuf, 1024, M1, 1024, 1.0f);
  // att[b] = T~[b] Wk^T / 32 -> f32 in d_out
  gemm_nt128d<true><<<dim3(8, 8, 4), b512, 0, stream>>>(
      tbuf, 1024, M1, wk, 1024, 0, (void*)attf, 1024, M1, 1024, 1.0f / 32.0f);
  // softmax rows -> P bf16
  softmax1<<<dim3(4096), b256, 0, stream>>>(attf, pbuf);

  // R^T[b]: C[e,k] = sum_j Wv[j,e] P[k,j]
  gemm_nt128d<false><<<dim3(8, 8, 4), b512, 0, stream>>>(
      wvT, 1024, 0, pbuf, 1024, M1, (void*)rtb, 1024, M1, 1024, 1.0f);
  // S[b]: C[e',e] = sum_k Wo[e',k] RT[e,k]
  gemm_nt128d<false><<<dim3(8, 8, 4), b512, 0, stream>>>(
      wo, 1024, 0, rtb, 1024, M1, (void*)sbuf, 1024, M1, 1024, 1.0f);

  // final[b] = x[b] S[b]^T  (M=4096/batch, N=1024, K=1024) -> d_out f32
  gemm_nt256<true><<<dim3(16, 4, 4), b512, 0, stream>>>(
      xbf, 1024, 0, 4096L * 1024, sbuf, 1024, 0, M1,
      d_out, 1024, 0, 4096L * 1024, NOF, NSH, 1024, 1.0f);
}

// Round 14
// 185.671 us; speedup vs baseline: 1.5287x; 1.0132x over previous
//
#include <hip/hip_runtime.h>
#include <hip/hip_bf16.h>

typedef unsigned short u16;
typedef __bf16 bf16x8 __attribute__((ext_vector_type(8)));
typedef float f32x4 __attribute__((ext_vector_type(4)));
typedef unsigned short ushort8 __attribute__((ext_vector_type(8)));

#define AS1 __attribute__((address_space(1)))
#define AS3 __attribute__((address_space(3)))

__device__ inline u16 f2bf(float f) {
  union { float f; unsigned int u; } c; c.f = f;
  unsigned int u = c.u;
  return (u16)((u + 0x7fffu + ((u >> 16) & 1u)) >> 16);
}
__device__ inline float bf2f(u16 v) {
  union { unsigned int u; float f; } c; c.u = ((unsigned int)v) << 16;
  return c.f;
}

// ---------------- fused x conversion + transpose ----------------
__global__ __launch_bounds__(256) void cvt_x_dual(const float* __restrict__ x,
                                                  u16* __restrict__ xbf,
                                                  u16* __restrict__ xT) {
  __shared__ u16 tile[64][68];
  const int t = threadIdx.x;
  const long e0 = (long)blockIdx.x * 64;     // feature tile
  const long l0 = (long)blockIdx.y * 64;     // token tile within batch
  const long b  = blockIdx.z;
  const int tr = t >> 4, tc = t & 15;
#pragma unroll
  for (int i = 0; i < 4; ++i) {
    const int r = tr + i * 16;
    const long gl = b * 4096 + l0 + r;
    float4 v = *reinterpret_cast<const float4*>(x + gl * 1024 + e0 + tc * 4);
    ushort4 o;
    o.x = f2bf(v.x); o.y = f2bf(v.y); o.z = f2bf(v.z); o.w = f2bf(v.w);
    *reinterpret_cast<ushort4*>(xbf + gl * 1024 + e0 + tc * 4) = o;
    *reinterpret_cast<ushort4*>(&tile[r][tc * 4]) = o;
  }
  __syncthreads();
#pragma unroll
  for (int i = 0; i < 4; ++i) {
    const int c = tr + i * 16;
    ushort4 o;
    o.x = tile[tc * 4 + 0][c]; o.y = tile[tc * 4 + 1][c];
    o.z = tile[tc * 4 + 2][c]; o.w = tile[tc * 4 + 3][c];
    *reinterpret_cast<ushort4*>(xT + b * (1024L * 4096) + (e0 + c) * 4096 + l0 + tc * 4) = o;
  }
}

// ---------------- fused conversion of the 4 weight matrices ----------------
__global__ __launch_bounds__(256) void cvt_w4(const float* __restrict__ a, const float* __restrict__ b,
                                              const float* __restrict__ c, const float* __restrict__ d,
                                              u16* __restrict__ oa, u16* __restrict__ ob,
                                              u16* __restrict__ oc, u16* __restrict__ od) {
  int i = blockIdx.x * 256 + threadIdx.x;
  const int which = i >> 18;
  const int j = i & 262143;
  const float* src = which == 0 ? a : which == 1 ? b : which == 2 ? c : d;
  u16* dst = which == 0 ? oa : which == 1 ? ob : which == 2 ? oc : od;
  float4 v = reinterpret_cast<const float4*>(src)[j];
  ushort4 o;
  o.x = f2bf(v.x); o.y = f2bf(v.y); o.z = f2bf(v.z); o.w = f2bf(v.w);
  reinterpret_cast<ushort4*>(dst)[j] = o;
}

// ---------------- bf16 tiled transpose ----------------
__global__ __launch_bounds__(256) void transpose_bf16(
    const u16* __restrict__ src, long sLd, long sZ,
    u16* __restrict__ dst, long dLd, long dZ) {
  __shared__ u16 tile[64][68];
  const int t = threadIdx.x;
  const long r0 = (long)blockIdx.y * 64;
  const long c0 = (long)blockIdx.x * 64;
  const long z = blockIdx.z;
  const int tr = t >> 4, tc = t & 15;
#pragma unroll
  for (int i = 0; i < 4; ++i) {
    const int r = tr + i * 16;
    ushort4 v = *reinterpret_cast<const ushort4*>(src + z * sZ + (r0 + r) * sLd + c0 + tc * 4);
    *reinterpret_cast<ushort4*>(&tile[r][tc * 4]) = v;
  }
  __syncthreads();
#pragma unroll
  for (int i = 0; i < 4; ++i) {
    const int c = tr + i * 16;
    ushort4 o;
    o.x = tile[tc * 4 + 0][c]; o.y = tile[tc * 4 + 1][c];
    o.z = tile[tc * 4 + 2][c]; o.w = tile[tc * 4 + 3][c];
    *reinterpret_cast<ushort4*>(dst + z * dZ + (c0 + c) * dLd + r0 + tc * 4) = o;
  }
}

// ---- staging helpers via gload_lds (pre-swizzled source) ----
__device__ __forceinline__ void stage_half(const u16* __restrict__ g, long ld, int k0,
                                           u16* dst, int t) {
#pragma unroll
  for (int i = 0; i < 2; ++i) {
    const int c = i * 512 + t;
    const int r = c >> 3;
    const int s = c & 7;
    const int col = ((s ^ (r & 7)) << 3) + k0;
    __builtin_amdgcn_global_load_lds((const AS1 void*)(g + (long)r * ld + col),
                                     (AS3 void*)(dst + c * 8), 16, 0, 0);
  }
}

// 256-thread variant: N16 chunks per thread (rows = N16*256/8)
template<int N16>
__device__ __forceinline__ void stage_rows256(const u16* __restrict__ g, long ld, int k0,
                                              u16* dst, int t) {
#pragma unroll
  for (int i = 0; i < N16; ++i) {
    const int c = i * 256 + t;
    const int r = c >> 3;
    const int s = c & 7;
    const int col = ((s ^ (r & 7)) << 3) + k0;
    __builtin_amdgcn_global_load_lds((const AS1 void*)(g + (long)r * ld + col),
                                     (AS3 void*)(dst + c * 8), 16, 0, 0);
  }
}

__device__ __forceinline__ bf16x8 frag_ld(const u16* s, int row, int colb) {
  return *reinterpret_cast<const bf16x8*>(
      reinterpret_cast<const char*>(s) + row * 128 + (colb ^ ((row & 7) << 4)));
}

// ---- flattened bijective XCD swizzle (total % 8 == 0 at all call sites) ----
#define XCD_DECODE2(TM, TN)                                                  \
  const int nxy = gridDim.x * gridDim.y;                                     \
  int flat = blockIdx.x + gridDim.x * blockIdx.y + nxy * blockIdx.z;         \
  const int total = nxy * gridDim.z;                                         \
  const int qq = total >> 3;                                                 \
  flat = (flat & 7) * qq + (flat >> 3);                                      \
  const int z = flat / nxy;                                                  \
  const int wg = flat % nxy;                                                 \
  const long m0 = (long)(wg % gridDim.x) * (TM);                             \
  const long n0 = (long)(wg / gridDim.x) * (TN);

// ============ 256x256 NT GEMM, BK=64, 8 waves, 4-phase, vmcnt(6)/phase ========
#define BAR_PRE()       do { asm volatile("s_waitcnt vmcnt(6)" ::: "memory"); \
                             __builtin_amdgcn_s_barrier(); \
                             asm volatile("" ::: "memory"); } while (0)
#define BAR_POST()      do { asm volatile("" ::: "memory"); \
                             __builtin_amdgcn_s_barrier(); \
                             asm volatile("" ::: "memory"); } while (0)

template<bool OUT_F32>
__global__ __launch_bounds__(512, 2) void gemm_nt256(
    const u16* __restrict__ A, long lda, long sAz4, long sAz1,
    const u16* __restrict__ B, long ldb, long sBz4, long sBz1,
    void* __restrict__ Cv, long ldc, long sCz4, long sCz1,
    long cBatch, int cShift,
    int K, float scale)
{
  __shared__ u16 sm[2 * 32768] __attribute__((aligned(16)));  // 128 KiB

  const int t = threadIdx.x;
  XCD_DECODE2(256, 256);
  const long azoff = (long)(z >> 2) * sAz4 + (long)(z & 3) * sAz1;
  const long bzoff = (long)(z >> 2) * sBz4 + (long)(z & 3) * sBz1;
  const u16* Ab = A + azoff + m0 * lda;
  const u16* Bb = B + bzoff + n0 * ldb;

  const int wid = t >> 6, lane = t & 63;
  const int lhi = lane >> 4, llo = lane & 15;
  const int wm = wid >> 2, wn = wid & 3;

  f32x4 acc[2][4][2][2] = {};
  const int NT = K >> 6;

  stage_half(Ab, lda, 0, sm, t);
  stage_half(Bb + 128 * ldb, ldb, 0, sm + 16384 + 8192, t);
  stage_half(Bb, ldb, 0, sm + 16384, t);
  stage_half(Ab + 128 * lda, lda, 0, sm + 8192, t);
  stage_half(Ab, lda, 64, sm + 32768, t);
  stage_half(Bb + 128 * ldb, ldb, 64, sm + 32768 + 16384 + 8192, t);
  asm volatile("s_waitcnt vmcnt(4)" ::: "memory");
  __builtin_amdgcn_s_barrier();
  asm volatile("" ::: "memory");

  for (int kt = 0; kt < NT; ++kt) {
    const int kb = kt & 1;
    u16* bc = sm + kb * 32768;
    u16* bn = sm + (kb ^ 1) * 32768;
    const u16* sAc = bc;
    const u16* sBc = bc + 16384;
    const int k1 = ((kt + 1 < NT) ? kt + 1 : 0) << 6;
    const int k2 = ((kt + 2 < NT) ? kt + 2 : kt + 2 - NT) << 6;

    bf16x8 a[4][2], bl[2][2], bh[2][2];

    // ph0
#pragma unroll
    for (int fr = 0; fr < 4; ++fr)
#pragma unroll
      for (int kk = 0; kk < 2; ++kk)
        a[fr][kk] = frag_ld(sAc, wm * 64 + fr * 16 + llo, (kk << 6) + (lhi << 4));
#pragma unroll
    for (int fc = 0; fc < 2; ++fc)
#pragma unroll
      for (int kk = 0; kk < 2; ++kk)
        bl[fc][kk] = frag_ld(sBc, wn * 32 + fc * 16 + llo, (kk << 6) + (lhi << 4));
    stage_half(Bb, ldb, k1, bn + 16384, t);
    BAR_PRE();
    __builtin_amdgcn_s_setprio(1);
#pragma unroll
    for (int fr = 0; fr < 4; ++fr)
#pragma unroll
      for (int fc = 0; fc < 2; ++fc)
#pragma unroll
        for (int kk = 0; kk < 2; ++kk)
          acc[0][fr][0][fc] = __builtin_amdgcn_mfma_f32_16x16x32_bf16(a[fr][kk], bl[fc][kk], acc[0][fr][0][fc], 0, 0, 0);
    __builtin_amdgcn_s_setprio(0);
    BAR_POST();

    // ph1
#pragma unroll
    for (int fc = 0; fc < 2; ++fc)
#pragma unroll
      for (int kk = 0; kk < 2; ++kk)
        bh[fc][kk] = frag_ld(sBc, 128 + wn * 32 + fc * 16 + llo, (kk << 6) + (lhi << 4));
    stage_half(Ab + 128 * lda, lda, k1, bn + 8192, t);
    BAR_PRE();
    __builtin_amdgcn_s_setprio(1);
#pragma unroll
    for (int fr = 0; fr < 4; ++fr)
#pragma unroll
      for (int fc = 0; fc < 2; ++fc)
#pragma unroll
        for (int kk = 0; kk < 2; ++kk)
          acc[0][fr][1][fc] = __builtin_amdgcn_mfma_f32_16x16x32_bf16(a[fr][kk], bh[fc][kk], acc[0][fr][1][fc], 0, 0, 0);
    __builtin_amdgcn_s_setprio(0);
    BAR_POST();

    // ph2
#pragma unroll
    for (int fr = 0; fr < 4; ++fr)
#pragma unroll
      for (int kk = 0; kk < 2; ++kk)
        a[fr][kk] = frag_ld(sAc, 128 + wm * 64 + fr * 16 + llo, (kk << 6) + (lhi << 4));
    stage_half(Ab, lda, k2, bc, t);
    BAR_PRE();
    __builtin_amdgcn_s_setprio(1);
#pragma unroll
    for (int fr = 0; fr < 4; ++fr)
#pragma unroll
      for (int fc = 0; fc < 2; ++fc)
#pragma unroll
        for (int kk = 0; kk < 2; ++kk)
          acc[1][fr][1][fc] = __builtin_amdgcn_mfma_f32_16x16x32_bf16(a[fr][kk], bh[fc][kk], acc[1][fr][1][fc], 0, 0, 0);
    __builtin_amdgcn_s_setprio(0);
    BAR_POST();

    // ph3
    stage_half(Bb + 128 * ldb, ldb, k2, bc + 16384 + 8192, t);
    BAR_PRE();
    __builtin_amdgcn_s_setprio(1);
#pragma unroll
    for (int fr = 0; fr < 4; ++fr)
#pragma unroll
      for (int fc = 0; fc < 2; ++fc)
#pragma unroll
        for (int kk = 0; kk < 2; ++kk)
          acc[1][fr][0][fc] = __builtin_amdgcn_mfma_f32_16x16x32_bf16(a[fr][kk], bl[fc][kk], acc[1][fr][0][fc], 0, 0, 0);
    __builtin_amdgcn_s_setprio(0);
    BAR_POST();
  }

  const long cb = n0 >> cShift;
  const long ncol0 = n0 - (cb << cShift);
  const long czoff = (long)(z >> 2) * sCz4 + (long)(z & 3) * sCz1 + cb * cBatch;
#pragma unroll
  for (int ah = 0; ah < 2; ++ah)
#pragma unroll
    for (int fr = 0; fr < 4; ++fr)
#pragma unroll
      for (int e = 0; e < 4; ++e) {
        const long r = m0 + ah * 128 + wm * 64 + fr * 16 + lhi * 4 + e;
#pragma unroll
        for (int bh2 = 0; bh2 < 2; ++bh2)
#pragma unroll
          for (int fc = 0; fc < 2; ++fc) {
            const long col = ncol0 + bh2 * 128 + wn * 32 + fc * 16 + llo;
            const float val = acc[ah][fr][bh2][fc][e] * scale;
            if (OUT_F32)
              ((float*)Cv)[czoff + r * ldc + col] = val;
            else
              ((u16*)Cv)[czoff + r * ldc + col] = f2bf(val);
          }
      }
}

// ===== 128x64 NT GEMM, BK=64, 4 waves (2x2), double-buffered, 3 blocks/CU ====
// Small-GEMM engine. Tile = A[128][64] + B[64][64] = 24 KiB; 2 buffers = 48 KiB
// -> 3 blocks/CU (144 KiB), 512-block grids -> 2 blocks actually co-resident:
// block A's MFMA covers block B's stage/vmcnt/barrier (m114). Staging: 6
// gload_lds/thread/tile (4 A + 2 B); prologue 2 tiles = 12 outstanding; per
// iter vmcnt(6) retires exactly tile kt. Restage after post-read barrier
// (WAR-safe); wrapped-dead tail keeps counts uniform. NT >= 2.
template<bool OUT_F32>
__global__ __launch_bounds__(256, 3) void gemm_nt128x64(
    const u16* __restrict__ A, long lda, long sAz,
    const u16* __restrict__ B, long ldb, long sBz,
    void* __restrict__ Cv, long ldc, long sCz,
    int K, float scale)
{
  __shared__ u16 sm[2 * 12288] __attribute__((aligned(16)));  // 48 KiB

  const int t = threadIdx.x;
  XCD_DECODE2(128, 64);
  A += (long)z * sAz + m0 * lda;
  B += (long)z * sBz + n0 * ldb;

  const int wid = t >> 6, lane = t & 63;
  const int lhi = lane >> 4, llo = lane & 15;
  const int wr = (wid >> 1) * 64, wc = (wid & 1) * 32;

  f32x4 acc[4][2] = {};
  const int NT = K >> 6;   // >= 2

  stage_rows256<4>(A, lda, 0, sm, t);
  stage_rows256<2>(B, ldb, 0, sm + 8192, t);
  stage_rows256<4>(A, lda, 64, sm + 12288, t);
  stage_rows256<2>(B, ldb, 64, sm + 12288 + 8192, t);

  for (int kt = 0; kt < NT; ++kt) {
    asm volatile("s_waitcnt vmcnt(6)" ::: "memory");   // tile kt resident (own-wave)
    __builtin_amdgcn_s_barrier();                      // -> all waves' portions resident
    asm volatile("" ::: "memory");
    u16* buf = sm + (kt & 1) * 12288;
    bf16x8 af[4][2], bfr[2][2];
#pragma unroll
    for (int i = 0; i < 4; ++i)
#pragma unroll
      for (int kk = 0; kk < 2; ++kk)
        af[i][kk] = frag_ld(buf, wr + i * 16 + llo, (kk << 6) + (lhi << 4));
#pragma unroll
    for (int j = 0; j < 2; ++j)
#pragma unroll
      for (int kk = 0; kk < 2; ++kk)
        bfr[j][kk] = frag_ld(buf + 8192, wc + j * 16 + llo, (kk << 6) + (lhi << 4));
    __builtin_amdgcn_s_setprio(1);
#pragma unroll
    for (int i = 0; i < 4; ++i)
#pragma unroll
      for (int j = 0; j < 2; ++j)
#pragma unroll
        for (int kk = 0; kk < 2; ++kk)
          acc[i][j] = __builtin_amdgcn_mfma_f32_16x16x32_bf16(af[i][kk], bfr[j][kk], acc[i][j], 0, 0, 0);
    __builtin_amdgcn_s_setprio(0);
    asm volatile("" ::: "memory");
    __builtin_amdgcn_s_barrier();
    asm volatile("" ::: "memory");
    const int k2 = ((kt + 2 < NT) ? kt + 2 : kt + 2 - NT) << 6;   // wrapped-dead at tail
    stage_rows256<4>(A, lda, k2, buf, t);
    stage_rows256<2>(B, ldb, k2, buf + 8192, t);
  }

#pragma unroll
  for (int i = 0; i < 4; ++i) {
#pragma unroll
    for (int e = 0; e < 4; ++e) {
      const long r = m0 + wr + i * 16 + lhi * 4 + e;
      if (OUT_F32) {
        float* C = (float*)Cv + (long)z * sCz + r * ldc + n0 + wc + llo;
#pragma unroll
        for (int j = 0; j < 2; ++j) C[j * 16] = acc[i][j][e] * scale;
      } else {
        u16* C = (u16*)Cv + (long)z * sCz + r * ldc + n0 + wc + llo;
#pragma unroll
        for (int j = 0; j < 2; ++j) C[j * 16] = f2bf(acc[i][j][e] * scale);
      }
    }
  }
}

// ---- reduce 4 split-K bf16 partials of G -> bf16 [4][1024][1024] ----
__global__ __launch_bounds__(256) void greduce4b(const u16* __restrict__ gp,
                                                 u16* __restrict__ gb) {
  const long o = (long)blockIdx.x * 256 + threadIdx.x;   // ushort8 index; 512K total
  const long b = o >> 17;
  const long r = o & 131071;
  float s[8] = {};
#pragma unroll
  for (int p = 0; p < 4; ++p) {
    ushort8 u = reinterpret_cast<const ushort8*>(gp)[((b * 4 + p) << 17) + r];
#pragma unroll
    for (int j = 0; j < 8; ++j) s[j] += bf2f(u[j]);
  }
  ushort8 out;
#pragma unroll
  for (int j = 0; j < 8; ++j) out[j] = f2bf(s[j]);
  reinterpret_cast<ushort8*>(gb)[o] = out;
}

// ---- single-pass row softmax: att f32 [4096][1024] -> P bf16 ----
__global__ __launch_bounds__(256) void softmax1(const float* __restrict__ att,
                                                u16* __restrict__ P) {
  const long row = blockIdx.x;
  const int t = threadIdx.x;
  float4 v = reinterpret_cast<const float4*>(att + row * 1024)[t];
  float m = fmaxf(fmaxf(v.x, v.y), fmaxf(v.z, v.w));
#pragma unroll
  for (int off = 32; off > 0; off >>= 1) m = fmaxf(m, __shfl_down(m, off, 64));
  __shared__ float smax[4], ssum[4];
  const int wid = t >> 6, lane = t & 63;
  if (lane == 0) smax[wid] = m;
  __syncthreads();
  m = fmaxf(fmaxf(smax[0], smax[1]), fmaxf(smax[2], smax[3]));
  float e0 = expf(v.x - m), e1 = expf(v.y - m), e2 = expf(v.z - m), e3 = expf(v.w - m);
  float s = e0 + e1 + e2 + e3;
#pragma unroll
  for (int off = 32; off > 0; off >>= 1) s += __shfl_down(s, off, 64);
  if (lane == 0) ssum[wid] = s;
  __syncthreads();
  s = ssum[0] + ssum[1] + ssum[2] + ssum[3];
  float inv = 1.0f / s;
  ushort4 o;
  o.x = f2bf(e0 * inv); o.y = f2bf(e1 * inv); o.z = f2bf(e2 * inv); o.w = f2bf(e3 * inv);
  reinterpret_cast<ushort4*>(P + row * 1024)[t] = o;
}

extern "C" void kernel_launch(void* const* d_in, const int* in_sizes, int n_in,
                              void* d_out, int out_size, void* d_ws, size_t ws_size,
                              hipStream_t stream) {
  const float* x  = (const float*)d_in[0];
  const float* Wq = (const float*)d_in[1];
  const float* Wk = (const float*)d_in[2];
  const float* Wv = (const float*)d_in[3];
  const float* Wo = (const float*)d_in[4];

  const long M1 = 1L << 20;               // 1M elements

  // workspace layout (u16 elements)
  u16* xbf    = (u16*)d_ws;               // [16384][1024]                      16M
  u16* wq     = xbf + 16 * M1;            //                                     1M
  u16* wk     = wq + M1;                  //                                     1M
  u16* wv     = wk + M1;                  //                                     1M
  u16* wo     = wv + M1;                  //                                     1M
  u16* wvT    = wo + M1;                  // Wv^T                                1M
  u16* xT     = wvT + M1;                 // [4][1024 feat][4096 tok]           16M
  u16* gbf    = xT + 16 * M1;             // G bf16 [4][1024][1024]              4M
  u16* tbuf   = gbf + 4 * M1;             // T~ = Wq G                           4M
  u16* pbuf   = tbuf + 4 * M1;            // P (softmax)                         4M
  u16* rtb    = pbuf + 4 * M1;            // R^T                                 4M
  u16* sbuf   = rtb + 4 * M1;             // S = Wo R                            4M
  u16* gpartb = sbuf + 4 * M1;            // G bf16 partials [16][1024][1024]   16M
  float* attf = (float*)d_out;            // att f32 [4][1024][1024] (16 MB)

  dim3 b256(256), b512(512);
  const long NOF = 0;
  const int NSH = 30;

  // conversions + transposes
  cvt_x_dual<<<dim3(16, 64, 4), b256, 0, stream>>>(x, xbf, xT);
  cvt_w4<<<dim3(4096), b256, 0, stream>>>(Wq, Wk, Wv, Wo, wq, wk, wv, wo);
  transpose_bf16<<<dim3(16, 16, 1), b256, 0, stream>>>(wv, 1024, 0, wvT, 1024, 0);

  // G[b] = x[b]^T x[b]  (M=N=1024, K=4096 split 4; z=b*4+p) -> bf16 partials
  gemm_nt256<false><<<dim3(4, 4, 16), b512, 0, stream>>>(
      xT, 4096, 1024L * 4096, 1024, xT, 4096, 1024L * 4096, 1024,
      (void*)gpartb, 1024, 4L << 20, 1L << 20, NOF, NSH, 1024, 1.0f);
  greduce4b<<<dim3(2048), b256, 0, stream>>>(gpartb, gbf);

  // T~[b] = Wq G[b]   (G symmetric -> NT form)
  gemm_nt128x64<false><<<dim3(8, 16, 4), b256, 0, stream>>>(
      wq, 1024, 0, gbf, 1024, M1, (void*)tbuf, 1024, M1, 1024, 1.0f);
  // att[b] = T~[b] Wk^T / 32 -> f32 in d_out
  gemm_nt128x64<true><<<dim3(8, 16, 4), b256, 0, stream>>>(
      tbuf, 1024, M1, wk, 1024, 0, (void*)attf, 1024, M1, 1024, 1.0f / 32.0f);
  // softmax rows -> P bf16
  softmax1<<<dim3(4096), b256, 0, stream>>>(attf, pbuf);

  // R^T[b]: C[e,k] = sum_j Wv[j,e] P[k,j]
  gemm_nt128x64<false><<<dim3(8, 16, 4), b256, 0, stream>>>(
      wvT, 1024, 0, pbuf, 1024, M1, (void*)rtb, 1024, M1, 1024, 1.0f);
  // S[b]: C[e',e] = sum_k Wo[e',k] RT[e,k]
  gemm_nt128x64<false><<<dim3(8, 16, 4), b256, 0, stream>>>(
      wo, 1024, 0, rtb, 1024, M1, (void*)sbuf, 1024, M1, 1024, 1.0f);

  // final[b] = x[b] S[b]^T  (M=4096/batch, N=1024, K=1024) -> d_out f32
  gemm_nt256<true><<<dim3(16, 4, 4), b512, 0, stream>>>(
      xbf, 1024, 0, 4096L * 1024, sbuf, 1024, 0, M1,
      d_out, 1024, 0, 4096L * 1024, NOF, NSH, 1024, 1.0f);
}

// Round 15
// 183.795 us; speedup vs baseline: 1.5443x; 1.0102x over previous
//
#include <hip/hip_runtime.h>
#include <hip/hip_bf16.h>

typedef unsigned short u16;
typedef __bf16 bf16x8 __attribute__((ext_vector_type(8)));
typedef float f32x4 __attribute__((ext_vector_type(4)));
typedef unsigned short ushort8 __attribute__((ext_vector_type(8)));

#define AS1 __attribute__((address_space(1)))
#define AS3 __attribute__((address_space(3)))

__device__ inline u16 f2bf(float f) {
  union { float f; unsigned int u; } c; c.f = f;
  unsigned int u = c.u;
  return (u16)((u + 0x7fffu + ((u >> 16) & 1u)) >> 16);
}
__device__ inline float bf2f(u16 v) {
  union { unsigned int u; float f; } c; c.u = ((unsigned int)v) << 16;
  return c.f;
}

// ---------------- fused x conversion + transpose ----------------
__global__ __launch_bounds__(256) void cvt_x_dual(const float* __restrict__ x,
                                                  u16* __restrict__ xbf,
                                                  u16* __restrict__ xT) {
  __shared__ u16 tile[64][68];
  const int t = threadIdx.x;
  const long e0 = (long)blockIdx.x * 64;     // feature tile
  const long l0 = (long)blockIdx.y * 64;     // token tile within batch
  const long b  = blockIdx.z;
  const int tr = t >> 4, tc = t & 15;
#pragma unroll
  for (int i = 0; i < 4; ++i) {
    const int r = tr + i * 16;
    const long gl = b * 4096 + l0 + r;
    float4 v = *reinterpret_cast<const float4*>(x + gl * 1024 + e0 + tc * 4);
    ushort4 o;
    o.x = f2bf(v.x); o.y = f2bf(v.y); o.z = f2bf(v.z); o.w = f2bf(v.w);
    *reinterpret_cast<ushort4*>(xbf + gl * 1024 + e0 + tc * 4) = o;
    *reinterpret_cast<ushort4*>(&tile[r][tc * 4]) = o;
  }
  __syncthreads();
#pragma unroll
  for (int i = 0; i < 4; ++i) {
    const int c = tr + i * 16;
    ushort4 o;
    o.x = tile[tc * 4 + 0][c]; o.y = tile[tc * 4 + 1][c];
    o.z = tile[tc * 4 + 2][c]; o.w = tile[tc * 4 + 3][c];
    *reinterpret_cast<ushort4*>(xT + b * (1024L * 4096) + (e0 + c) * 4096 + l0 + tc * 4) = o;
  }
}

// ---------------- fused conversion of the 4 weight matrices ----------------
__global__ __launch_bounds__(256) void cvt_w4(const float* __restrict__ a, const float* __restrict__ b,
                                              const float* __restrict__ c, const float* __restrict__ d,
                                              u16* __restrict__ oa, u16* __restrict__ ob,
                                              u16* __restrict__ oc, u16* __restrict__ od) {
  int i = blockIdx.x * 256 + threadIdx.x;
  const int which = i >> 18;
  const int j = i & 262143;
  const float* src = which == 0 ? a : which == 1 ? b : which == 2 ? c : d;
  u16* dst = which == 0 ? oa : which == 1 ? ob : which == 2 ? oc : od;
  float4 v = reinterpret_cast<const float4*>(src)[j];
  ushort4 o;
  o.x = f2bf(v.x); o.y = f2bf(v.y); o.z = f2bf(v.z); o.w = f2bf(v.w);
  reinterpret_cast<ushort4*>(dst)[j] = o;
}

// ---------------- bf16 tiled transpose ----------------
__global__ __launch_bounds__(256) void transpose_bf16(
    const u16* __restrict__ src, long sLd, long sZ,
    u16* __restrict__ dst, long dLd, long dZ) {
  __shared__ u16 tile[64][68];
  const int t = threadIdx.x;
  const long r0 = (long)blockIdx.y * 64;
  const long c0 = (long)blockIdx.x * 64;
  const long z = blockIdx.z;
  const int tr = t >> 4, tc = t & 15;
#pragma unroll
  for (int i = 0; i < 4; ++i) {
    const int r = tr + i * 16;
    ushort4 v = *reinterpret_cast<const ushort4*>(src + z * sZ + (r0 + r) * sLd + c0 + tc * 4);
    *reinterpret_cast<ushort4*>(&tile[r][tc * 4]) = v;
  }
  __syncthreads();
#pragma unroll
  for (int i = 0; i < 4; ++i) {
    const int c = tr + i * 16;
    ushort4 o;
    o.x = tile[tc * 4 + 0][c]; o.y = tile[tc * 4 + 1][c];
    o.z = tile[tc * 4 + 2][c]; o.w = tile[tc * 4 + 3][c];
    *reinterpret_cast<ushort4*>(dst + z * dZ + (c0 + c) * dLd + r0 + tc * 4) = o;
  }
}

// ---- staging helpers via gload_lds (pre-swizzled source) ----
__device__ __forceinline__ void stage_half(const u16* __restrict__ g, long ld, int k0,
                                           u16* dst, int t) {
#pragma unroll
  for (int i = 0; i < 2; ++i) {
    const int c = i * 512 + t;
    const int r = c >> 3;
    const int s = c & 7;
    const int col = ((s ^ (r & 7)) << 3) + k0;
    __builtin_amdgcn_global_load_lds((const AS1 void*)(g + (long)r * ld + col),
                                     (AS3 void*)(dst + c * 8), 16, 0, 0);
  }
}

// 256-thread variant: N16 chunks per thread (rows = N16*256/8)
template<int N16>
__device__ __forceinline__ void stage_rows256(const u16* __restrict__ g, long ld, int k0,
                                              u16* dst, int t) {
#pragma unroll
  for (int i = 0; i < N16; ++i) {
    const int c = i * 256 + t;
    const int r = c >> 3;
    const int s = c & 7;
    const int col = ((s ^ (r & 7)) << 3) + k0;
    __builtin_amdgcn_global_load_lds((const AS1 void*)(g + (long)r * ld + col),
                                     (AS3 void*)(dst + c * 8), 16, 0, 0);
  }
}

__device__ __forceinline__ bf16x8 frag_ld(const u16* s, int row, int colb) {
  return *reinterpret_cast<const bf16x8*>(
      reinterpret_cast<const char*>(s) + row * 128 + (colb ^ ((row & 7) << 4)));
}

// ---- flattened bijective XCD swizzle (total % 8 == 0 at all call sites) ----
#define XCD_DECODE2(TM, TN)                                                  \
  const int nxy = gridDim.x * gridDim.y;                                     \
  int flat = blockIdx.x + gridDim.x * blockIdx.y + nxy * blockIdx.z;         \
  const int total = nxy * gridDim.z;                                         \
  const int qq = total >> 3;                                                 \
  flat = (flat & 7) * qq + (flat >> 3);                                      \
  const int z = flat / nxy;                                                  \
  const int wg = flat % nxy;                                                 \
  const long m0 = (long)(wg % gridDim.x) * (TM);                             \
  const long n0 = (long)(wg / gridDim.x) * (TN);

// ============ 256x256 NT GEMM, BK=64, 8 waves, 4-phase, vmcnt(6)/phase ========
// R15 change: read-balance 12/4/8/0 -> 0/4/8/12. ph3 pre-reads NEXT tile's
// A-lo + B-lo (safe: ph3's vmcnt(6) retires B0(t+1), the only outstanding
// prerequisite; A-lo(t+1) staged at ph2(t-1) is long retired), held in
// persistent registers so ph0 has ZERO ds_reads before its MFMA.
#define BAR_PRE()       do { asm volatile("s_waitcnt vmcnt(6)" ::: "memory"); \
                             __builtin_amdgcn_s_barrier(); \
                             asm volatile("" ::: "memory"); } while (0)
#define BAR_POST()      do { asm volatile("" ::: "memory"); \
                             __builtin_amdgcn_s_barrier(); \
                             asm volatile("" ::: "memory"); } while (0)

template<bool OUT_F32>
__global__ __launch_bounds__(512, 2) void gemm_nt256(
    const u16* __restrict__ A, long lda, long sAz4, long sAz1,
    const u16* __restrict__ B, long ldb, long sBz4, long sBz1,
    void* __restrict__ Cv, long ldc, long sCz4, long sCz1,
    long cBatch, int cShift,
    int K, float scale)
{
  __shared__ u16 sm[2 * 32768] __attribute__((aligned(16)));  // 128 KiB

  const int t = threadIdx.x;
  XCD_DECODE2(256, 256);
  const long azoff = (long)(z >> 2) * sAz4 + (long)(z & 3) * sAz1;
  const long bzoff = (long)(z >> 2) * sBz4 + (long)(z & 3) * sBz1;
  const u16* Ab = A + azoff + m0 * lda;
  const u16* Bb = B + bzoff + n0 * ldb;

  const int wid = t >> 6, lane = t & 63;
  const int lhi = lane >> 4, llo = lane & 15;
  const int wm = wid >> 2, wn = wid & 3;

  f32x4 acc[2][4][2][2] = {};
  bf16x8 aLo[4][2], bl[2][2];    // persistent across iterations
  const int NT = K >> 6;

  stage_half(Ab, lda, 0, sm, t);
  stage_half(Bb + 128 * ldb, ldb, 0, sm + 16384 + 8192, t);
  stage_half(Bb, ldb, 0, sm + 16384, t);
  stage_half(Ab + 128 * lda, lda, 0, sm + 8192, t);
  stage_half(Ab, lda, 64, sm + 32768, t);
  stage_half(Bb + 128 * ldb, ldb, 64, sm + 32768 + 16384 + 8192, t);
  asm volatile("s_waitcnt vmcnt(4)" ::: "memory");
  __builtin_amdgcn_s_barrier();
  asm volatile("" ::: "memory");
  // pre-read tile0's A-lo + B-lo
#pragma unroll
  for (int fr = 0; fr < 4; ++fr)
#pragma unroll
    for (int kk = 0; kk < 2; ++kk)
      aLo[fr][kk] = frag_ld(sm, wm * 64 + fr * 16 + llo, (kk << 6) + (lhi << 4));
#pragma unroll
  for (int fc = 0; fc < 2; ++fc)
#pragma unroll
    for (int kk = 0; kk < 2; ++kk)
      bl[fc][kk] = frag_ld(sm + 16384, wn * 32 + fc * 16 + llo, (kk << 6) + (lhi << 4));

  for (int kt = 0; kt < NT; ++kt) {
    const int kb = kt & 1;
    u16* bc = sm + kb * 32768;
    u16* bn = sm + (kb ^ 1) * 32768;
    const u16* sAc = bc;
    const u16* sBc = bc + 16384;
    const int k1 = ((kt + 1 < NT) ? kt + 1 : 0) << 6;
    const int k2 = ((kt + 2 < NT) ? kt + 2 : kt + 2 - NT) << 6;

    bf16x8 aHi[4][2], bh[2][2];

    // ph0: stage B0(t+1); NO ds_reads; MFMA (Alo,Blo) from persistent regs
    stage_half(Bb, ldb, k1, bn + 16384, t);
    BAR_PRE();
    __builtin_amdgcn_s_setprio(1);
#pragma unroll
    for (int fr = 0; fr < 4; ++fr)
#pragma unroll
      for (int fc = 0; fc < 2; ++fc)
#pragma unroll
        for (int kk = 0; kk < 2; ++kk)
          acc[0][fr][0][fc] = __builtin_amdgcn_mfma_f32_16x16x32_bf16(aLo[fr][kk], bl[fc][kk], acc[0][fr][0][fc], 0, 0, 0);
    __builtin_amdgcn_s_setprio(0);
    BAR_POST();

    // ph1: read B-hi(4); stage A1(t+1); MFMA (Alo,Bhi)
#pragma unroll
    for (int fc = 0; fc < 2; ++fc)
#pragma unroll
      for (int kk = 0; kk < 2; ++kk)
        bh[fc][kk] = frag_ld(sBc, 128 + wn * 32 + fc * 16 + llo, (kk << 6) + (lhi << 4));
    stage_half(Ab + 128 * lda, lda, k1, bn + 8192, t);
    BAR_PRE();
    __builtin_amdgcn_s_setprio(1);
#pragma unroll
    for (int fr = 0; fr < 4; ++fr)
#pragma unroll
      for (int fc = 0; fc < 2; ++fc)
#pragma unroll
        for (int kk = 0; kk < 2; ++kk)
          acc[0][fr][1][fc] = __builtin_amdgcn_mfma_f32_16x16x32_bf16(aLo[fr][kk], bh[fc][kk], acc[0][fr][1][fc], 0, 0, 0);
    __builtin_amdgcn_s_setprio(0);
    BAR_POST();

    // ph2: read A-hi(8); stage A0(t+2); MFMA (Ahi,Bhi)
#pragma unroll
    for (int fr = 0; fr < 4; ++fr)
#pragma unroll
      for (int kk = 0; kk < 2; ++kk)
        aHi[fr][kk] = frag_ld(sAc, 128 + wm * 64 + fr * 16 + llo, (kk << 6) + (lhi << 4));
    stage_half(Ab, lda, k2, bc, t);
    BAR_PRE();
    __builtin_amdgcn_s_setprio(1);
#pragma unroll
    for (int fr = 0; fr < 4; ++fr)
#pragma unroll
      for (int fc = 0; fc < 2; ++fc)
#pragma unroll
        for (int kk = 0; kk < 2; ++kk)
          acc[1][fr][1][fc] = __builtin_amdgcn_mfma_f32_16x16x32_bf16(aHi[fr][kk], bh[fc][kk], acc[1][fr][1][fc], 0, 0, 0);
    __builtin_amdgcn_s_setprio(0);
    BAR_POST();

    // ph3: stage B1(t+2); BAR_PRE retires B0(t+1); MFMA (Ahi,Blo);
    //      then pre-read NEXT tile's A-lo + B-lo (latency spans 2 barriers)
    stage_half(Bb + 128 * ldb, ldb, k2, bc + 16384 + 8192, t);
    BAR_PRE();
    __builtin_amdgcn_s_setprio(1);
#pragma unroll
    for (int fr = 0; fr < 4; ++fr)
#pragma unroll
      for (int fc = 0; fc < 2; ++fc)
#pragma unroll
        for (int kk = 0; kk < 2; ++kk)
          acc[1][fr][0][fc] = __builtin_amdgcn_mfma_f32_16x16x32_bf16(aHi[fr][kk], bl[fc][kk], acc[1][fr][0][fc], 0, 0, 0);
    __builtin_amdgcn_s_setprio(0);
#pragma unroll
    for (int fr = 0; fr < 4; ++fr)
#pragma unroll
      for (int kk = 0; kk < 2; ++kk)
        aLo[fr][kk] = frag_ld(bn, wm * 64 + fr * 16 + llo, (kk << 6) + (lhi << 4));
#pragma unroll
    for (int fc = 0; fc < 2; ++fc)
#pragma unroll
      for (int kk = 0; kk < 2; ++kk)
        bl[fc][kk] = frag_ld(bn + 16384, wn * 32 + fc * 16 + llo, (kk << 6) + (lhi << 4));
    BAR_POST();
  }

  const long cb = n0 >> cShift;
  const long ncol0 = n0 - (cb << cShift);
  const long czoff = (long)(z >> 2) * sCz4 + (long)(z & 3) * sCz1 + cb * cBatch;
#pragma unroll
  for (int ah = 0; ah < 2; ++ah)
#pragma unroll
    for (int fr = 0; fr < 4; ++fr)
#pragma unroll
      for (int e = 0; e < 4; ++e) {
        const long r = m0 + ah * 128 + wm * 64 + fr * 16 + lhi * 4 + e;
#pragma unroll
        for (int bh2 = 0; bh2 < 2; ++bh2)
#pragma unroll
          for (int fc = 0; fc < 2; ++fc) {
            const long col = ncol0 + bh2 * 128 + wn * 32 + fc * 16 + llo;
            const float val = acc[ah][fr][bh2][fc][e] * scale;
            if (OUT_F32)
              ((float*)Cv)[czoff + r * ldc + col] = val;
            else
              ((u16*)Cv)[czoff + r * ldc + col] = f2bf(val);
          }
      }
}

// ===== 128x64 NT GEMM, BK=64, 4 waves (2x2), double-buffered (R14-proven) ====
template<bool OUT_F32>
__global__ __launch_bounds__(256, 3) void gemm_nt128x64(
    const u16* __restrict__ A, long lda, long sAz,
    const u16* __restrict__ B, long ldb, long sBz,
    void* __restrict__ Cv, long ldc, long sCz,
    int K, float scale)
{
  __shared__ u16 sm[2 * 12288] __attribute__((aligned(16)));  // 48 KiB

  const int t = threadIdx.x;
  XCD_DECODE2(128, 64);
  A += (long)z * sAz + m0 * lda;
  B += (long)z * sBz + n0 * ldb;

  const int wid = t >> 6, lane = t & 63;
  const int lhi = lane >> 4, llo = lane & 15;
  const int wr = (wid >> 1) * 64, wc = (wid & 1) * 32;

  f32x4 acc[4][2] = {};
  const int NT = K >> 6;   // >= 2

  stage_rows256<4>(A, lda, 0, sm, t);
  stage_rows256<2>(B, ldb, 0, sm + 8192, t);
  stage_rows256<4>(A, lda, 64, sm + 12288, t);
  stage_rows256<2>(B, ldb, 64, sm + 12288 + 8192, t);

  for (int kt = 0; kt < NT; ++kt) {
    asm volatile("s_waitcnt vmcnt(6)" ::: "memory");   // tile kt resident (own-wave)
    __builtin_amdgcn_s_barrier();
    asm volatile("" ::: "memory");
    u16* buf = sm + (kt & 1) * 12288;
    bf16x8 af[4][2], bfr[2][2];
#pragma unroll
    for (int i = 0; i < 4; ++i)
#pragma unroll
      for (int kk = 0; kk < 2; ++kk)
        af[i][kk] = frag_ld(buf, wr + i * 16 + llo, (kk << 6) + (lhi << 4));
#pragma unroll
    for (int j = 0; j < 2; ++j)
#pragma unroll
      for (int kk = 0; kk < 2; ++kk)
        bfr[j][kk] = frag_ld(buf + 8192, wc + j * 16 + llo, (kk << 6) + (lhi << 4));
    __builtin_amdgcn_s_setprio(1);
#pragma unroll
    for (int i = 0; i < 4; ++i)
#pragma unroll
      for (int j = 0; j < 2; ++j)
#pragma unroll
        for (int kk = 0; kk < 2; ++kk)
          acc[i][j] = __builtin_amdgcn_mfma_f32_16x16x32_bf16(af[i][kk], bfr[j][kk], acc[i][j], 0, 0, 0);
    __builtin_amdgcn_s_setprio(0);
    asm volatile("" ::: "memory");
    __builtin_amdgcn_s_barrier();
    asm volatile("" ::: "memory");
    const int k2 = ((kt + 2 < NT) ? kt + 2 : kt + 2 - NT) << 6;   // wrapped-dead at tail
    stage_rows256<4>(A, lda, k2, buf, t);
    stage_rows256<2>(B, ldb, k2, buf + 8192, t);
  }

#pragma unroll
  for (int i = 0; i < 4; ++i) {
#pragma unroll
    for (int e = 0; e < 4; ++e) {
      const long r = m0 + wr + i * 16 + lhi * 4 + e;
      if (OUT_F32) {
        float* C = (float*)Cv + (long)z * sCz + r * ldc + n0 + wc + llo;
#pragma unroll
        for (int j = 0; j < 2; ++j) C[j * 16] = acc[i][j][e] * scale;
      } else {
        u16* C = (u16*)Cv + (long)z * sCz + r * ldc + n0 + wc + llo;
#pragma unroll
        for (int j = 0; j < 2; ++j) C[j * 16] = f2bf(acc[i][j][e] * scale);
      }
    }
  }
}

// ---- reduce 4 split-K bf16 partials of G -> bf16 [4][1024][1024] ----
__global__ __launch_bounds__(256) void greduce4b(const u16* __restrict__ gp,
                                                 u16* __restrict__ gb) {
  const long o = (long)blockIdx.x * 256 + threadIdx.x;   // ushort8 index; 512K total
  const long b = o >> 17;
  const long r = o & 131071;
  float s[8] = {};
#pragma unroll
  for (int p = 0; p < 4; ++p) {
    ushort8 u = reinterpret_cast<const ushort8*>(gp)[((b * 4 + p) << 17) + r];
#pragma unroll
    for (int j = 0; j < 8; ++j) s[j] += bf2f(u[j]);
  }
  ushort8 out;
#pragma unroll
  for (int j = 0; j < 8; ++j) out[j] = f2bf(s[j]);
  reinterpret_cast<ushort8*>(gb)[o] = out;
}

// ---- single-pass row softmax: att f32 [4096][1024] -> P bf16 ----
__global__ __launch_bounds__(256) void softmax1(const float* __restrict__ att,
                                                u16* __restrict__ P) {
  const long row = blockIdx.x;
  const int t = threadIdx.x;
  float4 v = reinterpret_cast<const float4*>(att + row * 1024)[t];
  float m = fmaxf(fmaxf(v.x, v.y), fmaxf(v.z, v.w));
#pragma unroll
  for (int off = 32; off > 0; off >>= 1) m = fmaxf(m, __shfl_down(m, off, 64));
  __shared__ float smax[4], ssum[4];
  const int wid = t >> 6, lane = t & 63;
  if (lane == 0) smax[wid] = m;
  __syncthreads();
  m = fmaxf(fmaxf(smax[0], smax[1]), fmaxf(smax[2], smax[3]));
  float e0 = expf(v.x - m), e1 = expf(v.y - m), e2 = expf(v.z - m), e3 = expf(v.w - m);
  float s = e0 + e1 + e2 + e3;
#pragma unroll
  for (int off = 32; off > 0; off >>= 1) s += __shfl_down(s, off, 64);
  if (lane == 0) ssum[wid] = s;
  __syncthreads();
  s = ssum[0] + ssum[1] + ssum[2] + ssum[3];
  float inv = 1.0f / s;
  ushort4 o;
  o.x = f2bf(e0 * inv); o.y = f2bf(e1 * inv); o.z = f2bf(e2 * inv); o.w = f2bf(e3 * inv);
  reinterpret_cast<ushort4*>(P + row * 1024)[t] = o;
}

extern "C" void kernel_launch(void* const* d_in, const int* in_sizes, int n_in,
                              void* d_out, int out_size, void* d_ws, size_t ws_size,
                              hipStream_t stream) {
  const float* x  = (const float*)d_in[0];
  const float* Wq = (const float*)d_in[1];
  const float* Wk = (const float*)d_in[2];
  const float* Wv = (const float*)d_in[3];
  const float* Wo = (const float*)d_in[4];

  const long M1 = 1L << 20;               // 1M elements

  // workspace layout (u16 elements)
  u16* xbf    = (u16*)d_ws;               // [16384][1024]                      16M
  u16* wq     = xbf + 16 * M1;            //                                     1M
  u16* wk     = wq + M1;                  //                                     1M
  u16* wv     = wk + M1;                  //                                     1M
  u16* wo     = wv + M1;                  //                                     1M
  u16* wvT    = wo + M1;                  // Wv^T                                1M
  u16* xT     = wvT + M1;                 // [4][1024 feat][4096 tok]           16M
  u16* gbf    = xT + 16 * M1;             // G bf16 [4][1024][1024]              4M
  u16* tbuf   = gbf + 4 * M1;             // T~ = Wq G                           4M
  u16* pbuf   = tbuf + 4 * M1;            // P (softmax)                         4M
  u16* rtb    = pbuf + 4 * M1;            // R^T                                 4M
  u16* sbuf   = rtb + 4 * M1;             // S = Wo R                            4M
  u16* gpartb = sbuf + 4 * M1;            // G bf16 partials [16][1024][1024]   16M
  float* attf = (float*)d_out;            // att f32 [4][1024][1024] (16 MB)

  dim3 b256(256), b512(512);
  const long NOF = 0;
  const int NSH = 30;

  // conversions + transposes
  cvt_x_dual<<<dim3(16, 64, 4), b256, 0, stream>>>(x, xbf, xT);
  cvt_w4<<<dim3(4096), b256, 0, stream>>>(Wq, Wk, Wv, Wo, wq, wk, wv, wo);
  transpose_bf16<<<dim3(16, 16, 1), b256, 0, stream>>>(wv, 1024, 0, wvT, 1024, 0);

  // G[b] = x[b]^T x[b]  (M=N=1024, K=4096 split 4; z=b*4+p) -> bf16 partials
  gemm_nt256<false><<<dim3(4, 4, 16), b512, 0, stream>>>(
      xT, 4096, 1024L * 4096, 1024, xT, 4096, 1024L * 4096, 1024,
      (void*)gpartb, 1024, 4L << 20, 1L << 20, NOF, NSH, 1024, 1.0f);
  greduce4b<<<dim3(2048), b256, 0, stream>>>(gpartb, gbf);

  // T~[b] = Wq G[b]   (G symmetric -> NT form)
  gemm_nt128x64<false><<<dim3(8, 16, 4), b256, 0, stream>>>(
      wq, 1024, 0, gbf, 1024, M1, (void*)tbuf, 1024, M1, 1024, 1.0f);
  // att[b] = T~[b] Wk^T / 32 -> f32 in d_out
  gemm_nt128x64<true><<<dim3(8, 16, 4), b256, 0, stream>>>(
      tbuf, 1024, M1, wk, 1024, 0, (void*)attf, 1024, M1, 1024, 1.0f / 32.0f);
  // softmax rows -> P bf16
  softmax1<<<dim3(4096), b256, 0, stream>>>(attf, pbuf);

  // R^T[b]: C[e,k] = sum_j Wv[j,e] P[k,j]
  gemm_nt128x64<false><<<dim3(8, 16, 4), b256, 0, stream>>>(
      wvT, 1024, 0, pbuf, 1024, M1, (void*)rtb, 1024, M1, 1024, 1.0f);
  // S[b]: C[e',e] = sum_k Wo[e',k] RT[e,k]
  gemm_nt128x64<false><<<dim3(8, 16, 4), b256, 0, stream>>>(
      wo, 1024, 0, rtb, 1024, M1, (void*)sbuf, 1024, M1, 1024, 1.0f);

  // final[b] = x[b] S[b]^T  (M=4096/batch, N=1024, K=1024) -> d_out f32
  gemm_nt256<true><<<dim3(16, 4, 4), b512, 0, stream>>>(
      xbf, 1024, 0, 4096L * 1024, sbuf, 1024, 0, M1,
      d_out, 1024, 0, 4096L * 1024, NOF, NSH, 1024, 1.0f);
}